// Round 9
// baseline (1314.470 us; speedup 1.0000x reference)
//
#include <hip/hip_runtime.h>
#include <hip/hip_bf16.h>
#include <math.h>

constexpr int NA  = 100000;
constexpr int NPP = 100000;
constexpr int D   = 128;
constexpr int H   = 4;
constexpr int E   = 400000;
constexpr int R   = 3;
constexpr int L   = 2;
constexpr int NSLOT = 23;
constexpr int SLOT_ELEMS = 8 * 4 * 512;   // 8 col-tiles * 4 ksteps * 512 bf16
constexpr int FCH = 4096;                 // dsts per CSR-build chunk
constexpr int NCH = (NPP + FCH - 1) / FCH; // 25

using s8v = __attribute__((ext_vector_type(8))) short;
using f4v = __attribute__((ext_vector_type(4))) float;
typedef unsigned short ushort_t;

static __device__ __forceinline__ unsigned short f2bf(float f) {
  unsigned u = __float_as_uint(f);
  return (unsigned short)((u + 0x7fffu + ((u >> 16) & 1u)) >> 16);
}
static __device__ __forceinline__ float bf2f(unsigned short s) {
  return __uint_as_float(((unsigned)s) << 16);
}
static __device__ __forceinline__ float gelu_f(float x) {
  return 0.5f * x * (1.0f + erff(x * 0.70710678118654752f));
}
static __device__ __forceinline__ float elu_f(float x) {
  return x > 0.0f ? x : expm1f(x);
}

// =============== LDS-staged MFMA GEMM: C = act(A[M,128]) @ B + bias =============
// block = 256 thr = 4 waves; wave computes 32 rows (2 frags) x NT16*16 cols.
// B staged in LDS once per block; fragments via ds_read_b128.
// A fragment: lane l -> row = l&15, k(i) = 4*(l>>4) + (i&3) + 16*(i>>2) + 32*ks.
// B packed in the SAME k-order -> any hw k-permutation cancels.
// C/D layout (m89-verified): col = lane&15, row = (lane>>4)*4 + reg.
// BLO: include B-lo correction MFMAs (near-fp32 weights). TA=float also splits A.
// STORE: 0 = fp32 out, 1 = bf16 out. MIX: bf16 h residual read-modify-write.
template<int NT16, int NCOLS, int STORE, bool GELU_A, bool MIX, bool BLO, typename TA>
__global__ __launch_bounds__(256, 4) void gemm4(
    const TA* __restrict__ A,
    const ushort_t* __restrict__ Bhi, const ushort_t* __restrict__ Blo,
    const float* __restrict__ bias, void* __restrict__ Cv,
    const float* __restrict__ skip_ptr, int M) {
  constexpr int HN = NT16 * 2048;          // ushorts per (hi) half
  __shared__ ushort_t Bs[HN * (BLO ? 2 : 1)];
  constexpr bool AFP32 = sizeof(TA) == 4;

  for (int i = threadIdx.x; i < (HN / 8) * (BLO ? 2 : 1); i += 256) {
    int half = i / (HN / 8), j = i % (HN / 8);
    const ushort_t* src = (half ? Blo : Bhi) + (size_t)j * 8;
    *(s8v*)&Bs[half * HN + j * 8] = *(const s8v*)src;
  }
  __syncthreads();

  const int lane = threadIdx.x & 63;
  const int wave = threadIdx.x >> 6;
  const int row0 = blockIdx.x * 128 + wave * 32;
  const int g = lane >> 4, li = lane & 15;

  f4v acc0[NT16], acc1[NT16];
#pragma unroll
  for (int ct = 0; ct < NT16; ++ct) {
    acc0[ct] = f4v{0.f, 0.f, 0.f, 0.f};
    acc1[ct] = f4v{0.f, 0.f, 0.f, 0.f};
  }

  int ar0 = row0 + li;       if (ar0 >= M) ar0 = M - 1;
  int ar1 = row0 + 16 + li;  if (ar1 >= M) ar1 = M - 1;

#pragma unroll
  for (int ks = 0; ks < 4; ++ks) {
    s8v ahi[2], alo[2];
#pragma unroll
    for (int rf = 0; rf < 2; ++rf) {
      int ar = rf ? ar1 : ar0;
      if constexpr (AFP32) {
        const float* ap = (const float*)A + (size_t)ar * 128 + ks * 32 + g * 4;
        float4 u0 = *(const float4*)ap;
        float4 u1 = *(const float4*)(ap + 16);
        float x[8] = {u0.x, u0.y, u0.z, u0.w, u1.x, u1.y, u1.z, u1.w};
#pragma unroll
        for (int i = 0; i < 8; ++i) {
          float v = GELU_A ? gelu_f(x[i]) : x[i];
          unsigned short h = f2bf(v);
          ahi[rf][i] = (short)h;
          alo[rf][i] = (short)f2bf(v - bf2f(h));
        }
      } else {
        const ushort_t* ap = (const ushort_t*)A + (size_t)ar * 128 + ks * 32 + g * 4;
        ushort4 u0 = *(const ushort4*)ap;
        ushort4 u1 = *(const ushort4*)(ap + 16);
        ushort_t uu[8] = {u0.x, u0.y, u0.z, u0.w, u1.x, u1.y, u1.z, u1.w};
#pragma unroll
        for (int i = 0; i < 8; ++i) {
          if (GELU_A) ahi[rf][i] = (short)f2bf(gelu_f(bf2f(uu[i])));
          else        ahi[rf][i] = (short)uu[i];
        }
      }
    }
#pragma unroll
    for (int ct = 0; ct < NT16; ++ct) {
      const ushort_t* bp = &Bs[(ct * 4 + ks) * 512 + lane * 8];
      s8v bhi = *(const s8v*)bp;
      acc0[ct] = __builtin_amdgcn_mfma_f32_16x16x32_bf16(ahi[0], bhi, acc0[ct], 0, 0, 0);
      acc1[ct] = __builtin_amdgcn_mfma_f32_16x16x32_bf16(ahi[1], bhi, acc1[ct], 0, 0, 0);
      if constexpr (BLO) {
        s8v blo = *(const s8v*)(bp + HN);
        if constexpr (AFP32) {
          acc0[ct] = __builtin_amdgcn_mfma_f32_16x16x32_bf16(alo[0], bhi, acc0[ct], 0, 0, 0);
          acc1[ct] = __builtin_amdgcn_mfma_f32_16x16x32_bf16(alo[1], bhi, acc1[ct], 0, 0, 0);
        }
        acc0[ct] = __builtin_amdgcn_mfma_f32_16x16x32_bf16(ahi[0], blo, acc0[ct], 0, 0, 0);
        acc1[ct] = __builtin_amdgcn_mfma_f32_16x16x32_bf16(ahi[1], blo, acc1[ct], 0, 0, 0);
      }
    }
  }

  float sskip = 0.f;
  if (MIX) sskip = 1.f / (1.f + __expf(-*skip_ptr));
#pragma unroll
  for (int rf = 0; rf < 2; ++rf) {
#pragma unroll
    for (int ct = 0; ct < NT16; ++ct) {
      int col = ct * 16 + li;
      bool colok = (col < NCOLS);
      float bv = colok ? bias[col] : 0.f;
      f4v a = rf ? acc1[ct] : acc0[ct];
#pragma unroll
      for (int r = 0; r < 4; ++r) {
        int grow = row0 + rf * 16 + g * 4 + r;
        if (grow < M && colok) {
          float v = a[r] + bv;
          size_t off = (size_t)grow * NCOLS + col;
          if constexpr (MIX) {            // bf16 h residual
            ushort_t* Cp = (ushort_t*)Cv;
            float hprev = bf2f(Cp[off]);
            Cp[off] = f2bf(elu_f(sskip * v + (1.f - sskip) * hprev));
          } else if constexpr (STORE == 1) {
            ((ushort_t*)Cv)[off] = f2bf(v);
          } else {
            ((float*)Cv)[off] = v;
          }
        }
      }
    }
  }
}

// ============ KV GEMM: LDS-staged, column-half split, pair-interleaved store ====
__global__ __launch_bounds__(256, 4) void gemm_kv(
    const ushort_t* __restrict__ A,
    const ushort_t* __restrict__ Bhi, const ushort_t* __restrict__ Blo,
    const float* __restrict__ bias, ushort_t* __restrict__ kvout, int M) {
  __shared__ ushort_t Bs[16384];           // [kv][t][ks][512]
  const int ch = blockIdx.y;
  for (int i = threadIdx.x; i < 2048; i += 256) {
    int kvh = i >> 10, j = i & 1023;
    const ushort_t* src = Bhi + (size_t)kvh * SLOT_ELEMS + ch * 8192 + j * 8;
    *(s8v*)&Bs[kvh * 8192 + j * 8] = *(const s8v*)src;
  }
  __syncthreads();

  const int lane = threadIdx.x & 63;
  const int wave = threadIdx.x >> 6;
  const int row0 = blockIdx.x * 128 + wave * 32;
  const int g = lane >> 4, li = lane & 15;

  f4v acc0[8], acc1[8];                    // [0..3]=K, [4..7]=V
#pragma unroll
  for (int t = 0; t < 8; ++t) {
    acc0[t] = f4v{0.f, 0.f, 0.f, 0.f};
    acc1[t] = f4v{0.f, 0.f, 0.f, 0.f};
  }

  int ar0 = row0 + li;       if (ar0 >= M) ar0 = M - 1;
  int ar1 = row0 + 16 + li;  if (ar1 >= M) ar1 = M - 1;

#pragma unroll
  for (int ks = 0; ks < 4; ++ks) {
    s8v a0, a1;
    {
      const ushort_t* ap = A + (size_t)ar0 * 128 + ks * 32 + g * 4;
      ushort4 u0 = *(const ushort4*)ap;
      ushort4 u1 = *(const ushort4*)(ap + 16);
      a0[0] = (short)u0.x; a0[1] = (short)u0.y; a0[2] = (short)u0.z; a0[3] = (short)u0.w;
      a0[4] = (short)u1.x; a0[5] = (short)u1.y; a0[6] = (short)u1.z; a0[7] = (short)u1.w;
    }
    {
      const ushort_t* ap = A + (size_t)ar1 * 128 + ks * 32 + g * 4;
      ushort4 u0 = *(const ushort4*)ap;
      ushort4 u1 = *(const ushort4*)(ap + 16);
      a1[0] = (short)u0.x; a1[1] = (short)u0.y; a1[2] = (short)u0.z; a1[3] = (short)u0.w;
      a1[4] = (short)u1.x; a1[5] = (short)u1.y; a1[6] = (short)u1.z; a1[7] = (short)u1.w;
    }
#pragma unroll
    for (int t = 0; t < 4; ++t) {
      s8v kh = *(const s8v*)&Bs[(t * 4 + ks) * 512 + lane * 8];
      acc0[t] = __builtin_amdgcn_mfma_f32_16x16x32_bf16(a0, kh, acc0[t], 0, 0, 0);
      acc1[t] = __builtin_amdgcn_mfma_f32_16x16x32_bf16(a1, kh, acc1[t], 0, 0, 0);
      s8v vh = *(const s8v*)&Bs[8192 + (t * 4 + ks) * 512 + lane * 8];
      acc0[4 + t] = __builtin_amdgcn_mfma_f32_16x16x32_bf16(a0, vh, acc0[4 + t], 0, 0, 0);
      acc1[4 + t] = __builtin_amdgcn_mfma_f32_16x16x32_bf16(a1, vh, acc1[4 + t], 0, 0, 0);
    }
  }

#pragma unroll
  for (int rf = 0; rf < 2; ++rf) {
#pragma unroll
    for (int t = 0; t < 4; ++t) {
      int col = ch * 64 + t * 16 + li;
      float bk = bias[col], bv = bias[128 + col];
#pragma unroll
      for (int r = 0; r < 4; ++r) {
        int grow = row0 + rf * 16 + g * 4 + r;
        if (grow < M) {
          float kvl = rf ? acc1[t][r] : acc0[t][r];
          float vvl = rf ? acc1[4 + t][r] : acc0[4 + t][r];
          ushort2 o;
          o.x = f2bf(kvl + bk);
          o.y = f2bf(vvl + bv);
          *(ushort2*)(kvout + (size_t)grow * 256 + 2 * col) = o;
        }
      }
    }
  }
}

// ------------- combined weights: cw = W @ blockdiag(rel), cb = b @ blockdiag(rel)
__global__ __launch_bounds__(256) void combine_w(
    const float* __restrict__ kqv_w, const float* __restrict__ kqv_b,
    const float* __restrict__ rel_a, const float* __restrict__ rel_m,
    float* __restrict__ cw, float* __restrict__ cb) {
  int b  = blockIdx.x;            // ((l*R)+r)*2+kv
  int kv = b & 1;
  int r  = (b >> 1) % R;
  int l  = b / (2 * R);
  int t_src = (r == 0) ? 0 : 1;
  int i_w   = (kv == 0) ? 0 : 2;
  const float* W    = kqv_w + ((size_t)((l*3 + i_w)*2 + t_src)) * D * D;
  const float* bvec = kqv_b + ((size_t)((l*3 + i_w)*2 + t_src)) * D;
  const float* rel  = ((kv == 0) ? rel_a : rel_m) + ((size_t)(l*R + r)) * H * 32 * 32;
  float* Cout = cw + (size_t)b * D * D;
  float* cbo  = cb + (size_t)b * D;
  for (int idx = threadIdx.x; idx < D * D; idx += 256) {
    int i = idx / D, j = idx % D;
    int h = j >> 5, f = j & 31;
    const float* relh = rel + h * 32 * 32;
    float sum = 0.f;
#pragma unroll
    for (int d = 0; d < 32; ++d) sum += W[i*D + (h*32 + d)] * relh[d*32 + f];
    Cout[idx] = sum;
  }
  if (threadIdx.x < D) {
    int j = threadIdx.x;
    int h = j >> 5, f = j & 31;
    const float* relh = rel + h * 32 * 32;
    float sum = 0.f;
#pragma unroll
    for (int d = 0; d < 32; ++d) sum += bvec[h*32 + d] * relh[d*32 + f];
    cbo[j] = sum;
  }
}

// ------------- pack weight matrices into MFMA-fragment order (hi/lo split) -------
__global__ __launch_bounds__(256) void pack_b(
    const float* __restrict__ proj_w, const float* __restrict__ kqv_w,
    const float* __restrict__ out_w, const float* __restrict__ cls_w,
    const float* __restrict__ cw,
    ushort_t* __restrict__ phi, ushort_t* __restrict__ plo) {
  int slot = blockIdx.x;
  const float* src; int ncol = 128;
  if (slot == 0) src = proj_w;
  else if (slot == 1) src = proj_w + D * D;
  else if (slot == 22) { src = cls_w; ncol = 40; }
  else {
    int l = (slot - 2) / 10, k = (slot - 2) % 10;
    if (k == 0)      src = kqv_w + ((size_t)((l*3 + 1)*2 + 0)) * D * D;
    else if (k == 1) src = kqv_w + ((size_t)((l*3 + 1)*2 + 1)) * D * D;
    else if (k < 8)  { int idx = k - 2; src = cw + ((size_t)((l*R)*2 + idx)) * D * D; }
    else             src = out_w + ((size_t)(l*2 + (k - 8))) * D * D;
  }
  int nt = (ncol + 15) / 16;
  int total = nt * 4 * 512;
  ushort_t* ph = phi + (size_t)slot * SLOT_ELEMS;
  ushort_t* pl = plo + (size_t)slot * SLOT_ELEMS;
  for (int idx = threadIdx.x; idx < total; idx += 256) {
    int j = idx & 7, lane = (idx >> 3) & 63, ks = (idx >> 9) & 3, ct = idx >> 11;
    int k = 4 * (lane >> 4) + (j & 3) + 16 * (j >> 2) + 32 * ks;
    int n = ct * 16 + (lane & 15);
    float v = (n < ncol) ? src[(size_t)k * ncol + n] : 0.f;
    unsigned short h = f2bf(v);
    ph[idx] = h;
    pl[idx] = f2bf(v - bf2f(h));
  }
}

// ---------------- CSR build: dst-chunked, single-writer, LDS counters -----------
// grid (NCH, 3); block owns dsts [chunk*FCH, chunk*FCH+FCH); scans the whole
// edge list as int4; in-range edges counted/placed via LDS atomics; global
// writes confined to the block's own contiguous deg/col region (no cross-XCD
// line sharing, no global atomics, no memset needed).
__global__ __launch_bounds__(256) void count_chunk(
    const int* __restrict__ ei_w, const int* __restrict__ ei_c,
    const int* __restrict__ ei_r, int* __restrict__ degz) {
  int rel = blockIdx.y;
  const int* ei = rel == 0 ? ei_w : rel == 1 ? ei_c : ei_r;
  const int4* dst4 = (const int4*)(ei + E);
  int lo = blockIdx.x * FCH;
  __shared__ int cnt[FCH];
  for (int i = threadIdx.x; i < FCH; i += 256) cnt[i] = 0;
  __syncthreads();
  for (int e4 = threadIdx.x; e4 < E / 4; e4 += 256) {
    int4 d = dst4[e4];
    unsigned a0 = (unsigned)(d.x - lo), a1 = (unsigned)(d.y - lo);
    unsigned a2 = (unsigned)(d.z - lo), a3 = (unsigned)(d.w - lo);
    if (a0 < FCH) atomicAdd(&cnt[a0], 1);
    if (a1 < FCH) atomicAdd(&cnt[a1], 1);
    if (a2 < FCH) atomicAdd(&cnt[a2], 1);
    if (a3 < FCH) atomicAdd(&cnt[a3], 1);
  }
  __syncthreads();
  int* deg = degz + rel * NPP;
  for (int i = threadIdx.x; i < FCH; i += 256) {
    int g = lo + i;
    if (g < NPP) deg[g] = cnt[i];
  }
}

__global__ __launch_bounds__(256) void fill_chunk(
    const int* __restrict__ ei_w, const int* __restrict__ ei_c,
    const int* __restrict__ ei_r,
    const int* __restrict__ rp_w, const int* __restrict__ rp_c,
    const int* __restrict__ rp_r, int* __restrict__ colz) {
  int rel = blockIdx.y;
  const int* ei  = rel == 0 ? ei_w : rel == 1 ? ei_c : ei_r;
  const int* rp  = rel == 0 ? rp_w : rel == 1 ? rp_c : rp_r;
  const int4* src4 = (const int4*)ei;
  const int4* dst4 = (const int4*)(ei + E);
  int* col = colz + rel * E;
  int lo = blockIdx.x * FCH;
  __shared__ int base[FCH];
  __shared__ int cnt[FCH];
  for (int i = threadIdx.x; i < FCH; i += 256) {
    int g = lo + i;
    base[i] = (g < NPP) ? rp[g] : 0;
    cnt[i] = 0;
  }
  __syncthreads();
  for (int e4 = threadIdx.x; e4 < E / 4; e4 += 256) {
    int4 d = dst4[e4];
    int4 s = src4[e4];
    unsigned a0 = (unsigned)(d.x - lo), a1 = (unsigned)(d.y - lo);
    unsigned a2 = (unsigned)(d.z - lo), a3 = (unsigned)(d.w - lo);
    if (a0 < FCH) { int p = atomicAdd(&cnt[a0], 1); col[base[a0] + p] = s.x; }
    if (a1 < FCH) { int p = atomicAdd(&cnt[a1], 1); col[base[a1] + p] = s.y; }
    if (a2 < FCH) { int p = atomicAdd(&cnt[a2], 1); col[base[a2] + p] = s.z; }
    if (a3 < FCH) { int p = atomicAdd(&cnt[a3], 1); col[base[a3] + p] = s.w; }
  }
}

// 3-phase exclusive scan over three 100000-length deg arrays (contiguous)
__global__ __launch_bounds__(256) void scan_partial(const int* __restrict__ degz,
                                                    int* __restrict__ bsum) {
  int blk = blockIdx.x, rel = blk / 25, t25 = blk % 25;
  const int* deg = degz + rel * NPP + t25 * 4096;
  int nrem = min(4096, NPP - t25 * 4096);
  int base = threadIdx.x * 16;
  int s = 0;
  if (base < nrem) {
#pragma unroll
    for (int i4 = 0; i4 < 4; ++i4) {
      int4 v = *(const int4*)(deg + base + i4 * 4);
      s += v.x + v.y + v.z + v.w;
    }
  }
  __shared__ int sm[256];
  sm[threadIdx.x] = s; __syncthreads();
  for (int o = 128; o > 0; o >>= 1) {
    if (threadIdx.x < o) sm[threadIdx.x] += sm[threadIdx.x + o];
    __syncthreads();
  }
  if (threadIdx.x == 0) bsum[blk] = sm[0];
}
__global__ __launch_bounds__(128) void scan_offsets(const int* __restrict__ bsum,
                                                    int* __restrict__ boff,
                                                    int* rp_w, int* rp_c, int* rp_r) {
  __shared__ int sm[128];
  int t = threadIdx.x;
  sm[t] = (t < 75) ? bsum[t] : 0;
  __syncthreads();
  for (int o = 1; o < 128; o <<= 1) {
    int v = (t >= o) ? sm[t - o] : 0;
    __syncthreads(); sm[t] += v; __syncthreads();
  }
  if (t < 75) {
    int rel = t / 25;
    int base = rel ? sm[rel * 25 - 1] : 0;
    boff[t] = (t % 25 == 0) ? 0 : (sm[t - 1] - base);
    if (t % 25 == 24) {
      int total = sm[t] - base;
      if (rel == 0) rp_w[NPP] = total;
      else if (rel == 1) rp_c[NPP] = total;
      else rp_r[NA] = total;
    }
  }
}
__global__ __launch_bounds__(256) void scan_final(const int* __restrict__ degz,
                                                  const int* __restrict__ boff,
                                                  int* rp_w, int* rp_c, int* rp_r) {
  int blk = blockIdx.x, rel = blk / 25, t25 = blk % 25;
  const int* deg = degz + rel * NPP + t25 * 4096;
  int* rp = (rel == 0 ? rp_w : rel == 1 ? rp_c : rp_r) + t25 * 4096;
  int nrem = min(4096, NPP - t25 * 4096);
  int base = threadIdx.x * 16;
  bool ok = base < nrem;
  int v[16]; int s = 0;
  if (ok) {
#pragma unroll
    for (int i4 = 0; i4 < 4; ++i4) {
      int4 u = *(const int4*)(deg + base + i4 * 4);
      v[i4*4+0] = u.x; v[i4*4+1] = u.y; v[i4*4+2] = u.z; v[i4*4+3] = u.w;
      s += u.x + u.y + u.z + u.w;
    }
  }
  __shared__ int sm[256];
  sm[threadIdx.x] = s; __syncthreads();
  for (int o = 1; o < 256; o <<= 1) {
    int x = (threadIdx.x >= o) ? sm[threadIdx.x - o] : 0;
    __syncthreads(); sm[threadIdx.x] += x; __syncthreads();
  }
  int run = boff[blk] + sm[threadIdx.x] - s;
  if (ok) {
    int w[16];
#pragma unroll
    for (int i = 0; i < 16; ++i) { w[i] = run; run += v[i]; }
#pragma unroll
    for (int i4 = 0; i4 < 4; ++i4) *(int4*)(rp + base + i4 * 4) = *(const int4*)&w[i4*4];
  }
}

// -------- per-destination attention (no-max softmax: scores are O(1)) -----------
// 1 wave / node; lane holds dims {2l,2l+1}; head = lane>>4; one ushort4 gather
// per edge from the pair-interleaved kv [k0,v0,k1,v1,...]; 4/2/1 edge ladder
// keeps 4 independent gathers in flight. TWO: second relation (paper dst joins
// writes + cites in one softmax). Writes normalized bf16 agg into aggout (the
// q buffer: each wave reads its own q row before overwriting it).
static __device__ __forceinline__ void attn_seg(
    const int* __restrict__ rp, const int* __restrict__ col,
    const ushort_t* __restrict__ kv, float pr, int dst, int lane,
    float qx, float qy, float& z, float& ax, float& ay) {
  int e0 = rp[dst], e1 = rp[dst + 1];
  int j = e0;
  for (; j + 3 < e1; j += 4) {
    int s0 = col[j], s1 = col[j+1], s2 = col[j+2], s3 = col[j+3];
    ushort4 u0 = *(const ushort4*)(kv + (size_t)s0 * 256 + lane * 4);
    ushort4 u1 = *(const ushort4*)(kv + (size_t)s1 * 256 + lane * 4);
    ushort4 u2 = *(const ushort4*)(kv + (size_t)s2 * 256 + lane * 4);
    ushort4 u3 = *(const ushort4*)(kv + (size_t)s3 * 256 + lane * 4);
    float p0 = qx * bf2f(u0.x) + qy * bf2f(u0.z);
    float p1 = qx * bf2f(u1.x) + qy * bf2f(u1.z);
    float p2 = qx * bf2f(u2.x) + qy * bf2f(u2.z);
    float p3 = qx * bf2f(u3.x) + qy * bf2f(u3.z);
    p0 += __shfl_xor(p0, 1); p1 += __shfl_xor(p1, 1); p2 += __shfl_xor(p2, 1); p3 += __shfl_xor(p3, 1);
    p0 += __shfl_xor(p0, 2); p1 += __shfl_xor(p1, 2); p2 += __shfl_xor(p2, 2); p3 += __shfl_xor(p3, 2);
    p0 += __shfl_xor(p0, 4); p1 += __shfl_xor(p1, 4); p2 += __shfl_xor(p2, 4); p3 += __shfl_xor(p3, 4);
    p0 += __shfl_xor(p0, 8); p1 += __shfl_xor(p1, 8); p2 += __shfl_xor(p2, 8); p3 += __shfl_xor(p3, 8);
    float e0v = __expf(p0 * pr), e1v = __expf(p1 * pr);
    float e2v = __expf(p2 * pr), e3v = __expf(p3 * pr);
    z  += (e0v + e1v) + (e2v + e3v);
    ax += e0v * bf2f(u0.y) + e1v * bf2f(u1.y) + e2v * bf2f(u2.y) + e3v * bf2f(u3.y);
    ay += e0v * bf2f(u0.w) + e1v * bf2f(u1.w) + e2v * bf2f(u2.w) + e3v * bf2f(u3.w);
  }
  if (j + 1 < e1) {
    int s0 = col[j], s1 = col[j+1];
    ushort4 u0 = *(const ushort4*)(kv + (size_t)s0 * 256 + lane * 4);
    ushort4 u1 = *(const ushort4*)(kv + (size_t)s1 * 256 + lane * 4);
    float p0 = qx * bf2f(u0.x) + qy * bf2f(u0.z);
    float p1 = qx * bf2f(u1.x) + qy * bf2f(u1.z);
    p0 += __shfl_xor(p0, 1); p1 += __shfl_xor(p1, 1);
    p0 += __shfl_xor(p0, 2); p1 += __shfl_xor(p1, 2);
    p0 += __shfl_xor(p0, 4); p1 += __shfl_xor(p1, 4);
    p0 += __shfl_xor(p0, 8); p1 += __shfl_xor(p1, 8);
    float e0v = __expf(p0 * pr), e1v = __expf(p1 * pr);
    z  += e0v + e1v;
    ax += e0v * bf2f(u0.y) + e1v * bf2f(u1.y);
    ay += e0v * bf2f(u0.w) + e1v * bf2f(u1.w);
    j += 2;
  }
  if (j < e1) {
    int s0 = col[j];
    ushort4 u0 = *(const ushort4*)(kv + (size_t)s0 * 256 + lane * 4);
    float p0 = qx * bf2f(u0.x) + qy * bf2f(u0.z);
    p0 += __shfl_xor(p0, 1);
    p0 += __shfl_xor(p0, 2);
    p0 += __shfl_xor(p0, 4);
    p0 += __shfl_xor(p0, 8);
    float e0v = __expf(p0 * pr);
    z  += e0v;
    ax += e0v * bf2f(u0.y);
    ay += e0v * bf2f(u0.w);
  }
}

template<bool TWO>
__global__ __launch_bounds__(256, 8) void attn4(
    const int* __restrict__ rp1, const int* __restrict__ col1,
    const ushort_t* __restrict__ kv1,
    const int* __restrict__ rp2, const int* __restrict__ col2,
    const ushort_t* __restrict__ kv2,
    const ushort_t* __restrict__ q,
    const float* __restrict__ prel1, const float* __restrict__ prel2,
    int ndst, ushort_t* __restrict__ aggout) {
  int dst  = blockIdx.x * 4 + (threadIdx.x >> 6);
  int lane = threadIdx.x & 63;
  if (dst >= ndst) return;
  int head = lane >> 4;
  const float scale = 0.17677669529663688f; // 1/sqrt(32)
  float pr1 = prel1[head] * scale;
  ushort2 qv = *(const ushort2*)(q + (size_t)dst * D + lane * 2);
  float qx = bf2f(qv.x), qy = bf2f(qv.y);
  float z = 0.f, ax = 0.f, ay = 0.f;
  attn_seg(rp1, col1, kv1, pr1, dst, lane, qx, qy, z, ax, ay);
  if (TWO) {
    float pr2 = prel2[head] * scale;
    attn_seg(rp2, col2, kv2, pr2, dst, lane, qx, qy, z, ax, ay);
  }
  float inv = 1.f / (z + 1e-16f);
  ushort2 o;
  o.x = f2bf(ax * inv);
  o.y = f2bf(ay * inv);
  *(ushort2*)(aggout + (size_t)dst * D + lane * 2) = o;
}

extern "C" void kernel_launch(void* const* d_in, const int* in_sizes, int n_in,
                              void* d_out, int out_size, void* d_ws, size_t ws_size,
                              hipStream_t stream) {
  const float* x_a    = (const float*)d_in[0];
  const float* x_p    = (const float*)d_in[1];
  const int*   ei_w   = (const int*)d_in[2];
  const int*   ei_r   = (const int*)d_in[3];
  const int*   ei_c   = (const int*)d_in[4];
  const float* proj_w = (const float*)d_in[5];
  const float* proj_b = (const float*)d_in[6];
  const float* kqv_w  = (const float*)d_in[7];
  const float* kqv_b  = (const float*)d_in[8];
  const float* out_w  = (const float*)d_in[9];
  const float* out_b  = (const float*)d_in[10];
  const float* rel_a  = (const float*)d_in[11];
  const float* rel_m  = (const float*)d_in[12];
  const float* p_rel  = (const float*)d_in[13];
  const float* skip   = (const float*)d_in[14];
  const float* cls_w  = (const float*)d_in[15];
  const float* cls_b  = (const float*)d_in[16];
  float* out = (float*)d_out;

  const size_t NF = (size_t)NA * D;   // 12.8M
  float* ws    = (float*)d_ws;
  // fp32 region
  float* cw    = ws;                             // 12*D*D
  float* cb    = cw + 12 * D * D;                // 12*D
  // bf16 region
  ushort_t* h_a   = (ushort_t*)(cb + 12 * D);    // NF
  ushort_t* h_p   = h_a + NF;                    // NF
  ushort_t* b_q   = h_p + NF;                    // NF (q, then bf16 agg)
  ushort_t* b_kv  = b_q + NF;                    // 2*NF pair-interleaved
  ushort_t* b_kv2 = b_kv + 2 * NF;               // 2*NF (writes-relation kv)
  ushort_t* phi   = b_kv2 + 2 * NF;              // 23*SLOT_ELEMS
  ushort_t* plo   = phi + (size_t)NSLOT * SLOT_ELEMS;
  // int region
  int* ip    = (int*)(plo + (size_t)NSLOT * SLOT_ELEMS);
  int* rp_w  = ip;                      // NPP+1
  int* rp_c  = rp_w + (NPP + 1);
  int* rp_r  = rp_c + (NPP + 1);
  int* degz  = rp_r + (NA + 1);         // 3*NPP
  int* colz  = degz + 3 * NPP;          // 3*E (src-node per CSR entry)
  int* bsum  = colz + 3 * E;            // 75
  int* boff  = bsum + 128;              // 75
  size_t need_bytes = (size_t)((char*)(boff + 128) - (char*)d_ws);
  if (ws_size < need_bytes) return;

  count_chunk<<<dim3(NCH, 3), 256, 0, stream>>>(ei_w, ei_c, ei_r, degz);
  scan_partial<<<75, 256, 0, stream>>>(degz, bsum);
  scan_offsets<<<1, 128, 0, stream>>>(bsum, boff, rp_w, rp_c, rp_r);
  scan_final<<<75, 256, 0, stream>>>(degz, boff, rp_w, rp_c, rp_r);
  fill_chunk<<<dim3(NCH, 3), 256, 0, stream>>>(ei_w, ei_c, ei_r, rp_w, rp_c, rp_r, colz);
  int* col_w = colz;
  int* col_c = colz + E;
  int* col_r = colz + 2 * E;

  combine_w<<<12, 256, 0, stream>>>(kqv_w, kqv_b, rel_a, rel_m, cw, cb);
  pack_b<<<NSLOT, 256, 0, stream>>>(proj_w, kqv_w, out_w, cls_w, cw, phi, plo);

  auto PH = [&](int s){ return phi + (size_t)s * SLOT_ELEMS; };
  auto PL = [&](int s){ return plo + (size_t)s * SLOT_ELEMS; };

  const int GB2 = (NA + 127) / 128;    // 782
  const dim3 G1(GB2, 1), GKV(GB2, 2);
  // initial projections (fp32 input, bf16 h out, A+B split for precision)
  gemm4<8, 128, 1, false, false, true, float><<<G1, 256, 0, stream>>>(
      x_a, PH(0), PL(0), proj_b,     h_a, nullptr, NA);
  gemm4<8, 128, 1, false, false, true, float><<<G1, 256, 0, stream>>>(
      x_p, PH(1), PL(1), proj_b + D, h_p, nullptr, NPP);

  for (int l = 0; l < L; ++l) {
    const int SQA = 2 + l * 10 + 0, SQP = 2 + l * 10 + 1;
    auto SKV = [&](int r){ return 2 + l * 10 + 2 + r * 2; };  // k slot; v slot = +1
    const int SO0 = 2 + l * 10 + 8, SO1 = 2 + l * 10 + 9;
    const float* bq_a = kqv_b + ((size_t)((l*3 + 1)*2 + 0)) * D;
    const float* bq_p = kqv_b + ((size_t)((l*3 + 1)*2 + 1)) * D;
    auto CB2 = [&](int r){ return cb + ((size_t)((l*R + r)*2)) * D; };  // 256 floats (k|v)
    const float* prelW = p_rel + (size_t)(l*R + 0) * H;
    const float* prelR = p_rel + (size_t)(l*R + 1) * H;
    const float* prelC = p_rel + (size_t)(l*R + 2) * H;

    // ---- author destination (rev_writes r=1, src=paper) ----
    gemm4<8, 128, 1, false, false, false, ushort_t><<<G1, 256, 0, stream>>>(
        h_a, PH(SQA), PL(SQA), bq_a, b_q, nullptr, NA);
    gemm_kv<<<GKV, 256, 0, stream>>>(
        h_p, PH(SKV(1)), PL(SKV(1)), CB2(1), b_kv, NPP);
    attn4<false><<<(NA + 3) / 4, 256, 0, stream>>>(
        rp_r, col_r, b_kv, nullptr, nullptr, nullptr,
        b_q, prelR, prelR, NA, b_q);
    // writes-relation K/V from OLD h_a (before author update) into b_kv2
    gemm_kv<<<GKV, 256, 0, stream>>>(
        h_a, PH(SKV(0)), PL(SKV(0)), CB2(0), b_kv2, NA);
    // author out-mix (in-place bf16 h_a); A = bf16 agg in b_q, gelu applied
    gemm4<8, 128, 1, true, true, false, ushort_t><<<G1, 256, 0, stream>>>(
        b_q, PH(SO0), PL(SO0), out_b + (size_t)(l*2 + 0) * D, h_a,
        skip + l*2 + 0, NA);

    // ---- paper destination: joint softmax over writes(r=0) + cites(r=2) ----
    gemm4<8, 128, 1, false, false, false, ushort_t><<<G1, 256, 0, stream>>>(
        h_p, PH(SQP), PL(SQP), bq_p, b_q, nullptr, NPP);
    gemm_kv<<<GKV, 256, 0, stream>>>(
        h_p, PH(SKV(2)), PL(SKV(2)), CB2(2), b_kv, NPP);
    attn4<true><<<(NPP + 3) / 4, 256, 0, stream>>>(
        rp_w, col_w, b_kv2, rp_c, col_c, b_kv,
        b_q, prelW, prelC, NPP, b_q);
    gemm4<8, 128, 1, true, true, false, ushort_t><<<G1, 256, 0, stream>>>(
        b_q, PH(SO1), PL(SO1), out_b + (size_t)(l*2 + 1) * D, h_p,
        skip + l*2 + 1, NPP);
  }

  gemm4<3, 40, 0, false, false, true, ushort_t><<<G1, 256, 0, stream>>>(
      h_p, PH(22), PL(22), cls_b, out, nullptr, NPP);
}

// Round 10
// 931.438 us; speedup vs baseline: 1.4112x; 1.4112x over previous
//
#include <hip/hip_runtime.h>
#include <hip/hip_bf16.h>
#include <math.h>

constexpr int NA  = 100000;
constexpr int NPP = 100000;
constexpr int D   = 128;
constexpr int H   = 4;
constexpr int E   = 400000;
constexpr int R   = 3;
constexpr int L   = 2;
constexpr int NSLOT = 23;
constexpr int SLOT_ELEMS = 8 * 4 * 512;   // 8 col-tiles * 4 ksteps * 512 bf16

using s8v = __attribute__((ext_vector_type(8))) short;
using f4v = __attribute__((ext_vector_type(4))) float;
typedef unsigned short ushort_t;

static __device__ __forceinline__ unsigned short f2bf(float f) {
  unsigned u = __float_as_uint(f);
  return (unsigned short)((u + 0x7fffu + ((u >> 16) & 1u)) >> 16);
}
static __device__ __forceinline__ float bf2f(unsigned short s) {
  return __uint_as_float(((unsigned)s) << 16);
}
static __device__ __forceinline__ float gelu_f(float x) {
  return 0.5f * x * (1.0f + erff(x * 0.70710678118654752f));
}
static __device__ __forceinline__ float elu_f(float x) {
  return x > 0.0f ? x : expm1f(x);
}

// =============== LDS-staged MFMA GEMM: C = act(A[M,128]) @ B + bias =============
// block = 256 thr = 4 waves; wave computes 32 rows (2 frags) x NT16*16 cols.
// B staged in LDS once per block; fragments via ds_read_b128.
// A fragment: lane l -> row = l&15, k(i) = 4*(l>>4) + (i&3) + 16*(i>>2) + 32*ks.
// B packed in the SAME k-order -> any hw k-permutation cancels.
// C/D layout (m89-verified): col = lane&15, row = (lane>>4)*4 + reg.
// BLO: include B-lo correction MFMAs (near-fp32 weights). TA=float also splits A.
// STORE: 0 = fp32 out, 1 = bf16 out. MIX: bf16 h residual read-modify-write.
template<int NT16, int NCOLS, int STORE, bool GELU_A, bool MIX, bool BLO, typename TA>
__global__ __launch_bounds__(256, 4) void gemm4(
    const TA* __restrict__ A,
    const ushort_t* __restrict__ Bhi, const ushort_t* __restrict__ Blo,
    const float* __restrict__ bias, void* __restrict__ Cv,
    const float* __restrict__ skip_ptr, int M) {
  constexpr int HN = NT16 * 2048;          // ushorts per (hi) half
  __shared__ ushort_t Bs[HN * (BLO ? 2 : 1)];
  constexpr bool AFP32 = sizeof(TA) == 4;

  for (int i = threadIdx.x; i < (HN / 8) * (BLO ? 2 : 1); i += 256) {
    int half = i / (HN / 8), j = i % (HN / 8);
    const ushort_t* src = (half ? Blo : Bhi) + (size_t)j * 8;
    *(s8v*)&Bs[half * HN + j * 8] = *(const s8v*)src;
  }
  __syncthreads();

  const int lane = threadIdx.x & 63;
  const int wave = threadIdx.x >> 6;
  const int row0 = blockIdx.x * 128 + wave * 32;
  const int g = lane >> 4, li = lane & 15;

  f4v acc0[NT16], acc1[NT16];
#pragma unroll
  for (int ct = 0; ct < NT16; ++ct) {
    acc0[ct] = f4v{0.f, 0.f, 0.f, 0.f};
    acc1[ct] = f4v{0.f, 0.f, 0.f, 0.f};
  }

  int ar0 = row0 + li;       if (ar0 >= M) ar0 = M - 1;
  int ar1 = row0 + 16 + li;  if (ar1 >= M) ar1 = M - 1;

#pragma unroll
  for (int ks = 0; ks < 4; ++ks) {
    s8v ahi[2], alo[2];
#pragma unroll
    for (int rf = 0; rf < 2; ++rf) {
      int ar = rf ? ar1 : ar0;
      if constexpr (AFP32) {
        const float* ap = (const float*)A + (size_t)ar * 128 + ks * 32 + g * 4;
        float4 u0 = *(const float4*)ap;
        float4 u1 = *(const float4*)(ap + 16);
        float x[8] = {u0.x, u0.y, u0.z, u0.w, u1.x, u1.y, u1.z, u1.w};
#pragma unroll
        for (int i = 0; i < 8; ++i) {
          float v = GELU_A ? gelu_f(x[i]) : x[i];
          unsigned short h = f2bf(v);
          ahi[rf][i] = (short)h;
          alo[rf][i] = (short)f2bf(v - bf2f(h));
        }
      } else {
        const ushort_t* ap = (const ushort_t*)A + (size_t)ar * 128 + ks * 32 + g * 4;
        ushort4 u0 = *(const ushort4*)ap;
        ushort4 u1 = *(const ushort4*)(ap + 16);
        ushort_t uu[8] = {u0.x, u0.y, u0.z, u0.w, u1.x, u1.y, u1.z, u1.w};
#pragma unroll
        for (int i = 0; i < 8; ++i) {
          if (GELU_A) ahi[rf][i] = (short)f2bf(gelu_f(bf2f(uu[i])));
          else        ahi[rf][i] = (short)uu[i];
        }
      }
    }
#pragma unroll
    for (int ct = 0; ct < NT16; ++ct) {
      const ushort_t* bp = &Bs[(ct * 4 + ks) * 512 + lane * 8];
      s8v bhi = *(const s8v*)bp;
      acc0[ct] = __builtin_amdgcn_mfma_f32_16x16x32_bf16(ahi[0], bhi, acc0[ct], 0, 0, 0);
      acc1[ct] = __builtin_amdgcn_mfma_f32_16x16x32_bf16(ahi[1], bhi, acc1[ct], 0, 0, 0);
      if constexpr (BLO) {
        s8v blo = *(const s8v*)(bp + HN);
        if constexpr (AFP32) {
          acc0[ct] = __builtin_amdgcn_mfma_f32_16x16x32_bf16(alo[0], bhi, acc0[ct], 0, 0, 0);
          acc1[ct] = __builtin_amdgcn_mfma_f32_16x16x32_bf16(alo[1], bhi, acc1[ct], 0, 0, 0);
        }
        acc0[ct] = __builtin_amdgcn_mfma_f32_16x16x32_bf16(ahi[0], blo, acc0[ct], 0, 0, 0);
        acc1[ct] = __builtin_amdgcn_mfma_f32_16x16x32_bf16(ahi[1], blo, acc1[ct], 0, 0, 0);
      }
    }
  }

  float sskip = 0.f;
  if (MIX) sskip = 1.f / (1.f + __expf(-*skip_ptr));
#pragma unroll
  for (int rf = 0; rf < 2; ++rf) {
#pragma unroll
    for (int ct = 0; ct < NT16; ++ct) {
      int col = ct * 16 + li;
      bool colok = (col < NCOLS);
      float bv = colok ? bias[col] : 0.f;
      f4v a = rf ? acc1[ct] : acc0[ct];
#pragma unroll
      for (int r = 0; r < 4; ++r) {
        int grow = row0 + rf * 16 + g * 4 + r;
        if (grow < M && colok) {
          float v = a[r] + bv;
          size_t off = (size_t)grow * NCOLS + col;
          if constexpr (MIX) {            // bf16 h residual
            ushort_t* Cp = (ushort_t*)Cv;
            float hprev = bf2f(Cp[off]);
            Cp[off] = f2bf(elu_f(sskip * v + (1.f - sskip) * hprev));
          } else if constexpr (STORE == 1) {
            ((ushort_t*)Cv)[off] = f2bf(v);
          } else {
            ((float*)Cv)[off] = v;
          }
        }
      }
    }
  }
}

// ============ KV GEMM: LDS-staged, column-half split, pair-interleaved store ====
__global__ __launch_bounds__(256, 4) void gemm_kv(
    const ushort_t* __restrict__ A,
    const ushort_t* __restrict__ Bhi, const ushort_t* __restrict__ Blo,
    const float* __restrict__ bias, ushort_t* __restrict__ kvout, int M) {
  __shared__ ushort_t Bs[16384];           // [kv][t][ks][512]
  const int ch = blockIdx.y;
  for (int i = threadIdx.x; i < 2048; i += 256) {
    int kvh = i >> 10, j = i & 1023;
    const ushort_t* src = Bhi + (size_t)kvh * SLOT_ELEMS + ch * 8192 + j * 8;
    *(s8v*)&Bs[kvh * 8192 + j * 8] = *(const s8v*)src;
  }
  __syncthreads();

  const int lane = threadIdx.x & 63;
  const int wave = threadIdx.x >> 6;
  const int row0 = blockIdx.x * 128 + wave * 32;
  const int g = lane >> 4, li = lane & 15;

  f4v acc0[8], acc1[8];                    // [0..3]=K, [4..7]=V
#pragma unroll
  for (int t = 0; t < 8; ++t) {
    acc0[t] = f4v{0.f, 0.f, 0.f, 0.f};
    acc1[t] = f4v{0.f, 0.f, 0.f, 0.f};
  }

  int ar0 = row0 + li;       if (ar0 >= M) ar0 = M - 1;
  int ar1 = row0 + 16 + li;  if (ar1 >= M) ar1 = M - 1;

#pragma unroll
  for (int ks = 0; ks < 4; ++ks) {
    s8v a0, a1;
    {
      const ushort_t* ap = A + (size_t)ar0 * 128 + ks * 32 + g * 4;
      ushort4 u0 = *(const ushort4*)ap;
      ushort4 u1 = *(const ushort4*)(ap + 16);
      a0[0] = (short)u0.x; a0[1] = (short)u0.y; a0[2] = (short)u0.z; a0[3] = (short)u0.w;
      a0[4] = (short)u1.x; a0[5] = (short)u1.y; a0[6] = (short)u1.z; a0[7] = (short)u1.w;
    }
    {
      const ushort_t* ap = A + (size_t)ar1 * 128 + ks * 32 + g * 4;
      ushort4 u0 = *(const ushort4*)ap;
      ushort4 u1 = *(const ushort4*)(ap + 16);
      a1[0] = (short)u0.x; a1[1] = (short)u0.y; a1[2] = (short)u0.z; a1[3] = (short)u0.w;
      a1[4] = (short)u1.x; a1[5] = (short)u1.y; a1[6] = (short)u1.z; a1[7] = (short)u1.w;
    }
#pragma unroll
    for (int t = 0; t < 4; ++t) {
      s8v kh = *(const s8v*)&Bs[(t * 4 + ks) * 512 + lane * 8];
      acc0[t] = __builtin_amdgcn_mfma_f32_16x16x32_bf16(a0, kh, acc0[t], 0, 0, 0);
      acc1[t] = __builtin_amdgcn_mfma_f32_16x16x32_bf16(a1, kh, acc1[t], 0, 0, 0);
      s8v vh = *(const s8v*)&Bs[8192 + (t * 4 + ks) * 512 + lane * 8];
      acc0[4 + t] = __builtin_amdgcn_mfma_f32_16x16x32_bf16(a0, vh, acc0[4 + t], 0, 0, 0);
      acc1[4 + t] = __builtin_amdgcn_mfma_f32_16x16x32_bf16(a1, vh, acc1[4 + t], 0, 0, 0);
    }
  }

#pragma unroll
  for (int rf = 0; rf < 2; ++rf) {
#pragma unroll
    for (int t = 0; t < 4; ++t) {
      int col = ch * 64 + t * 16 + li;
      float bk = bias[col], bv = bias[128 + col];
#pragma unroll
      for (int r = 0; r < 4; ++r) {
        int grow = row0 + rf * 16 + g * 4 + r;
        if (grow < M) {
          float kvl = rf ? acc1[t][r] : acc0[t][r];
          float vvl = rf ? acc1[4 + t][r] : acc0[4 + t][r];
          ushort2 o;
          o.x = f2bf(kvl + bk);
          o.y = f2bf(vvl + bv);
          *(ushort2*)(kvout + (size_t)grow * 256 + 2 * col) = o;
        }
      }
    }
  }
}

// ------------- combined weights: cw = W @ blockdiag(rel), cb = b @ blockdiag(rel)
__global__ __launch_bounds__(256) void combine_w(
    const float* __restrict__ kqv_w, const float* __restrict__ kqv_b,
    const float* __restrict__ rel_a, const float* __restrict__ rel_m,
    float* __restrict__ cw, float* __restrict__ cb) {
  int b  = blockIdx.x;            // ((l*R)+r)*2+kv
  int kv = b & 1;
  int r  = (b >> 1) % R;
  int l  = b / (2 * R);
  int t_src = (r == 0) ? 0 : 1;
  int i_w   = (kv == 0) ? 0 : 2;
  const float* W    = kqv_w + ((size_t)((l*3 + i_w)*2 + t_src)) * D * D;
  const float* bvec = kqv_b + ((size_t)((l*3 + i_w)*2 + t_src)) * D;
  const float* rel  = ((kv == 0) ? rel_a : rel_m) + ((size_t)(l*R + r)) * H * 32 * 32;
  float* Cout = cw + (size_t)b * D * D;
  float* cbo  = cb + (size_t)b * D;
  for (int idx = threadIdx.x; idx < D * D; idx += 256) {
    int i = idx / D, j = idx % D;
    int h = j >> 5, f = j & 31;
    const float* relh = rel + h * 32 * 32;
    float sum = 0.f;
#pragma unroll
    for (int d = 0; d < 32; ++d) sum += W[i*D + (h*32 + d)] * relh[d*32 + f];
    Cout[idx] = sum;
  }
  if (threadIdx.x < D) {
    int j = threadIdx.x;
    int h = j >> 5, f = j & 31;
    const float* relh = rel + h * 32 * 32;
    float sum = 0.f;
#pragma unroll
    for (int d = 0; d < 32; ++d) sum += bvec[h*32 + d] * relh[d*32 + f];
    cbo[j] = sum;
  }
}

// ------------- pack weight matrices into MFMA-fragment order (hi/lo split) -------
__global__ __launch_bounds__(256) void pack_b(
    const float* __restrict__ proj_w, const float* __restrict__ kqv_w,
    const float* __restrict__ out_w, const float* __restrict__ cls_w,
    const float* __restrict__ cw,
    ushort_t* __restrict__ phi, ushort_t* __restrict__ plo) {
  int slot = blockIdx.x;
  const float* src; int ncol = 128;
  if (slot == 0) src = proj_w;
  else if (slot == 1) src = proj_w + D * D;
  else if (slot == 22) { src = cls_w; ncol = 40; }
  else {
    int l = (slot - 2) / 10, k = (slot - 2) % 10;
    if (k == 0)      src = kqv_w + ((size_t)((l*3 + 1)*2 + 0)) * D * D;
    else if (k == 1) src = kqv_w + ((size_t)((l*3 + 1)*2 + 1)) * D * D;
    else if (k < 8)  { int idx = k - 2; src = cw + ((size_t)((l*R)*2 + idx)) * D * D; }
    else             src = out_w + ((size_t)(l*2 + (k - 8))) * D * D;
  }
  int nt = (ncol + 15) / 16;
  int total = nt * 4 * 512;
  ushort_t* ph = phi + (size_t)slot * SLOT_ELEMS;
  ushort_t* pl = plo + (size_t)slot * SLOT_ELEMS;
  for (int idx = threadIdx.x; idx < total; idx += 256) {
    int j = idx & 7, lane = (idx >> 3) & 63, ks = (idx >> 9) & 3, ct = idx >> 11;
    int k = 4 * (lane >> 4) + (j & 3) + 16 * (j >> 2) + 32 * ks;
    int n = ct * 16 + (lane & 15);
    float v = (n < ncol) ? src[(size_t)k * ncol + n] : 0.f;
    unsigned short h = f2bf(v);
    ph[idx] = h;
    pl[idx] = f2bf(v - bf2f(h));
  }
}

// ---------------- CSR build (global-atomic; measured best at this size) ---------
__global__ void count3(const int* __restrict__ ei_w, const int* __restrict__ ei_c,
                       const int* __restrict__ ei_r, int* __restrict__ degz) {
  const int* dst = blockIdx.y == 0 ? ei_w + E : blockIdx.y == 1 ? ei_c + E : ei_r + E;
  int* deg = degz + blockIdx.y * NPP;
  for (int e = blockIdx.x * blockDim.x + threadIdx.x; e < E; e += gridDim.x * blockDim.x)
    atomicAdd(&deg[dst[e]], 1);
}
__global__ void fill3(const int* __restrict__ ei_w, const int* __restrict__ ei_c,
                      const int* __restrict__ ei_r,
                      const int* __restrict__ rp_w, const int* __restrict__ rp_c,
                      const int* __restrict__ rp_r,
                      int* __restrict__ cntz, int* __restrict__ colz) {
  int rel = blockIdx.y;
  const int* ei = rel == 0 ? ei_w : rel == 1 ? ei_c : ei_r;
  const int* dst = ei + E;
  const int* rp  = rel == 0 ? rp_w : rel == 1 ? rp_c : rp_r;
  int* cnt = cntz + rel * NPP;
  int* col = colz + rel * E;
  for (int e = blockIdx.x * blockDim.x + threadIdx.x; e < E; e += gridDim.x * blockDim.x) {
    int d = dst[e];
    int pos = atomicAdd(&cnt[d], 1);
    col[rp[d] + pos] = ei[e];          // store SOURCE node directly
  }
}

// 3-phase exclusive scan over three 100000-length deg arrays (contiguous)
__global__ __launch_bounds__(256) void scan_partial(const int* __restrict__ degz,
                                                    int* __restrict__ bsum) {
  int blk = blockIdx.x, rel = blk / 25, t25 = blk % 25;
  const int* deg = degz + rel * NPP + t25 * 4096;
  int nrem = min(4096, NPP - t25 * 4096);
  int base = threadIdx.x * 16;
  int s = 0;
  if (base < nrem) {
#pragma unroll
    for (int i4 = 0; i4 < 4; ++i4) {
      int4 v = *(const int4*)(deg + base + i4 * 4);
      s += v.x + v.y + v.z + v.w;
    }
  }
  __shared__ int sm[256];
  sm[threadIdx.x] = s; __syncthreads();
  for (int o = 128; o > 0; o >>= 1) {
    if (threadIdx.x < o) sm[threadIdx.x] += sm[threadIdx.x + o];
    __syncthreads();
  }
  if (threadIdx.x == 0) bsum[blk] = sm[0];
}
__global__ __launch_bounds__(128) void scan_offsets(const int* __restrict__ bsum,
                                                    int* __restrict__ boff,
                                                    int* rp_w, int* rp_c, int* rp_r) {
  __shared__ int sm[128];
  int t = threadIdx.x;
  sm[t] = (t < 75) ? bsum[t] : 0;
  __syncthreads();
  for (int o = 1; o < 128; o <<= 1) {
    int v = (t >= o) ? sm[t - o] : 0;
    __syncthreads(); sm[t] += v; __syncthreads();
  }
  if (t < 75) {
    int rel = t / 25;
    int base = rel ? sm[rel * 25 - 1] : 0;
    boff[t] = (t % 25 == 0) ? 0 : (sm[t - 1] - base);
    if (t % 25 == 24) {
      int total = sm[t] - base;
      if (rel == 0) rp_w[NPP] = total;
      else if (rel == 1) rp_c[NPP] = total;
      else rp_r[NA] = total;
    }
  }
}
__global__ __launch_bounds__(256) void scan_final(const int* __restrict__ degz,
                                                  const int* __restrict__ boff,
                                                  int* rp_w, int* rp_c, int* rp_r) {
  int blk = blockIdx.x, rel = blk / 25, t25 = blk % 25;
  const int* deg = degz + rel * NPP + t25 * 4096;
  int* rp = (rel == 0 ? rp_w : rel == 1 ? rp_c : rp_r) + t25 * 4096;
  int nrem = min(4096, NPP - t25 * 4096);
  int base = threadIdx.x * 16;
  bool ok = base < nrem;
  int v[16]; int s = 0;
  if (ok) {
#pragma unroll
    for (int i4 = 0; i4 < 4; ++i4) {
      int4 u = *(const int4*)(deg + base + i4 * 4);
      v[i4*4+0] = u.x; v[i4*4+1] = u.y; v[i4*4+2] = u.z; v[i4*4+3] = u.w;
      s += u.x + u.y + u.z + u.w;
    }
  }
  __shared__ int sm[256];
  sm[threadIdx.x] = s; __syncthreads();
  for (int o = 1; o < 256; o <<= 1) {
    int x = (threadIdx.x >= o) ? sm[threadIdx.x - o] : 0;
    __syncthreads(); sm[threadIdx.x] += x; __syncthreads();
  }
  int run = boff[blk] + sm[threadIdx.x] - s;
  if (ok) {
    int w[16];
#pragma unroll
    for (int i = 0; i < 16; ++i) { w[i] = run; run += v[i]; }
#pragma unroll
    for (int i4 = 0; i4 < 4; ++i4) *(int4*)(rp + base + i4 * 4) = *(const int4*)&w[i4*4];
  }
}

// -------- per-destination attention (no-max softmax: scores are O(1)) -----------
// 1 wave / node; lane holds dims {2l,2l+1}; head = lane>>4; one ushort4 gather
// per edge from the pair-interleaved kv [k0,v0,k1,v1,...]; 4/2/1 edge ladder
// keeps 4 independent gathers in flight. TWO: second relation (paper dst joins
// writes + cites in one softmax). Writes normalized bf16 agg into aggout (the
// q buffer: each wave reads its own q row before overwriting it).
static __device__ __forceinline__ void attn_seg(
    const int* __restrict__ rp, const int* __restrict__ col,
    const ushort_t* __restrict__ kv, float pr, int dst, int lane,
    float qx, float qy, float& z, float& ax, float& ay) {
  int e0 = rp[dst], e1 = rp[dst + 1];
  int j = e0;
  for (; j + 3 < e1; j += 4) {
    int s0 = col[j], s1 = col[j+1], s2 = col[j+2], s3 = col[j+3];
    ushort4 u0 = *(const ushort4*)(kv + (size_t)s0 * 256 + lane * 4);
    ushort4 u1 = *(const ushort4*)(kv + (size_t)s1 * 256 + lane * 4);
    ushort4 u2 = *(const ushort4*)(kv + (size_t)s2 * 256 + lane * 4);
    ushort4 u3 = *(const ushort4*)(kv + (size_t)s3 * 256 + lane * 4);
    float p0 = qx * bf2f(u0.x) + qy * bf2f(u0.z);
    float p1 = qx * bf2f(u1.x) + qy * bf2f(u1.z);
    float p2 = qx * bf2f(u2.x) + qy * bf2f(u2.z);
    float p3 = qx * bf2f(u3.x) + qy * bf2f(u3.z);
    p0 += __shfl_xor(p0, 1); p1 += __shfl_xor(p1, 1); p2 += __shfl_xor(p2, 1); p3 += __shfl_xor(p3, 1);
    p0 += __shfl_xor(p0, 2); p1 += __shfl_xor(p1, 2); p2 += __shfl_xor(p2, 2); p3 += __shfl_xor(p3, 2);
    p0 += __shfl_xor(p0, 4); p1 += __shfl_xor(p1, 4); p2 += __shfl_xor(p2, 4); p3 += __shfl_xor(p3, 4);
    p0 += __shfl_xor(p0, 8); p1 += __shfl_xor(p1, 8); p2 += __shfl_xor(p2, 8); p3 += __shfl_xor(p3, 8);
    float e0v = __expf(p0 * pr), e1v = __expf(p1 * pr);
    float e2v = __expf(p2 * pr), e3v = __expf(p3 * pr);
    z  += (e0v + e1v) + (e2v + e3v);
    ax += e0v * bf2f(u0.y) + e1v * bf2f(u1.y) + e2v * bf2f(u2.y) + e3v * bf2f(u3.y);
    ay += e0v * bf2f(u0.w) + e1v * bf2f(u1.w) + e2v * bf2f(u2.w) + e3v * bf2f(u3.w);
  }
  if (j + 1 < e1) {
    int s0 = col[j], s1 = col[j+1];
    ushort4 u0 = *(const ushort4*)(kv + (size_t)s0 * 256 + lane * 4);
    ushort4 u1 = *(const ushort4*)(kv + (size_t)s1 * 256 + lane * 4);
    float p0 = qx * bf2f(u0.x) + qy * bf2f(u0.z);
    float p1 = qx * bf2f(u1.x) + qy * bf2f(u1.z);
    p0 += __shfl_xor(p0, 1); p1 += __shfl_xor(p1, 1);
    p0 += __shfl_xor(p0, 2); p1 += __shfl_xor(p1, 2);
    p0 += __shfl_xor(p0, 4); p1 += __shfl_xor(p1, 4);
    p0 += __shfl_xor(p0, 8); p1 += __shfl_xor(p1, 8);
    float e0v = __expf(p0 * pr), e1v = __expf(p1 * pr);
    z  += e0v + e1v;
    ax += e0v * bf2f(u0.y) + e1v * bf2f(u1.y);
    ay += e0v * bf2f(u0.w) + e1v * bf2f(u1.w);
    j += 2;
  }
  if (j < e1) {
    int s0 = col[j];
    ushort4 u0 = *(const ushort4*)(kv + (size_t)s0 * 256 + lane * 4);
    float p0 = qx * bf2f(u0.x) + qy * bf2f(u0.z);
    p0 += __shfl_xor(p0, 1);
    p0 += __shfl_xor(p0, 2);
    p0 += __shfl_xor(p0, 4);
    p0 += __shfl_xor(p0, 8);
    float e0v = __expf(p0 * pr);
    z  += e0v;
    ax += e0v * bf2f(u0.y);
    ay += e0v * bf2f(u0.w);
  }
}

template<bool TWO>
__global__ __launch_bounds__(256, 8) void attn4(
    const int* __restrict__ rp1, const int* __restrict__ col1,
    const ushort_t* __restrict__ kv1,
    const int* __restrict__ rp2, const int* __restrict__ col2,
    const ushort_t* __restrict__ kv2,
    const ushort_t* __restrict__ q,
    const float* __restrict__ prel1, const float* __restrict__ prel2,
    int ndst, ushort_t* __restrict__ aggout) {
  int dst  = blockIdx.x * 4 + (threadIdx.x >> 6);
  int lane = threadIdx.x & 63;
  if (dst >= ndst) return;
  int head = lane >> 4;
  const float scale = 0.17677669529663688f; // 1/sqrt(32)
  float pr1 = prel1[head] * scale;
  ushort2 qv = *(const ushort2*)(q + (size_t)dst * D + lane * 2);
  float qx = bf2f(qv.x), qy = bf2f(qv.y);
  float z = 0.f, ax = 0.f, ay = 0.f;
  attn_seg(rp1, col1, kv1, pr1, dst, lane, qx, qy, z, ax, ay);
  if (TWO) {
    float pr2 = prel2[head] * scale;
    attn_seg(rp2, col2, kv2, pr2, dst, lane, qx, qy, z, ax, ay);
  }
  float inv = 1.f / (z + 1e-16f);
  ushort2 o;
  o.x = f2bf(ax * inv);
  o.y = f2bf(ay * inv);
  *(ushort2*)(aggout + (size_t)dst * D + lane * 2) = o;
}

extern "C" void kernel_launch(void* const* d_in, const int* in_sizes, int n_in,
                              void* d_out, int out_size, void* d_ws, size_t ws_size,
                              hipStream_t stream) {
  const float* x_a    = (const float*)d_in[0];
  const float* x_p    = (const float*)d_in[1];
  const int*   ei_w   = (const int*)d_in[2];
  const int*   ei_r   = (const int*)d_in[3];
  const int*   ei_c   = (const int*)d_in[4];
  const float* proj_w = (const float*)d_in[5];
  const float* proj_b = (const float*)d_in[6];
  const float* kqv_w  = (const float*)d_in[7];
  const float* kqv_b  = (const float*)d_in[8];
  const float* out_w  = (const float*)d_in[9];
  const float* out_b  = (const float*)d_in[10];
  const float* rel_a  = (const float*)d_in[11];
  const float* rel_m  = (const float*)d_in[12];
  const float* p_rel  = (const float*)d_in[13];
  const float* skip   = (const float*)d_in[14];
  const float* cls_w  = (const float*)d_in[15];
  const float* cls_b  = (const float*)d_in[16];
  float* out = (float*)d_out;

  const size_t NF = (size_t)NA * D;   // 12.8M
  float* ws    = (float*)d_ws;
  // fp32 region
  float* cw    = ws;                             // 12*D*D
  float* cb    = cw + 12 * D * D;                // 12*D
  // bf16 region
  ushort_t* h_a   = (ushort_t*)(cb + 12 * D);    // NF
  ushort_t* h_p   = h_a + NF;                    // NF
  ushort_t* b_q   = h_p + NF;                    // NF (q, then bf16 agg)
  ushort_t* b_kv  = b_q + NF;                    // 2*NF pair-interleaved
  ushort_t* b_kv2 = b_kv + 2 * NF;               // 2*NF (writes-relation kv)
  ushort_t* phi   = b_kv2 + 2 * NF;              // 23*SLOT_ELEMS
  ushort_t* plo   = phi + (size_t)NSLOT * SLOT_ELEMS;
  // int region
  int* ip    = (int*)(plo + (size_t)NSLOT * SLOT_ELEMS);
  int* rp_w  = ip;                      // NPP+1
  int* rp_c  = rp_w + (NPP + 1);
  int* rp_r  = rp_c + (NPP + 1);
  int* degz  = rp_r + (NA + 1);         // 3*NPP deg + 3*NPP cnt (contiguous)
  int* cntz  = degz + 3 * NPP;
  int* colz  = cntz + 3 * NPP;          // 3*E (src-node per CSR entry)
  int* bsum  = colz + 3 * E;            // 75
  int* boff  = bsum + 128;              // 75
  size_t need_bytes = (size_t)((char*)(boff + 128) - (char*)d_ws);
  if (ws_size < need_bytes) return;

  hipMemsetAsync(degz, 0, sizeof(int) * 6 * (size_t)NPP, stream);

  count3<<<dim3(256, 3), 256, 0, stream>>>(ei_w, ei_c, ei_r, degz);
  scan_partial<<<75, 256, 0, stream>>>(degz, bsum);
  scan_offsets<<<1, 128, 0, stream>>>(bsum, boff, rp_w, rp_c, rp_r);
  scan_final<<<75, 256, 0, stream>>>(degz, boff, rp_w, rp_c, rp_r);
  fill3<<<dim3(256, 3), 256, 0, stream>>>(ei_w, ei_c, ei_r, rp_w, rp_c, rp_r, cntz, colz);
  int* col_w = colz;
  int* col_c = colz + E;
  int* col_r = colz + 2 * E;

  combine_w<<<12, 256, 0, stream>>>(kqv_w, kqv_b, rel_a, rel_m, cw, cb);
  pack_b<<<NSLOT, 256, 0, stream>>>(proj_w, kqv_w, out_w, cls_w, cw, phi, plo);

  auto PH = [&](int s){ return phi + (size_t)s * SLOT_ELEMS; };
  auto PL = [&](int s){ return plo + (size_t)s * SLOT_ELEMS; };

  const int GB2 = (NA + 127) / 128;    // 782
  const dim3 G1(GB2, 1), GKV(GB2, 2);
  // initial projections (fp32 input, bf16 h out, A+B split for precision)
  gemm4<8, 128, 1, false, false, true, float><<<G1, 256, 0, stream>>>(
      x_a, PH(0), PL(0), proj_b,     h_a, nullptr, NA);
  gemm4<8, 128, 1, false, false, true, float><<<G1, 256, 0, stream>>>(
      x_p, PH(1), PL(1), proj_b + D, h_p, nullptr, NPP);

  for (int l = 0; l < L; ++l) {
    const int SQA = 2 + l * 10 + 0, SQP = 2 + l * 10 + 1;
    auto SKV = [&](int r){ return 2 + l * 10 + 2 + r * 2; };  // k slot; v slot = +1
    const int SO0 = 2 + l * 10 + 8, SO1 = 2 + l * 10 + 9;
    const float* bq_a = kqv_b + ((size_t)((l*3 + 1)*2 + 0)) * D;
    const float* bq_p = kqv_b + ((size_t)((l*3 + 1)*2 + 1)) * D;
    auto CB2 = [&](int r){ return cb + ((size_t)((l*R + r)*2)) * D; };  // 256 floats (k|v)
    const float* prelW = p_rel + (size_t)(l*R + 0) * H;
    const float* prelR = p_rel + (size_t)(l*R + 1) * H;
    const float* prelC = p_rel + (size_t)(l*R + 2) * H;

    // ---- author destination (rev_writes r=1, src=paper) ----
    gemm4<8, 128, 1, false, false, false, ushort_t><<<G1, 256, 0, stream>>>(
        h_a, PH(SQA), PL(SQA), bq_a, b_q, nullptr, NA);
    gemm_kv<<<GKV, 256, 0, stream>>>(
        h_p, PH(SKV(1)), PL(SKV(1)), CB2(1), b_kv, NPP);
    attn4<false><<<(NA + 3) / 4, 256, 0, stream>>>(
        rp_r, col_r, b_kv, nullptr, nullptr, nullptr,
        b_q, prelR, prelR, NA, b_q);
    // writes-relation K/V from OLD h_a (before author update) into b_kv2
    gemm_kv<<<GKV, 256, 0, stream>>>(
        h_a, PH(SKV(0)), PL(SKV(0)), CB2(0), b_kv2, NA);
    // author out-mix (in-place bf16 h_a); A = bf16 agg in b_q, gelu applied
    gemm4<8, 128, 1, true, true, false, ushort_t><<<G1, 256, 0, stream>>>(
        b_q, PH(SO0), PL(SO0), out_b + (size_t)(l*2 + 0) * D, h_a,
        skip + l*2 + 0, NA);

    // ---- paper destination: joint softmax over writes(r=0) + cites(r=2) ----
    gemm4<8, 128, 1, false, false, false, ushort_t><<<G1, 256, 0, stream>>>(
        h_p, PH(SQP), PL(SQP), bq_p, b_q, nullptr, NPP);
    gemm_kv<<<GKV, 256, 0, stream>>>(
        h_p, PH(SKV(2)), PL(SKV(2)), CB2(2), b_kv, NPP);
    attn4<true><<<(NPP + 3) / 4, 256, 0, stream>>>(
        rp_w, col_w, b_kv2, rp_c, col_c, b_kv,
        b_q, prelW, prelC, NPP, b_q);
    gemm4<8, 128, 1, true, true, false, ushort_t><<<G1, 256, 0, stream>>>(
        b_q, PH(SO1), PL(SO1), out_b + (size_t)(l*2 + 1) * D, h_p,
        skip + l*2 + 1, NPP);
  }

  gemm4<3, 40, 0, false, false, true, ushort_t><<<G1, 256, 0, stream>>>(
      h_p, PH(22), PL(22), cls_b, out, nullptr, NPP);
}

// Round 11
// 903.239 us; speedup vs baseline: 1.4553x; 1.0312x over previous
//
#include <hip/hip_runtime.h>
#include <hip/hip_bf16.h>
#include <math.h>

constexpr int NA  = 100000;
constexpr int NPP = 100000;
constexpr int D   = 128;
constexpr int H   = 4;
constexpr int E   = 400000;
constexpr int R   = 3;
constexpr int L   = 2;
constexpr int NSLOT = 23;
constexpr int SLOT_ELEMS = 8 * 4 * 512;   // 8 col-tiles * 4 ksteps * 512 bf16

using s8v = __attribute__((ext_vector_type(8))) short;
using f4v = __attribute__((ext_vector_type(4))) float;
typedef unsigned short ushort_t;

static __device__ __forceinline__ unsigned short f2bf(float f) {
  unsigned u = __float_as_uint(f);
  return (unsigned short)((u + 0x7fffu + ((u >> 16) & 1u)) >> 16);
}
static __device__ __forceinline__ float bf2f(unsigned short s) {
  return __uint_as_float(((unsigned)s) << 16);
}
static __device__ __forceinline__ float klo(int i) {        // low bf16 -> f32
  return __uint_as_float(((unsigned)i) << 16);
}
static __device__ __forceinline__ float vhi(int i) {        // high bf16 -> f32
  return __uint_as_float(((unsigned)i) & 0xffff0000u);
}
static __device__ __forceinline__ float gelu_f(float x) {
  return 0.5f * x * (1.0f + erff(x * 0.70710678118654752f));
}
static __device__ __forceinline__ float elu_f(float x) {
  return x > 0.0f ? x : expm1f(x);
}

// =============== LDS-staged MFMA GEMM: C = act(A[M,128]) @ B + bias =============
// block = 256 thr = 4 waves; wave computes 32 rows (2 frags) x NT16*16 cols.
// B staged in LDS once per block; fragments via ds_read_b128.
// A fragment: lane l -> row = l&15, k(i) = 4*(l>>4) + (i&3) + 16*(i>>2) + 32*ks.
// B packed in the SAME k-order -> any hw k-permutation cancels.
// C/D layout (m89-verified): col = lane&15, row = (lane>>4)*4 + reg.
// BLO: include B-lo correction MFMAs (near-fp32 weights). TA=float also splits A.
// STORE: 0 = fp32 out, 1 = bf16 out. MIX: bf16 h residual read-modify-write.
template<int NT16, int NCOLS, int STORE, bool GELU_A, bool MIX, bool BLO, typename TA>
__global__ __launch_bounds__(256, 4) void gemm4(
    const TA* __restrict__ A,
    const ushort_t* __restrict__ Bhi, const ushort_t* __restrict__ Blo,
    const float* __restrict__ bias, void* __restrict__ Cv,
    const float* __restrict__ skip_ptr, int M) {
  constexpr int HN = NT16 * 2048;          // ushorts per (hi) half
  __shared__ ushort_t Bs[HN * (BLO ? 2 : 1)];
  constexpr bool AFP32 = sizeof(TA) == 4;

  for (int i = threadIdx.x; i < (HN / 8) * (BLO ? 2 : 1); i += 256) {
    int half = i / (HN / 8), j = i % (HN / 8);
    const ushort_t* src = (half ? Blo : Bhi) + (size_t)j * 8;
    *(s8v*)&Bs[half * HN + j * 8] = *(const s8v*)src;
  }
  __syncthreads();

  const int lane = threadIdx.x & 63;
  const int wave = threadIdx.x >> 6;
  const int row0 = blockIdx.x * 128 + wave * 32;
  const int g = lane >> 4, li = lane & 15;

  f4v acc0[NT16], acc1[NT16];
#pragma unroll
  for (int ct = 0; ct < NT16; ++ct) {
    acc0[ct] = f4v{0.f, 0.f, 0.f, 0.f};
    acc1[ct] = f4v{0.f, 0.f, 0.f, 0.f};
  }

  int ar0 = row0 + li;       if (ar0 >= M) ar0 = M - 1;
  int ar1 = row0 + 16 + li;  if (ar1 >= M) ar1 = M - 1;

#pragma unroll
  for (int ks = 0; ks < 4; ++ks) {
    s8v ahi[2], alo[2];
#pragma unroll
    for (int rf = 0; rf < 2; ++rf) {
      int ar = rf ? ar1 : ar0;
      if constexpr (AFP32) {
        const float* ap = (const float*)A + (size_t)ar * 128 + ks * 32 + g * 4;
        float4 u0 = *(const float4*)ap;
        float4 u1 = *(const float4*)(ap + 16);
        float x[8] = {u0.x, u0.y, u0.z, u0.w, u1.x, u1.y, u1.z, u1.w};
#pragma unroll
        for (int i = 0; i < 8; ++i) {
          float v = GELU_A ? gelu_f(x[i]) : x[i];
          unsigned short h = f2bf(v);
          ahi[rf][i] = (short)h;
          alo[rf][i] = (short)f2bf(v - bf2f(h));
        }
      } else {
        const ushort_t* ap = (const ushort_t*)A + (size_t)ar * 128 + ks * 32 + g * 4;
        ushort4 u0 = *(const ushort4*)ap;
        ushort4 u1 = *(const ushort4*)(ap + 16);
        ushort_t uu[8] = {u0.x, u0.y, u0.z, u0.w, u1.x, u1.y, u1.z, u1.w};
#pragma unroll
        for (int i = 0; i < 8; ++i) {
          if (GELU_A) ahi[rf][i] = (short)f2bf(gelu_f(bf2f(uu[i])));
          else        ahi[rf][i] = (short)uu[i];
        }
      }
    }
#pragma unroll
    for (int ct = 0; ct < NT16; ++ct) {
      const ushort_t* bp = &Bs[(ct * 4 + ks) * 512 + lane * 8];
      s8v bhi = *(const s8v*)bp;
      acc0[ct] = __builtin_amdgcn_mfma_f32_16x16x32_bf16(ahi[0], bhi, acc0[ct], 0, 0, 0);
      acc1[ct] = __builtin_amdgcn_mfma_f32_16x16x32_bf16(ahi[1], bhi, acc1[ct], 0, 0, 0);
      if constexpr (BLO) {
        s8v blo = *(const s8v*)(bp + HN);
        if constexpr (AFP32) {
          acc0[ct] = __builtin_amdgcn_mfma_f32_16x16x32_bf16(alo[0], bhi, acc0[ct], 0, 0, 0);
          acc1[ct] = __builtin_amdgcn_mfma_f32_16x16x32_bf16(alo[1], bhi, acc1[ct], 0, 0, 0);
        }
        acc0[ct] = __builtin_amdgcn_mfma_f32_16x16x32_bf16(ahi[0], blo, acc0[ct], 0, 0, 0);
        acc1[ct] = __builtin_amdgcn_mfma_f32_16x16x32_bf16(ahi[1], blo, acc1[ct], 0, 0, 0);
      }
    }
  }

  float sskip = 0.f;
  if (MIX) sskip = 1.f / (1.f + __expf(-*skip_ptr));
#pragma unroll
  for (int rf = 0; rf < 2; ++rf) {
#pragma unroll
    for (int ct = 0; ct < NT16; ++ct) {
      int col = ct * 16 + li;
      bool colok = (col < NCOLS);
      float bv = colok ? bias[col] : 0.f;
      f4v a = rf ? acc1[ct] : acc0[ct];
#pragma unroll
      for (int r = 0; r < 4; ++r) {
        int grow = row0 + rf * 16 + g * 4 + r;
        if (grow < M && colok) {
          float v = a[r] + bv;
          size_t off = (size_t)grow * NCOLS + col;
          if constexpr (MIX) {            // bf16 h residual
            ushort_t* Cp = (ushort_t*)Cv;
            float hprev = bf2f(Cp[off]);
            Cp[off] = f2bf(elu_f(sskip * v + (1.f - sskip) * hprev));
          } else if constexpr (STORE == 1) {
            ((ushort_t*)Cv)[off] = f2bf(v);
          } else {
            ((float*)Cv)[off] = v;
          }
        }
      }
    }
  }
}

// ============ KV GEMM: LDS-staged, column-half split, pair-interleaved store ====
__global__ __launch_bounds__(256, 4) void gemm_kv(
    const ushort_t* __restrict__ A,
    const ushort_t* __restrict__ Bhi, const ushort_t* __restrict__ Blo,
    const float* __restrict__ bias, ushort_t* __restrict__ kvout, int M) {
  __shared__ ushort_t Bs[16384];           // [kv][t][ks][512]
  const int ch = blockIdx.y;
  for (int i = threadIdx.x; i < 2048; i += 256) {
    int kvh = i >> 10, j = i & 1023;
    const ushort_t* src = Bhi + (size_t)kvh * SLOT_ELEMS + ch * 8192 + j * 8;
    *(s8v*)&Bs[kvh * 8192 + j * 8] = *(const s8v*)src;
  }
  __syncthreads();

  const int lane = threadIdx.x & 63;
  const int wave = threadIdx.x >> 6;
  const int row0 = blockIdx.x * 128 + wave * 32;
  const int g = lane >> 4, li = lane & 15;

  f4v acc0[8], acc1[8];                    // [0..3]=K, [4..7]=V
#pragma unroll
  for (int t = 0; t < 8; ++t) {
    acc0[t] = f4v{0.f, 0.f, 0.f, 0.f};
    acc1[t] = f4v{0.f, 0.f, 0.f, 0.f};
  }

  int ar0 = row0 + li;       if (ar0 >= M) ar0 = M - 1;
  int ar1 = row0 + 16 + li;  if (ar1 >= M) ar1 = M - 1;

#pragma unroll
  for (int ks = 0; ks < 4; ++ks) {
    s8v a0, a1;
    {
      const ushort_t* ap = A + (size_t)ar0 * 128 + ks * 32 + g * 4;
      ushort4 u0 = *(const ushort4*)ap;
      ushort4 u1 = *(const ushort4*)(ap + 16);
      a0[0] = (short)u0.x; a0[1] = (short)u0.y; a0[2] = (short)u0.z; a0[3] = (short)u0.w;
      a0[4] = (short)u1.x; a0[5] = (short)u1.y; a0[6] = (short)u1.z; a0[7] = (short)u1.w;
    }
    {
      const ushort_t* ap = A + (size_t)ar1 * 128 + ks * 32 + g * 4;
      ushort4 u0 = *(const ushort4*)ap;
      ushort4 u1 = *(const ushort4*)(ap + 16);
      a1[0] = (short)u0.x; a1[1] = (short)u0.y; a1[2] = (short)u0.z; a1[3] = (short)u0.w;
      a1[4] = (short)u1.x; a1[5] = (short)u1.y; a1[6] = (short)u1.z; a1[7] = (short)u1.w;
    }
#pragma unroll
    for (int t = 0; t < 4; ++t) {
      s8v kh = *(const s8v*)&Bs[(t * 4 + ks) * 512 + lane * 8];
      acc0[t] = __builtin_amdgcn_mfma_f32_16x16x32_bf16(a0, kh, acc0[t], 0, 0, 0);
      acc1[t] = __builtin_amdgcn_mfma_f32_16x16x32_bf16(a1, kh, acc1[t], 0, 0, 0);
      s8v vh = *(const s8v*)&Bs[8192 + (t * 4 + ks) * 512 + lane * 8];
      acc0[4 + t] = __builtin_amdgcn_mfma_f32_16x16x32_bf16(a0, vh, acc0[4 + t], 0, 0, 0);
      acc1[4 + t] = __builtin_amdgcn_mfma_f32_16x16x32_bf16(a1, vh, acc1[4 + t], 0, 0, 0);
    }
  }

#pragma unroll
  for (int rf = 0; rf < 2; ++rf) {
#pragma unroll
    for (int t = 0; t < 4; ++t) {
      int col = ch * 64 + t * 16 + li;
      float bk = bias[col], bv = bias[128 + col];
#pragma unroll
      for (int r = 0; r < 4; ++r) {
        int grow = row0 + rf * 16 + g * 4 + r;
        if (grow < M) {
          float kvl = rf ? acc1[t][r] : acc0[t][r];
          float vvl = rf ? acc1[4 + t][r] : acc0[4 + t][r];
          ushort2 o;
          o.x = f2bf(kvl + bk);
          o.y = f2bf(vvl + bv);
          *(ushort2*)(kvout + (size_t)grow * 256 + 2 * col) = o;
        }
      }
    }
  }
}

// ------------- combined weights: cw = W @ blockdiag(rel), cb = b @ blockdiag(rel)
__global__ __launch_bounds__(256) void combine_w(
    const float* __restrict__ kqv_w, const float* __restrict__ kqv_b,
    const float* __restrict__ rel_a, const float* __restrict__ rel_m,
    float* __restrict__ cw, float* __restrict__ cb) {
  int b  = blockIdx.x;            // ((l*R)+r)*2+kv
  int kv = b & 1;
  int r  = (b >> 1) % R;
  int l  = b / (2 * R);
  int t_src = (r == 0) ? 0 : 1;
  int i_w   = (kv == 0) ? 0 : 2;
  const float* W    = kqv_w + ((size_t)((l*3 + i_w)*2 + t_src)) * D * D;
  const float* bvec = kqv_b + ((size_t)((l*3 + i_w)*2 + t_src)) * D;
  const float* rel  = ((kv == 0) ? rel_a : rel_m) + ((size_t)(l*R + r)) * H * 32 * 32;
  float* Cout = cw + (size_t)b * D * D;
  float* cbo  = cb + (size_t)b * D;
  for (int idx = threadIdx.x; idx < D * D; idx += 256) {
    int i = idx / D, j = idx % D;
    int h = j >> 5, f = j & 31;
    const float* relh = rel + h * 32 * 32;
    float sum = 0.f;
#pragma unroll
    for (int d = 0; d < 32; ++d) sum += W[i*D + (h*32 + d)] * relh[d*32 + f];
    Cout[idx] = sum;
  }
  if (threadIdx.x < D) {
    int j = threadIdx.x;
    int h = j >> 5, f = j & 31;
    const float* relh = rel + h * 32 * 32;
    float sum = 0.f;
#pragma unroll
    for (int d = 0; d < 32; ++d) sum += bvec[h*32 + d] * relh[d*32 + f];
    cbo[j] = sum;
  }
}

// ------------- pack weight matrices into MFMA-fragment order (hi/lo split) -------
__global__ __launch_bounds__(256) void pack_b(
    const float* __restrict__ proj_w, const float* __restrict__ kqv_w,
    const float* __restrict__ out_w, const float* __restrict__ cls_w,
    const float* __restrict__ cw,
    ushort_t* __restrict__ phi, ushort_t* __restrict__ plo) {
  int slot = blockIdx.x;
  const float* src; int ncol = 128;
  if (slot == 0) src = proj_w;
  else if (slot == 1) src = proj_w + D * D;
  else if (slot == 22) { src = cls_w; ncol = 40; }
  else {
    int l = (slot - 2) / 10, k = (slot - 2) % 10;
    if (k == 0)      src = kqv_w + ((size_t)((l*3 + 1)*2 + 0)) * D * D;
    else if (k == 1) src = kqv_w + ((size_t)((l*3 + 1)*2 + 1)) * D * D;
    else if (k < 8)  { int idx = k - 2; src = cw + ((size_t)((l*R)*2 + idx)) * D * D; }
    else             src = out_w + ((size_t)(l*2 + (k - 8))) * D * D;
  }
  int nt = (ncol + 15) / 16;
  int total = nt * 4 * 512;
  ushort_t* ph = phi + (size_t)slot * SLOT_ELEMS;
  ushort_t* pl = plo + (size_t)slot * SLOT_ELEMS;
  for (int idx = threadIdx.x; idx < total; idx += 256) {
    int j = idx & 7, lane = (idx >> 3) & 63, ks = (idx >> 9) & 3, ct = idx >> 11;
    int k = 4 * (lane >> 4) + (j & 3) + 16 * (j >> 2) + 32 * ks;
    int n = ct * 16 + (lane & 15);
    float v = (n < ncol) ? src[(size_t)k * ncol + n] : 0.f;
    unsigned short h = f2bf(v);
    ph[idx] = h;
    pl[idx] = f2bf(v - bf2f(h));
  }
}

// ---------------- CSR build (global-atomic; measured best at this size) ---------
__global__ void count3(const int* __restrict__ ei_w, const int* __restrict__ ei_c,
                       const int* __restrict__ ei_r, int* __restrict__ degz) {
  const int* dst = blockIdx.y == 0 ? ei_w + E : blockIdx.y == 1 ? ei_c + E : ei_r + E;
  int* deg = degz + blockIdx.y * NPP;
  for (int e = blockIdx.x * blockDim.x + threadIdx.x; e < E; e += gridDim.x * blockDim.x)
    atomicAdd(&deg[dst[e]], 1);
}
__global__ void fill3(const int* __restrict__ ei_w, const int* __restrict__ ei_c,
                      const int* __restrict__ ei_r,
                      const int* __restrict__ rp_w, const int* __restrict__ rp_c,
                      const int* __restrict__ rp_r,
                      int* __restrict__ cntz, int* __restrict__ colz) {
  int rel = blockIdx.y;
  const int* ei = rel == 0 ? ei_w : rel == 1 ? ei_c : ei_r;
  const int* dst = ei + E;
  const int* rp  = rel == 0 ? rp_w : rel == 1 ? rp_c : rp_r;
  int* cnt = cntz + rel * NPP;
  int* col = colz + rel * E;
  for (int e = blockIdx.x * blockDim.x + threadIdx.x; e < E; e += gridDim.x * blockDim.x) {
    int d = dst[e];
    int pos = atomicAdd(&cnt[d], 1);
    col[rp[d] + pos] = ei[e];          // store SOURCE node directly
  }
}

// 3-phase exclusive scan over three 100000-length deg arrays (contiguous)
__global__ __launch_bounds__(256) void scan_partial(const int* __restrict__ degz,
                                                    int* __restrict__ bsum) {
  int blk = blockIdx.x, rel = blk / 25, t25 = blk % 25;
  const int* deg = degz + rel * NPP + t25 * 4096;
  int nrem = min(4096, NPP - t25 * 4096);
  int base = threadIdx.x * 16;
  int s = 0;
  if (base < nrem) {
#pragma unroll
    for (int i4 = 0; i4 < 4; ++i4) {
      int4 v = *(const int4*)(deg + base + i4 * 4);
      s += v.x + v.y + v.z + v.w;
    }
  }
  __shared__ int sm[256];
  sm[threadIdx.x] = s; __syncthreads();
  for (int o = 128; o > 0; o >>= 1) {
    if (threadIdx.x < o) sm[threadIdx.x] += sm[threadIdx.x + o];
    __syncthreads();
  }
  if (threadIdx.x == 0) bsum[blk] = sm[0];
}
__global__ __launch_bounds__(128) void scan_offsets(const int* __restrict__ bsum,
                                                    int* __restrict__ boff,
                                                    int* rp_w, int* rp_c, int* rp_r) {
  __shared__ int sm[128];
  int t = threadIdx.x;
  sm[t] = (t < 75) ? bsum[t] : 0;
  __syncthreads();
  for (int o = 1; o < 128; o <<= 1) {
    int v = (t >= o) ? sm[t - o] : 0;
    __syncthreads(); sm[t] += v; __syncthreads();
  }
  if (t < 75) {
    int rel = t / 25;
    int base = rel ? sm[rel * 25 - 1] : 0;
    boff[t] = (t % 25 == 0) ? 0 : (sm[t - 1] - base);
    if (t % 25 == 24) {
      int total = sm[t] - base;
      if (rel == 0) rp_w[NPP] = total;
      else if (rel == 1) rp_c[NPP] = total;
      else rp_r[NA] = total;
    }
  }
}
__global__ __launch_bounds__(256) void scan_final(const int* __restrict__ degz,
                                                  const int* __restrict__ boff,
                                                  int* rp_w, int* rp_c, int* rp_r) {
  int blk = blockIdx.x, rel = blk / 25, t25 = blk % 25;
  const int* deg = degz + rel * NPP + t25 * 4096;
  int* rp = (rel == 0 ? rp_w : rel == 1 ? rp_c : rp_r) + t25 * 4096;
  int nrem = min(4096, NPP - t25 * 4096);
  int base = threadIdx.x * 16;
  bool ok = base < nrem;
  int v[16]; int s = 0;
  if (ok) {
#pragma unroll
    for (int i4 = 0; i4 < 4; ++i4) {
      int4 u = *(const int4*)(deg + base + i4 * 4);
      v[i4*4+0] = u.x; v[i4*4+1] = u.y; v[i4*4+2] = u.z; v[i4*4+3] = u.w;
      s += u.x + u.y + u.z + u.w;
    }
  }
  __shared__ int sm[256];
  sm[threadIdx.x] = s; __syncthreads();
  for (int o = 1; o < 256; o <<= 1) {
    int x = (threadIdx.x >= o) ? sm[threadIdx.x - o] : 0;
    __syncthreads(); sm[threadIdx.x] += x; __syncthreads();
  }
  int run = boff[blk] + sm[threadIdx.x] - s;
  if (ok) {
    int w[16];
#pragma unroll
    for (int i = 0; i < 16; ++i) { w[i] = run; run += v[i]; }
#pragma unroll
    for (int i4 = 0; i4 < 4; ++i4) *(int4*)(rp + base + i4 * 4) = *(const int4*)&w[i4*4];
  }
}

// -------- per-destination attention v5: 2 dst per wave (no-max softmax) ---------
// lanes 0-31 own dst0, lanes 32-63 own dst1 (independent latency chains).
// lane32 = lane&31 holds dims [4*lane32, 4*lane32+4); head = lane32>>3.
// One int4 (16B) gather per edge per lane from pair-interleaved kv
// [k0,v0,k1,v1,...]: int i -> k = lo16(i), v = hi16(i).
// 3-step shfl_xor reduce within 8-lane head groups (never crosses halves;
// e0/e1 uniform within each 8-lane group so divergence is shfl-safe).
// Writes normalized bf16 agg into aggout (the q buffer; wave reads its own
// q rows before overwriting them).
static __device__ __forceinline__ void attn_seg2(
    const int* __restrict__ rp, const int* __restrict__ col,
    const ushort_t* __restrict__ kv, float pr, int dst, int l32,
    float q0, float q1, float q2, float q3,
    float& z, float& a0, float& a1, float& a2, float& a3) {
  int e0 = rp[dst], e1 = rp[dst + 1];
  int j = e0;
  for (; j + 1 < e1; j += 2) {
    int s0 = col[j], s1 = col[j + 1];
    int4 u = *(const int4*)(kv + (size_t)s0 * 256 + l32 * 8);
    int4 w = *(const int4*)(kv + (size_t)s1 * 256 + l32 * 8);
    float p0 = q0 * klo(u.x) + q1 * klo(u.y) + q2 * klo(u.z) + q3 * klo(u.w);
    float p1 = q0 * klo(w.x) + q1 * klo(w.y) + q2 * klo(w.z) + q3 * klo(w.w);
    p0 += __shfl_xor(p0, 1); p1 += __shfl_xor(p1, 1);
    p0 += __shfl_xor(p0, 2); p1 += __shfl_xor(p1, 2);
    p0 += __shfl_xor(p0, 4); p1 += __shfl_xor(p1, 4);
    float ea = __expf(p0 * pr);
    float eb = __expf(p1 * pr);
    z  += ea + eb;
    a0 += ea * vhi(u.x) + eb * vhi(w.x);
    a1 += ea * vhi(u.y) + eb * vhi(w.y);
    a2 += ea * vhi(u.z) + eb * vhi(w.z);
    a3 += ea * vhi(u.w) + eb * vhi(w.w);
  }
  if (j < e1) {
    int s0 = col[j];
    int4 u = *(const int4*)(kv + (size_t)s0 * 256 + l32 * 8);
    float p0 = q0 * klo(u.x) + q1 * klo(u.y) + q2 * klo(u.z) + q3 * klo(u.w);
    p0 += __shfl_xor(p0, 1);
    p0 += __shfl_xor(p0, 2);
    p0 += __shfl_xor(p0, 4);
    float ea = __expf(p0 * pr);
    z  += ea;
    a0 += ea * vhi(u.x);
    a1 += ea * vhi(u.y);
    a2 += ea * vhi(u.z);
    a3 += ea * vhi(u.w);
  }
}

template<bool TWO>
__global__ __launch_bounds__(256, 8) void attn5(
    const int* __restrict__ rp1, const int* __restrict__ col1,
    const ushort_t* __restrict__ kv1,
    const int* __restrict__ rp2, const int* __restrict__ col2,
    const ushort_t* __restrict__ kv2,
    const ushort_t* __restrict__ q,
    const float* __restrict__ prel1, const float* __restrict__ prel2,
    int ndst, ushort_t* __restrict__ aggout) {
  int lane = threadIdx.x & 63;
  int wave = threadIdx.x >> 6;
  int half = lane >> 5;
  int l32  = lane & 31;
  int dst  = blockIdx.x * 8 + wave * 2 + half;   // ndst % 8 == 0: no tail
  int head = l32 >> 3;
  const float scale = 0.17677669529663688f; // 1/sqrt(32)
  float pr1 = prel1[head] * scale;
  ushort4 qv = *(const ushort4*)(q + (size_t)dst * D + l32 * 4);
  float q0 = bf2f(qv.x), q1 = bf2f(qv.y), q2 = bf2f(qv.z), q3 = bf2f(qv.w);
  float z = 0.f, a0 = 0.f, a1 = 0.f, a2 = 0.f, a3 = 0.f;
  attn_seg2(rp1, col1, kv1, pr1, dst, l32, q0, q1, q2, q3, z, a0, a1, a2, a3);
  if (TWO) {
    float pr2 = prel2[head] * scale;
    attn_seg2(rp2, col2, kv2, pr2, dst, l32, q0, q1, q2, q3, z, a0, a1, a2, a3);
  }
  float inv = 1.f / (z + 1e-16f);
  ushort4 o;
  o.x = f2bf(a0 * inv);
  o.y = f2bf(a1 * inv);
  o.z = f2bf(a2 * inv);
  o.w = f2bf(a3 * inv);
  *(ushort4*)(aggout + (size_t)dst * D + l32 * 4) = o;
}

extern "C" void kernel_launch(void* const* d_in, const int* in_sizes, int n_in,
                              void* d_out, int out_size, void* d_ws, size_t ws_size,
                              hipStream_t stream) {
  const float* x_a    = (const float*)d_in[0];
  const float* x_p    = (const float*)d_in[1];
  const int*   ei_w   = (const int*)d_in[2];
  const int*   ei_r   = (const int*)d_in[3];
  const int*   ei_c   = (const int*)d_in[4];
  const float* proj_w = (const float*)d_in[5];
  const float* proj_b = (const float*)d_in[6];
  const float* kqv_w  = (const float*)d_in[7];
  const float* kqv_b  = (const float*)d_in[8];
  const float* out_w  = (const float*)d_in[9];
  const float* out_b  = (const float*)d_in[10];
  const float* rel_a  = (const float*)d_in[11];
  const float* rel_m  = (const float*)d_in[12];
  const float* p_rel  = (const float*)d_in[13];
  const float* skip   = (const float*)d_in[14];
  const float* cls_w  = (const float*)d_in[15];
  const float* cls_b  = (const float*)d_in[16];
  float* out = (float*)d_out;

  const size_t NF = (size_t)NA * D;   // 12.8M
  float* ws    = (float*)d_ws;
  // fp32 region
  float* cw    = ws;                             // 12*D*D
  float* cb    = cw + 12 * D * D;                // 12*D
  // bf16 region
  ushort_t* h_a   = (ushort_t*)(cb + 12 * D);    // NF
  ushort_t* h_p   = h_a + NF;                    // NF
  ushort_t* b_q   = h_p + NF;                    // NF (q, then bf16 agg)
  ushort_t* b_kv  = b_q + NF;                    // 2*NF pair-interleaved
  ushort_t* b_kv2 = b_kv + 2 * NF;               // 2*NF (writes-relation kv)
  ushort_t* phi   = b_kv2 + 2 * NF;              // 23*SLOT_ELEMS
  ushort_t* plo   = phi + (size_t)NSLOT * SLOT_ELEMS;
  // int region
  int* ip    = (int*)(plo + (size_t)NSLOT * SLOT_ELEMS);
  int* rp_w  = ip;                      // NPP+1
  int* rp_c  = rp_w + (NPP + 1);
  int* rp_r  = rp_c + (NPP + 1);
  int* degz  = rp_r + (NA + 1);         // 3*NPP deg + 3*NPP cnt (contiguous)
  int* cntz  = degz + 3 * NPP;
  int* colz  = cntz + 3 * NPP;          // 3*E (src-node per CSR entry)
  int* bsum  = colz + 3 * E;            // 75
  int* boff  = bsum + 128;              // 75
  size_t need_bytes = (size_t)((char*)(boff + 128) - (char*)d_ws);
  if (ws_size < need_bytes) return;

  hipMemsetAsync(degz, 0, sizeof(int) * 6 * (size_t)NPP, stream);

  count3<<<dim3(256, 3), 256, 0, stream>>>(ei_w, ei_c, ei_r, degz);
  scan_partial<<<75, 256, 0, stream>>>(degz, bsum);
  scan_offsets<<<1, 128, 0, stream>>>(bsum, boff, rp_w, rp_c, rp_r);
  scan_final<<<75, 256, 0, stream>>>(degz, boff, rp_w, rp_c, rp_r);
  fill3<<<dim3(256, 3), 256, 0, stream>>>(ei_w, ei_c, ei_r, rp_w, rp_c, rp_r, cntz, colz);
  int* col_w = colz;
  int* col_c = colz + E;
  int* col_r = colz + 2 * E;

  combine_w<<<12, 256, 0, stream>>>(kqv_w, kqv_b, rel_a, rel_m, cw, cb);
  pack_b<<<NSLOT, 256, 0, stream>>>(proj_w, kqv_w, out_w, cls_w, cw, phi, plo);

  auto PH = [&](int s){ return phi + (size_t)s * SLOT_ELEMS; };
  auto PL = [&](int s){ return plo + (size_t)s * SLOT_ELEMS; };

  const int GB2 = (NA + 127) / 128;    // 782
  const int GA  = NA / 8;              // 12500 (NA % 8 == 0)
  const dim3 G1(GB2, 1), GKV(GB2, 2);
  // initial projections (fp32 input, bf16 h out, A+B split for precision)
  gemm4<8, 128, 1, false, false, true, float><<<G1, 256, 0, stream>>>(
      x_a, PH(0), PL(0), proj_b,     h_a, nullptr, NA);
  gemm4<8, 128, 1, false, false, true, float><<<G1, 256, 0, stream>>>(
      x_p, PH(1), PL(1), proj_b + D, h_p, nullptr, NPP);

  for (int l = 0; l < L; ++l) {
    const int SQA = 2 + l * 10 + 0, SQP = 2 + l * 10 + 1;
    auto SKV = [&](int r){ return 2 + l * 10 + 2 + r * 2; };  // k slot; v slot = +1
    const int SO0 = 2 + l * 10 + 8, SO1 = 2 + l * 10 + 9;
    const float* bq_a = kqv_b + ((size_t)((l*3 + 1)*2 + 0)) * D;
    const float* bq_p = kqv_b + ((size_t)((l*3 + 1)*2 + 1)) * D;
    auto CB2 = [&](int r){ return cb + ((size_t)((l*R + r)*2)) * D; };  // 256 floats (k|v)
    const float* prelW = p_rel + (size_t)(l*R + 0) * H;
    const float* prelR = p_rel + (size_t)(l*R + 1) * H;
    const float* prelC = p_rel + (size_t)(l*R + 2) * H;

    // ---- author destination (rev_writes r=1, src=paper) ----
    gemm4<8, 128, 1, false, false, false, ushort_t><<<G1, 256, 0, stream>>>(
        h_a, PH(SQA), PL(SQA), bq_a, b_q, nullptr, NA);
    gemm_kv<<<GKV, 256, 0, stream>>>(
        h_p, PH(SKV(1)), PL(SKV(1)), CB2(1), b_kv, NPP);
    attn5<false><<<GA, 256, 0, stream>>>(
        rp_r, col_r, b_kv, nullptr, nullptr, nullptr,
        b_q, prelR, prelR, NA, b_q);
    // writes-relation K/V from OLD h_a (before author update) into b_kv2
    gemm_kv<<<GKV, 256, 0, stream>>>(
        h_a, PH(SKV(0)), PL(SKV(0)), CB2(0), b_kv2, NA);
    // author out-mix (in-place bf16 h_a); A = bf16 agg in b_q, gelu applied
    gemm4<8, 128, 1, true, true, false, ushort_t><<<G1, 256, 0, stream>>>(
        b_q, PH(SO0), PL(SO0), out_b + (size_t)(l*2 + 0) * D, h_a,
        skip + l*2 + 0, NA);

    // ---- paper destination: joint softmax over writes(r=0) + cites(r=2) ----
    gemm4<8, 128, 1, false, false, false, ushort_t><<<G1, 256, 0, stream>>>(
        h_p, PH(SQP), PL(SQP), bq_p, b_q, nullptr, NPP);
    gemm_kv<<<GKV, 256, 0, stream>>>(
        h_p, PH(SKV(2)), PL(SKV(2)), CB2(2), b_kv, NPP);
    attn5<true><<<GA, 256, 0, stream>>>(
        rp_w, col_w, b_kv2, rp_c, col_c, b_kv,
        b_q, prelW, prelC, NPP, b_q);
    gemm4<8, 128, 1, true, true, false, ushort_t><<<G1, 256, 0, stream>>>(
        b_q, PH(SO1), PL(SO1), out_b + (size_t)(l*2 + 1) * D, h_p,
        skip + l*2 + 1, NPP);
  }

  gemm4<3, 40, 0, false, false, true, ushort_t><<<G1, 256, 0, stream>>>(
      h_p, PH(22), PL(22), cls_b, out, nullptr, NPP);
}

// Round 12
// 895.322 us; speedup vs baseline: 1.4682x; 1.0088x over previous
//
#include <hip/hip_runtime.h>
#include <hip/hip_bf16.h>
#include <math.h>

constexpr int NA  = 100000;
constexpr int NPP = 100000;
constexpr int D   = 128;
constexpr int H   = 4;
constexpr int E   = 400000;
constexpr int R   = 3;
constexpr int L   = 2;
constexpr int NSLOT = 23;
constexpr int SLOT_ELEMS = 8 * 4 * 512;   // 8 col-tiles * 4 ksteps * 512 bf16

using s8v = __attribute__((ext_vector_type(8))) short;
using f4v = __attribute__((ext_vector_type(4))) float;
typedef unsigned short ushort_t;

static __device__ __forceinline__ unsigned short f2bf(float f) {
  unsigned u = __float_as_uint(f);
  return (unsigned short)((u + 0x7fffu + ((u >> 16) & 1u)) >> 16);
}
static __device__ __forceinline__ float bf2f(unsigned short s) {
  return __uint_as_float(((unsigned)s) << 16);
}
static __device__ __forceinline__ float klo(int i) {        // low bf16 -> f32
  return __uint_as_float(((unsigned)i) << 16);
}
static __device__ __forceinline__ float vhi(int i) {        // high bf16 -> f32
  return __uint_as_float(((unsigned)i) & 0xffff0000u);
}
static __device__ __forceinline__ float gelu_f(float x) {
  return 0.5f * x * (1.0f + erff(x * 0.70710678118654752f));
}
static __device__ __forceinline__ float elu_f(float x) {
  return x > 0.0f ? x : expm1f(x);
}

// =============== LDS-staged MFMA GEMM: C = act(A[M,128]) @ B + bias =============
// block = 256 thr = 4 waves; wave computes 32 rows (2 frags) x NT16*16 cols.
// B staged in LDS once per block; fragments via ds_read_b128.
// A fragment: lane l -> row = l&15, k(i) = 4*(l>>4) + (i&3) + 16*(i>>2) + 32*ks.
// B packed in the SAME k-order -> any hw k-permutation cancels.
// C/D layout (m89-verified): col = lane&15, row = (lane>>4)*4 + reg.
// BLO: include B-lo correction MFMAs (near-fp32 weights). TA=float also splits A.
// STORE: 0 = fp32 out, 1 = bf16 out. MIX: bf16 h residual read-modify-write.
template<int NT16, int NCOLS, int STORE, bool GELU_A, bool MIX, bool BLO, typename TA>
__global__ __launch_bounds__(256, 4) void gemm4(
    const TA* __restrict__ A,
    const ushort_t* __restrict__ Bhi, const ushort_t* __restrict__ Blo,
    const float* __restrict__ bias, void* __restrict__ Cv,
    const float* __restrict__ skip_ptr, int M) {
  constexpr int HN = NT16 * 2048;          // ushorts per (hi) half
  __shared__ ushort_t Bs[HN * (BLO ? 2 : 1)];
  constexpr bool AFP32 = sizeof(TA) == 4;

  for (int i = threadIdx.x; i < (HN / 8) * (BLO ? 2 : 1); i += 256) {
    int half = i / (HN / 8), j = i % (HN / 8);
    const ushort_t* src = (half ? Blo : Bhi) + (size_t)j * 8;
    *(s8v*)&Bs[half * HN + j * 8] = *(const s8v*)src;
  }
  __syncthreads();

  const int lane = threadIdx.x & 63;
  const int wave = threadIdx.x >> 6;
  const int row0 = blockIdx.x * 128 + wave * 32;
  const int g = lane >> 4, li = lane & 15;

  f4v acc0[NT16], acc1[NT16];
#pragma unroll
  for (int ct = 0; ct < NT16; ++ct) {
    acc0[ct] = f4v{0.f, 0.f, 0.f, 0.f};
    acc1[ct] = f4v{0.f, 0.f, 0.f, 0.f};
  }

  int ar0 = row0 + li;       if (ar0 >= M) ar0 = M - 1;
  int ar1 = row0 + 16 + li;  if (ar1 >= M) ar1 = M - 1;

#pragma unroll
  for (int ks = 0; ks < 4; ++ks) {
    s8v ahi[2], alo[2];
#pragma unroll
    for (int rf = 0; rf < 2; ++rf) {
      int ar = rf ? ar1 : ar0;
      if constexpr (AFP32) {
        const float* ap = (const float*)A + (size_t)ar * 128 + ks * 32 + g * 4;
        float4 u0 = *(const float4*)ap;
        float4 u1 = *(const float4*)(ap + 16);
        float x[8] = {u0.x, u0.y, u0.z, u0.w, u1.x, u1.y, u1.z, u1.w};
#pragma unroll
        for (int i = 0; i < 8; ++i) {
          float v = GELU_A ? gelu_f(x[i]) : x[i];
          unsigned short h = f2bf(v);
          ahi[rf][i] = (short)h;
          alo[rf][i] = (short)f2bf(v - bf2f(h));
        }
      } else {
        const ushort_t* ap = (const ushort_t*)A + (size_t)ar * 128 + ks * 32 + g * 4;
        ushort4 u0 = *(const ushort4*)ap;
        ushort4 u1 = *(const ushort4*)(ap + 16);
        ushort_t uu[8] = {u0.x, u0.y, u0.z, u0.w, u1.x, u1.y, u1.z, u1.w};
#pragma unroll
        for (int i = 0; i < 8; ++i) {
          if (GELU_A) ahi[rf][i] = (short)f2bf(gelu_f(bf2f(uu[i])));
          else        ahi[rf][i] = (short)uu[i];
        }
      }
    }
#pragma unroll
    for (int ct = 0; ct < NT16; ++ct) {
      const ushort_t* bp = &Bs[(ct * 4 + ks) * 512 + lane * 8];
      s8v bhi = *(const s8v*)bp;
      acc0[ct] = __builtin_amdgcn_mfma_f32_16x16x32_bf16(ahi[0], bhi, acc0[ct], 0, 0, 0);
      acc1[ct] = __builtin_amdgcn_mfma_f32_16x16x32_bf16(ahi[1], bhi, acc1[ct], 0, 0, 0);
      if constexpr (BLO) {
        s8v blo = *(const s8v*)(bp + HN);
        if constexpr (AFP32) {
          acc0[ct] = __builtin_amdgcn_mfma_f32_16x16x32_bf16(alo[0], bhi, acc0[ct], 0, 0, 0);
          acc1[ct] = __builtin_amdgcn_mfma_f32_16x16x32_bf16(alo[1], bhi, acc1[ct], 0, 0, 0);
        }
        acc0[ct] = __builtin_amdgcn_mfma_f32_16x16x32_bf16(ahi[0], blo, acc0[ct], 0, 0, 0);
        acc1[ct] = __builtin_amdgcn_mfma_f32_16x16x32_bf16(ahi[1], blo, acc1[ct], 0, 0, 0);
      }
    }
  }

  float sskip = 0.f;
  if (MIX) sskip = 1.f / (1.f + __expf(-*skip_ptr));
#pragma unroll
  for (int rf = 0; rf < 2; ++rf) {
#pragma unroll
    for (int ct = 0; ct < NT16; ++ct) {
      int col = ct * 16 + li;
      bool colok = (col < NCOLS);
      float bv = colok ? bias[col] : 0.f;
      f4v a = rf ? acc1[ct] : acc0[ct];
#pragma unroll
      for (int r = 0; r < 4; ++r) {
        int grow = row0 + rf * 16 + g * 4 + r;
        if (grow < M && colok) {
          float v = a[r] + bv;
          size_t off = (size_t)grow * NCOLS + col;
          if constexpr (MIX) {            // bf16 h residual
            ushort_t* Cp = (ushort_t*)Cv;
            float hprev = bf2f(Cp[off]);
            Cp[off] = f2bf(elu_f(sskip * v + (1.f - sskip) * hprev));
          } else if constexpr (STORE == 1) {
            ((ushort_t*)Cv)[off] = f2bf(v);
          } else {
            ((float*)Cv)[off] = v;
          }
        }
      }
    }
  }
}

// ============ KV GEMM: LDS-staged, column-half split, pair-interleaved store ====
__global__ __launch_bounds__(256, 4) void gemm_kv(
    const ushort_t* __restrict__ A,
    const ushort_t* __restrict__ Bhi, const ushort_t* __restrict__ Blo,
    const float* __restrict__ bias, ushort_t* __restrict__ kvout, int M) {
  __shared__ ushort_t Bs[16384];           // [kv][t][ks][512]
  const int ch = blockIdx.y;
  for (int i = threadIdx.x; i < 2048; i += 256) {
    int kvh = i >> 10, j = i & 1023;
    const ushort_t* src = Bhi + (size_t)kvh * SLOT_ELEMS + ch * 8192 + j * 8;
    *(s8v*)&Bs[kvh * 8192 + j * 8] = *(const s8v*)src;
  }
  __syncthreads();

  const int lane = threadIdx.x & 63;
  const int wave = threadIdx.x >> 6;
  const int row0 = blockIdx.x * 128 + wave * 32;
  const int g = lane >> 4, li = lane & 15;

  f4v acc0[8], acc1[8];                    // [0..3]=K, [4..7]=V
#pragma unroll
  for (int t = 0; t < 8; ++t) {
    acc0[t] = f4v{0.f, 0.f, 0.f, 0.f};
    acc1[t] = f4v{0.f, 0.f, 0.f, 0.f};
  }

  int ar0 = row0 + li;       if (ar0 >= M) ar0 = M - 1;
  int ar1 = row0 + 16 + li;  if (ar1 >= M) ar1 = M - 1;

#pragma unroll
  for (int ks = 0; ks < 4; ++ks) {
    s8v a0, a1;
    {
      const ushort_t* ap = A + (size_t)ar0 * 128 + ks * 32 + g * 4;
      ushort4 u0 = *(const ushort4*)ap;
      ushort4 u1 = *(const ushort4*)(ap + 16);
      a0[0] = (short)u0.x; a0[1] = (short)u0.y; a0[2] = (short)u0.z; a0[3] = (short)u0.w;
      a0[4] = (short)u1.x; a0[5] = (short)u1.y; a0[6] = (short)u1.z; a0[7] = (short)u1.w;
    }
    {
      const ushort_t* ap = A + (size_t)ar1 * 128 + ks * 32 + g * 4;
      ushort4 u0 = *(const ushort4*)ap;
      ushort4 u1 = *(const ushort4*)(ap + 16);
      a1[0] = (short)u0.x; a1[1] = (short)u0.y; a1[2] = (short)u0.z; a1[3] = (short)u0.w;
      a1[4] = (short)u1.x; a1[5] = (short)u1.y; a1[6] = (short)u1.z; a1[7] = (short)u1.w;
    }
#pragma unroll
    for (int t = 0; t < 4; ++t) {
      s8v kh = *(const s8v*)&Bs[(t * 4 + ks) * 512 + lane * 8];
      acc0[t] = __builtin_amdgcn_mfma_f32_16x16x32_bf16(a0, kh, acc0[t], 0, 0, 0);
      acc1[t] = __builtin_amdgcn_mfma_f32_16x16x32_bf16(a1, kh, acc1[t], 0, 0, 0);
      s8v vh = *(const s8v*)&Bs[8192 + (t * 4 + ks) * 512 + lane * 8];
      acc0[4 + t] = __builtin_amdgcn_mfma_f32_16x16x32_bf16(a0, vh, acc0[4 + t], 0, 0, 0);
      acc1[4 + t] = __builtin_amdgcn_mfma_f32_16x16x32_bf16(a1, vh, acc1[4 + t], 0, 0, 0);
    }
  }

#pragma unroll
  for (int rf = 0; rf < 2; ++rf) {
#pragma unroll
    for (int t = 0; t < 4; ++t) {
      int col = ch * 64 + t * 16 + li;
      float bk = bias[col], bv = bias[128 + col];
#pragma unroll
      for (int r = 0; r < 4; ++r) {
        int grow = row0 + rf * 16 + g * 4 + r;
        if (grow < M) {
          float kvl = rf ? acc1[t][r] : acc0[t][r];
          float vvl = rf ? acc1[4 + t][r] : acc0[4 + t][r];
          ushort2 o;
          o.x = f2bf(kvl + bk);
          o.y = f2bf(vvl + bv);
          *(ushort2*)(kvout + (size_t)grow * 256 + 2 * col) = o;
        }
      }
    }
  }
}

// ============ fused Q + KV GEMM: grid (GB2, 3). y=0: q from Aq; y=1/2: kv halves
// from Akv (pair-interleaved store). Saves one launch + identical math.
__global__ __launch_bounds__(256, 4) void gemm_qkv(
    const ushort_t* __restrict__ Aq, const ushort_t* __restrict__ Akv,
    const ushort_t* __restrict__ Bq, const ushort_t* __restrict__ Bkv,
    const float* __restrict__ bias_q, const float* __restrict__ bias_kv,
    ushort_t* __restrict__ qout, ushort_t* __restrict__ kvout, int M) {
  __shared__ ushort_t Bs[16384];
  const int lane = threadIdx.x & 63;
  const int wave = threadIdx.x >> 6;
  const int row0 = blockIdx.x * 128 + wave * 32;
  const int g = lane >> 4, li = lane & 15;

  if (blockIdx.y == 0) {
    // ---- q path: 8 col tiles from Aq ----
    for (int i = threadIdx.x; i < 2048; i += 256)
      *(s8v*)&Bs[i * 8] = *(const s8v*)(Bq + (size_t)i * 8);
    __syncthreads();
    f4v acc0[8], acc1[8];
#pragma unroll
    for (int ct = 0; ct < 8; ++ct) {
      acc0[ct] = f4v{0.f, 0.f, 0.f, 0.f};
      acc1[ct] = f4v{0.f, 0.f, 0.f, 0.f};
    }
    int ar0 = row0 + li;       if (ar0 >= M) ar0 = M - 1;
    int ar1 = row0 + 16 + li;  if (ar1 >= M) ar1 = M - 1;
#pragma unroll
    for (int ks = 0; ks < 4; ++ks) {
      s8v a0, a1;
      {
        const ushort_t* ap = Aq + (size_t)ar0 * 128 + ks * 32 + g * 4;
        ushort4 u0 = *(const ushort4*)ap;
        ushort4 u1 = *(const ushort4*)(ap + 16);
        a0[0]=(short)u0.x; a0[1]=(short)u0.y; a0[2]=(short)u0.z; a0[3]=(short)u0.w;
        a0[4]=(short)u1.x; a0[5]=(short)u1.y; a0[6]=(short)u1.z; a0[7]=(short)u1.w;
      }
      {
        const ushort_t* ap = Aq + (size_t)ar1 * 128 + ks * 32 + g * 4;
        ushort4 u0 = *(const ushort4*)ap;
        ushort4 u1 = *(const ushort4*)(ap + 16);
        a1[0]=(short)u0.x; a1[1]=(short)u0.y; a1[2]=(short)u0.z; a1[3]=(short)u0.w;
        a1[4]=(short)u1.x; a1[5]=(short)u1.y; a1[6]=(short)u1.z; a1[7]=(short)u1.w;
      }
#pragma unroll
      for (int ct = 0; ct < 8; ++ct) {
        s8v bhi = *(const s8v*)&Bs[(ct * 4 + ks) * 512 + lane * 8];
        acc0[ct] = __builtin_amdgcn_mfma_f32_16x16x32_bf16(a0, bhi, acc0[ct], 0, 0, 0);
        acc1[ct] = __builtin_amdgcn_mfma_f32_16x16x32_bf16(a1, bhi, acc1[ct], 0, 0, 0);
      }
    }
#pragma unroll
    for (int rf = 0; rf < 2; ++rf) {
#pragma unroll
      for (int ct = 0; ct < 8; ++ct) {
        int col = ct * 16 + li;
        float bv = bias_q[col];
        f4v a = rf ? acc1[ct] : acc0[ct];
#pragma unroll
        for (int r = 0; r < 4; ++r) {
          int grow = row0 + rf * 16 + g * 4 + r;
          if (grow < M) qout[(size_t)grow * 128 + col] = f2bf(a[r] + bv);
        }
      }
    }
  } else {
    // ---- kv path: column half ch from Akv ----
    const int ch = blockIdx.y - 1;
    for (int i = threadIdx.x; i < 2048; i += 256) {
      int kvh = i >> 10, j = i & 1023;
      const ushort_t* src = Bkv + (size_t)kvh * SLOT_ELEMS + ch * 8192 + j * 8;
      *(s8v*)&Bs[kvh * 8192 + j * 8] = *(const s8v*)src;
    }
    __syncthreads();
    f4v acc0[8], acc1[8];
#pragma unroll
    for (int t = 0; t < 8; ++t) {
      acc0[t] = f4v{0.f, 0.f, 0.f, 0.f};
      acc1[t] = f4v{0.f, 0.f, 0.f, 0.f};
    }
    int ar0 = row0 + li;       if (ar0 >= M) ar0 = M - 1;
    int ar1 = row0 + 16 + li;  if (ar1 >= M) ar1 = M - 1;
#pragma unroll
    for (int ks = 0; ks < 4; ++ks) {
      s8v a0, a1;
      {
        const ushort_t* ap = Akv + (size_t)ar0 * 128 + ks * 32 + g * 4;
        ushort4 u0 = *(const ushort4*)ap;
        ushort4 u1 = *(const ushort4*)(ap + 16);
        a0[0]=(short)u0.x; a0[1]=(short)u0.y; a0[2]=(short)u0.z; a0[3]=(short)u0.w;
        a0[4]=(short)u1.x; a0[5]=(short)u1.y; a0[6]=(short)u1.z; a0[7]=(short)u1.w;
      }
      {
        const ushort_t* ap = Akv + (size_t)ar1 * 128 + ks * 32 + g * 4;
        ushort4 u0 = *(const ushort4*)ap;
        ushort4 u1 = *(const ushort4*)(ap + 16);
        a1[0]=(short)u0.x; a1[1]=(short)u0.y; a1[2]=(short)u0.z; a1[3]=(short)u0.w;
        a1[4]=(short)u1.x; a1[5]=(short)u1.y; a1[6]=(short)u1.z; a1[7]=(short)u1.w;
      }
#pragma unroll
      for (int t = 0; t < 4; ++t) {
        s8v kh = *(const s8v*)&Bs[(t * 4 + ks) * 512 + lane * 8];
        acc0[t] = __builtin_amdgcn_mfma_f32_16x16x32_bf16(a0, kh, acc0[t], 0, 0, 0);
        acc1[t] = __builtin_amdgcn_mfma_f32_16x16x32_bf16(a1, kh, acc1[t], 0, 0, 0);
        s8v vh = *(const s8v*)&Bs[8192 + (t * 4 + ks) * 512 + lane * 8];
        acc0[4 + t] = __builtin_amdgcn_mfma_f32_16x16x32_bf16(a0, vh, acc0[4 + t], 0, 0, 0);
        acc1[4 + t] = __builtin_amdgcn_mfma_f32_16x16x32_bf16(a1, vh, acc1[4 + t], 0, 0, 0);
      }
    }
#pragma unroll
    for (int rf = 0; rf < 2; ++rf) {
#pragma unroll
      for (int t = 0; t < 4; ++t) {
        int col = ch * 64 + t * 16 + li;
        float bk = bias_kv[col], bv = bias_kv[128 + col];
#pragma unroll
        for (int r = 0; r < 4; ++r) {
          int grow = row0 + rf * 16 + g * 4 + r;
          if (grow < M) {
            float kvl = rf ? acc1[t][r] : acc0[t][r];
            float vvl = rf ? acc1[4 + t][r] : acc0[4 + t][r];
            ushort2 o;
            o.x = f2bf(kvl + bk);
            o.y = f2bf(vvl + bv);
            *(ushort2*)(kvout + (size_t)grow * 256 + 2 * col) = o;
          }
        }
      }
    }
  }
}

// ------------- combined weights: cw = W @ blockdiag(rel), cb = b @ blockdiag(rel)
__global__ __launch_bounds__(256) void combine_w(
    const float* __restrict__ kqv_w, const float* __restrict__ kqv_b,
    const float* __restrict__ rel_a, const float* __restrict__ rel_m,
    float* __restrict__ cw, float* __restrict__ cb) {
  int b  = blockIdx.x;            // ((l*R)+r)*2+kv
  int kv = b & 1;
  int r  = (b >> 1) % R;
  int l  = b / (2 * R);
  int t_src = (r == 0) ? 0 : 1;
  int i_w   = (kv == 0) ? 0 : 2;
  const float* W    = kqv_w + ((size_t)((l*3 + i_w)*2 + t_src)) * D * D;
  const float* bvec = kqv_b + ((size_t)((l*3 + i_w)*2 + t_src)) * D;
  const float* rel  = ((kv == 0) ? rel_a : rel_m) + ((size_t)(l*R + r)) * H * 32 * 32;
  float* Cout = cw + (size_t)b * D * D;
  float* cbo  = cb + (size_t)b * D;
  for (int idx = threadIdx.x; idx < D * D; idx += 256) {
    int i = idx / D, j = idx % D;
    int h = j >> 5, f = j & 31;
    const float* relh = rel + h * 32 * 32;
    float sum = 0.f;
#pragma unroll
    for (int d = 0; d < 32; ++d) sum += W[i*D + (h*32 + d)] * relh[d*32 + f];
    Cout[idx] = sum;
  }
  if (threadIdx.x < D) {
    int j = threadIdx.x;
    int h = j >> 5, f = j & 31;
    const float* relh = rel + h * 32 * 32;
    float sum = 0.f;
#pragma unroll
    for (int d = 0; d < 32; ++d) sum += bvec[h*32 + d] * relh[d*32 + f];
    cbo[j] = sum;
  }
}

// ------------- pack weight matrices into MFMA-fragment order (hi/lo split) -------
__global__ __launch_bounds__(256) void pack_b(
    const float* __restrict__ proj_w, const float* __restrict__ kqv_w,
    const float* __restrict__ out_w, const float* __restrict__ cls_w,
    const float* __restrict__ cw,
    ushort_t* __restrict__ phi, ushort_t* __restrict__ plo) {
  int slot = blockIdx.x;
  const float* src; int ncol = 128;
  if (slot == 0) src = proj_w;
  else if (slot == 1) src = proj_w + D * D;
  else if (slot == 22) { src = cls_w; ncol = 40; }
  else {
    int l = (slot - 2) / 10, k = (slot - 2) % 10;
    if (k == 0)      src = kqv_w + ((size_t)((l*3 + 1)*2 + 0)) * D * D;
    else if (k == 1) src = kqv_w + ((size_t)((l*3 + 1)*2 + 1)) * D * D;
    else if (k < 8)  { int idx = k - 2; src = cw + ((size_t)((l*R)*2 + idx)) * D * D; }
    else             src = out_w + ((size_t)(l*2 + (k - 8))) * D * D;
  }
  int nt = (ncol + 15) / 16;
  int total = nt * 4 * 512;
  ushort_t* ph = phi + (size_t)slot * SLOT_ELEMS;
  ushort_t* pl = plo + (size_t)slot * SLOT_ELEMS;
  for (int idx = threadIdx.x; idx < total; idx += 256) {
    int j = idx & 7, lane = (idx >> 3) & 63, ks = (idx >> 9) & 3, ct = idx >> 11;
    int k = 4 * (lane >> 4) + (j & 3) + 16 * (j >> 2) + 32 * ks;
    int n = ct * 16 + (lane & 15);
    float v = (n < ncol) ? src[(size_t)k * ncol + n] : 0.f;
    unsigned short h = f2bf(v);
    ph[idx] = h;
    pl[idx] = f2bf(v - bf2f(h));
  }
}

// ---------------- CSR build (global-atomic; measured best at this size) ---------
__global__ void count3(const int* __restrict__ ei_w, const int* __restrict__ ei_c,
                       const int* __restrict__ ei_r, int* __restrict__ degz) {
  const int* dst = blockIdx.y == 0 ? ei_w + E : blockIdx.y == 1 ? ei_c + E : ei_r + E;
  int* deg = degz + blockIdx.y * NPP;
  for (int e = blockIdx.x * blockDim.x + threadIdx.x; e < E; e += gridDim.x * blockDim.x)
    atomicAdd(&deg[dst[e]], 1);
}
__global__ void fill3(const int* __restrict__ ei_w, const int* __restrict__ ei_c,
                      const int* __restrict__ ei_r,
                      const int* __restrict__ rp_w, const int* __restrict__ rp_c,
                      const int* __restrict__ rp_r,
                      int* __restrict__ cntz, int* __restrict__ colz) {
  int rel = blockIdx.y;
  const int* ei = rel == 0 ? ei_w : rel == 1 ? ei_c : ei_r;
  const int* dst = ei + E;
  const int* rp  = rel == 0 ? rp_w : rel == 1 ? rp_c : rp_r;
  int* cnt = cntz + rel * NPP;
  int* col = colz + rel * E;
  for (int e = blockIdx.x * blockDim.x + threadIdx.x; e < E; e += gridDim.x * blockDim.x) {
    int d = dst[e];
    int pos = atomicAdd(&cnt[d], 1);
    col[rp[d] + pos] = ei[e];          // store SOURCE node directly
  }
}

// 2-phase exclusive scan over three 100000-length deg arrays (contiguous)
__global__ __launch_bounds__(256) void scan_partial(const int* __restrict__ degz,
                                                    int* __restrict__ bsum) {
  int blk = blockIdx.x, rel = blk / 25, t25 = blk % 25;
  const int* deg = degz + rel * NPP + t25 * 4096;
  int nrem = min(4096, NPP - t25 * 4096);
  int base = threadIdx.x * 16;
  int s = 0;
  if (base < nrem) {
#pragma unroll
    for (int i4 = 0; i4 < 4; ++i4) {
      int4 v = *(const int4*)(deg + base + i4 * 4);
      s += v.x + v.y + v.z + v.w;
    }
  }
  __shared__ int sm[256];
  sm[threadIdx.x] = s; __syncthreads();
  for (int o = 128; o > 0; o >>= 1) {
    if (threadIdx.x < o) sm[threadIdx.x] += sm[threadIdx.x + o];
    __syncthreads();
  }
  if (threadIdx.x == 0) bsum[blk] = sm[0];
}
// final scan; computes its own chunk offset from bsum (no scan_offsets pass)
__global__ __launch_bounds__(256) void scan_final(const int* __restrict__ degz,
                                                  const int* __restrict__ bsum,
                                                  int* rp_w, int* rp_c, int* rp_r) {
  int blk = blockIdx.x, rel = blk / 25, t25 = blk % 25;
  const int* deg = degz + rel * NPP + t25 * 4096;
  int* rpb = (rel == 0 ? rp_w : rel == 1 ? rp_c : rp_r);
  int* rp = rpb + t25 * 4096;
  int boffv = 0;
  for (int i = 0; i < t25; ++i) boffv += bsum[rel * 25 + i];
  int nrem = min(4096, NPP - t25 * 4096);
  int base = threadIdx.x * 16;
  bool ok = base < nrem;
  int v[16]; int s = 0;
  if (ok) {
#pragma unroll
    for (int i4 = 0; i4 < 4; ++i4) {
      int4 u = *(const int4*)(deg + base + i4 * 4);
      v[i4*4+0] = u.x; v[i4*4+1] = u.y; v[i4*4+2] = u.z; v[i4*4+3] = u.w;
      s += u.x + u.y + u.z + u.w;
    }
  }
  __shared__ int sm[256];
  sm[threadIdx.x] = s; __syncthreads();
  for (int o = 1; o < 256; o <<= 1) {
    int x = (threadIdx.x >= o) ? sm[threadIdx.x - o] : 0;
    __syncthreads(); sm[threadIdx.x] += x; __syncthreads();
  }
  int run = boffv + sm[threadIdx.x] - s;
  if (ok) {
    int w[16];
#pragma unroll
    for (int i = 0; i < 16; ++i) { w[i] = run; run += v[i]; }
#pragma unroll
    for (int i4 = 0; i4 < 4; ++i4) *(int4*)(rp + base + i4 * 4) = *(const int4*)&w[i4*4];
  }
  if (t25 == 24 && threadIdx.x == 255) rpb[NPP] = boffv + sm[255];
}

// -------- attention v6: 2 dst/wave, merged virtual edge list, 4-deep ladder -----
// lanes 0-31 own dst0, lanes 32-63 own dst1; lane32 holds dims [4*l32,4*l32+4);
// head = l32>>3. The (up to two) CSR segments are treated as ONE virtual list of
// length dt; groups of 4 branchless slots (per-slot col/kv/prel select, invalid
// slots clamp to idx 0 and contribute e=0) keep 4 gathers in flight per dst
// ACROSS the relation boundary. One int4 (16B) gather per edge per lane from
// pair-interleaved kv: int i -> k = lo16(i), v = hi16(i). 3-step shfl_xor reduce
// within 8-lane head groups (never crosses halves). Writes normalized bf16 agg
// into aggout (the q buffer; wave reads its own q rows before overwriting).
template<bool TWO>
__global__ __launch_bounds__(256, 8) void attn6(
    const int* __restrict__ rp1, const int* __restrict__ col1,
    const ushort_t* __restrict__ kv1,
    const int* __restrict__ rp2, const int* __restrict__ col2,
    const ushort_t* __restrict__ kv2,
    const ushort_t* __restrict__ q,
    const float* __restrict__ prel1, const float* __restrict__ prel2,
    int ndst, ushort_t* __restrict__ aggout) {
  int lane = threadIdx.x & 63;
  int wave = threadIdx.x >> 6;
  int half = lane >> 5;
  int l32  = lane & 31;
  int dst  = blockIdx.x * 8 + wave * 2 + half;   // ndst % 8 == 0: no tail
  int head = l32 >> 3;
  const float scale = 0.17677669529663688f; // 1/sqrt(32)
  float pr1 = prel1[head] * scale;
  float pr2 = TWO ? prel2[head] * scale : pr1;
  ushort4 qv = *(const ushort4*)(q + (size_t)dst * D + l32 * 4);
  float q0 = bf2f(qv.x), q1 = bf2f(qv.y), q2 = bf2f(qv.z), q3 = bf2f(qv.w);
  int e0a = rp1[dst];
  int d1  = rp1[dst + 1] - e0a;
  int e0b = 0, dt = d1;
  if (TWO) { e0b = rp2[dst]; dt = d1 + (rp2[dst + 1] - e0b); }
  float z = 0.f, a0 = 0.f, a1 = 0.f, a2 = 0.f, a3 = 0.f;
  for (int jj = 0; jj < dt; jj += 4) {
    int4 us[4]; bool vs[4]; float prs[4];
#pragma unroll
    for (int s2 = 0; s2 < 4; ++s2) {
      int idx = jj + s2;
      bool v = idx < dt;
      bool f = (!TWO) || (idx < d1);
      int ci = 0;
      if (v) ci = f ? (e0a + idx) : (e0b + idx - d1);
      int src = f ? col1[ci] : col2[ci];
      const ushort_t* kvp = f ? kv1 : kv2;
      us[s2] = *(const int4*)(kvp + (size_t)src * 256 + l32 * 8);
      vs[s2] = v;
      prs[s2] = f ? pr1 : pr2;
    }
#pragma unroll
    for (int s2 = 0; s2 < 4; ++s2) {
      float p = q0 * klo(us[s2].x) + q1 * klo(us[s2].y)
              + q2 * klo(us[s2].z) + q3 * klo(us[s2].w);
      p += __shfl_xor(p, 1);
      p += __shfl_xor(p, 2);
      p += __shfl_xor(p, 4);
      float e = vs[s2] ? __expf(p * prs[s2]) : 0.f;
      z  += e;
      a0 += e * vhi(us[s2].x);
      a1 += e * vhi(us[s2].y);
      a2 += e * vhi(us[s2].z);
      a3 += e * vhi(us[s2].w);
    }
  }
  float inv = 1.f / (z + 1e-16f);
  ushort4 o;
  o.x = f2bf(a0 * inv);
  o.y = f2bf(a1 * inv);
  o.z = f2bf(a2 * inv);
  o.w = f2bf(a3 * inv);
  *(ushort4*)(aggout + (size_t)dst * D + l32 * 4) = o;
}

extern "C" void kernel_launch(void* const* d_in, const int* in_sizes, int n_in,
                              void* d_out, int out_size, void* d_ws, size_t ws_size,
                              hipStream_t stream) {
  const float* x_a    = (const float*)d_in[0];
  const float* x_p    = (const float*)d_in[1];
  const int*   ei_w   = (const int*)d_in[2];
  const int*   ei_r   = (const int*)d_in[3];
  const int*   ei_c   = (const int*)d_in[4];
  const float* proj_w = (const float*)d_in[5];
  const float* proj_b = (const float*)d_in[6];
  const float* kqv_w  = (const float*)d_in[7];
  const float* kqv_b  = (const float*)d_in[8];
  const float* out_w  = (const float*)d_in[9];
  const float* out_b  = (const float*)d_in[10];
  const float* rel_a  = (const float*)d_in[11];
  const float* rel_m  = (const float*)d_in[12];
  const float* p_rel  = (const float*)d_in[13];
  const float* skip   = (const float*)d_in[14];
  const float* cls_w  = (const float*)d_in[15];
  const float* cls_b  = (const float*)d_in[16];
  float* out = (float*)d_out;

  const size_t NF = (size_t)NA * D;   // 12.8M
  float* ws    = (float*)d_ws;
  // fp32 region
  float* cw    = ws;                             // 12*D*D
  float* cb    = cw + 12 * D * D;                // 12*D
  // bf16 region
  ushort_t* h_a   = (ushort_t*)(cb + 12 * D);    // NF
  ushort_t* h_p   = h_a + NF;                    // NF
  ushort_t* b_q   = h_p + NF;                    // NF (q, then bf16 agg)
  ushort_t* b_kv  = b_q + NF;                    // 2*NF pair-interleaved
  ushort_t* b_kv2 = b_kv + 2 * NF;               // 2*NF (writes-relation kv)
  ushort_t* phi   = b_kv2 + 2 * NF;              // 23*SLOT_ELEMS
  ushort_t* plo   = phi + (size_t)NSLOT * SLOT_ELEMS;
  // int region
  int* ip    = (int*)(plo + (size_t)NSLOT * SLOT_ELEMS);
  int* rp_w  = ip;                      // NPP+1
  int* rp_c  = rp_w + (NPP + 1);
  int* rp_r  = rp_c + (NPP + 1);
  int* degz  = rp_r + (NA + 1);         // 3*NPP deg + 3*NPP cnt (contiguous)
  int* cntz  = degz + 3 * NPP;
  int* colz  = cntz + 3 * NPP;          // 3*E (src-node per CSR entry)
  int* bsum  = colz + 3 * E;            // 75
  int* boff  = bsum + 128;              // 75 (unused; kept for layout stability)
  size_t need_bytes = (size_t)((char*)(boff + 128) - (char*)d_ws);
  if (ws_size < need_bytes) return;

  hipMemsetAsync(degz, 0, sizeof(int) * 6 * (size_t)NPP, stream);

  count3<<<dim3(256, 3), 256, 0, stream>>>(ei_w, ei_c, ei_r, degz);
  scan_partial<<<75, 256, 0, stream>>>(degz, bsum);
  scan_final<<<75, 256, 0, stream>>>(degz, bsum, rp_w, rp_c, rp_r);
  fill3<<<dim3(256, 3), 256, 0, stream>>>(ei_w, ei_c, ei_r, rp_w, rp_c, rp_r, cntz, colz);
  int* col_w = colz;
  int* col_c = colz + E;
  int* col_r = colz + 2 * E;

  combine_w<<<12, 256, 0, stream>>>(kqv_w, kqv_b, rel_a, rel_m, cw, cb);
  pack_b<<<NSLOT, 256, 0, stream>>>(proj_w, kqv_w, out_w, cls_w, cw, phi, plo);

  auto PH = [&](int s){ return phi + (size_t)s * SLOT_ELEMS; };
  auto PL = [&](int s){ return plo + (size_t)s * SLOT_ELEMS; };

  const int GB2 = (NA + 127) / 128;    // 782
  const int GA  = NA / 8;              // 12500 (NA % 8 == 0)
  const dim3 G1(GB2, 1), GKV(GB2, 2), GQKV(GB2, 3);
  // initial projections (fp32 input, bf16 h out, A+B split for precision)
  gemm4<8, 128, 1, false, false, true, float><<<G1, 256, 0, stream>>>(
      x_a, PH(0), PL(0), proj_b,     h_a, nullptr, NA);
  gemm4<8, 128, 1, false, false, true, float><<<G1, 256, 0, stream>>>(
      x_p, PH(1), PL(1), proj_b + D, h_p, nullptr, NPP);

  for (int l = 0; l < L; ++l) {
    const int SQA = 2 + l * 10 + 0, SQP = 2 + l * 10 + 1;
    auto SKV = [&](int r){ return 2 + l * 10 + 2 + r * 2; };  // k slot; v slot = +1
    const int SO0 = 2 + l * 10 + 8, SO1 = 2 + l * 10 + 9;
    const float* bq_a = kqv_b + ((size_t)((l*3 + 1)*2 + 0)) * D;
    const float* bq_p = kqv_b + ((size_t)((l*3 + 1)*2 + 1)) * D;
    auto CB2 = [&](int r){ return cb + ((size_t)((l*R + r)*2)) * D; };  // 256 floats (k|v)
    const float* prelW = p_rel + (size_t)(l*R + 0) * H;
    const float* prelR = p_rel + (size_t)(l*R + 1) * H;
    const float* prelC = p_rel + (size_t)(l*R + 2) * H;

    // ---- author destination (rev_writes r=1, src=paper) ----
    // fused: q_a (from h_a) + kv1 (from h_p)
    gemm_qkv<<<GQKV, 256, 0, stream>>>(
        h_a, h_p, PH(SQA), PH(SKV(1)), bq_a, CB2(1), b_q, b_kv, NA);
    attn6<false><<<GA, 256, 0, stream>>>(
        rp_r, col_r, b_kv, nullptr, nullptr, nullptr,
        b_q, prelR, prelR, NA, b_q);
    // writes-relation K/V from OLD h_a (before author update) into b_kv2
    gemm_kv<<<GKV, 256, 0, stream>>>(
        h_a, PH(SKV(0)), PL(SKV(0)), CB2(0), b_kv2, NA);
    // author out-mix (in-place bf16 h_a); A = bf16 agg in b_q, gelu applied
    gemm4<8, 128, 1, true, true, false, ushort_t><<<G1, 256, 0, stream>>>(
        b_q, PH(SO0), PL(SO0), out_b + (size_t)(l*2 + 0) * D, h_a,
        skip + l*2 + 0, NA);

    // ---- paper destination: joint softmax over writes(r=0) + cites(r=2) ----
    // fused: q_p + kv2(cites), both from h_p
    gemm_qkv<<<GQKV, 256, 0, stream>>>(
        h_p, h_p, PH(SQP), PH(SKV(2)), bq_p, CB2(2), b_q, b_kv, NPP);
    attn6<true><<<GA, 256, 0, stream>>>(
        rp_w, col_w, b_kv2, rp_c, col_c, b_kv,
        b_q, prelW, prelC, NPP, b_q);
    gemm4<8, 128, 1, true, true, false, ushort_t><<<G1, 256, 0, stream>>>(
        b_q, PH(SO1), PL(SO1), out_b + (size_t)(l*2 + 1) * D, h_p,
        skip + l*2 + 1, NPP);
  }

  gemm4<3, 40, 0, false, false, true, ushort_t><<<G1, 256, 0, stream>>>(
      h_p, PH(22), PL(22), cls_b, out, nullptr, NPP);
}

// Round 13
// 875.824 us; speedup vs baseline: 1.5008x; 1.0223x over previous
//
#include <hip/hip_runtime.h>
#include <hip/hip_bf16.h>
#include <math.h>

constexpr int NA  = 100000;
constexpr int NPP = 100000;
constexpr int D   = 128;
constexpr int H   = 4;
constexpr int E   = 400000;
constexpr int R   = 3;
constexpr int L   = 2;
constexpr int NSLOT = 23;
constexpr int SLOT_ELEMS = 8 * 4 * 512;   // 8 col-tiles * 4 ksteps * 512 bf16
constexpr int GB2c = (NA + 127) / 128;    // 782
constexpr int GAc  = NA / 8;              // 12500
constexpr int MEGA_G = 1564 * 9;          // 14076: 1/9 gemm-kv blocks, 8/9 attn

using s8v = __attribute__((ext_vector_type(8))) short;
using f4v = __attribute__((ext_vector_type(4))) float;
typedef unsigned short ushort_t;

static __device__ __forceinline__ unsigned short f2bf(float f) {
  unsigned u = __float_as_uint(f);
  return (unsigned short)((u + 0x7fffu + ((u >> 16) & 1u)) >> 16);
}
static __device__ __forceinline__ float bf2f(unsigned short s) {
  return __uint_as_float(((unsigned)s) << 16);
}
static __device__ __forceinline__ float klo(int i) {        // low bf16 -> f32
  return __uint_as_float(((unsigned)i) << 16);
}
static __device__ __forceinline__ float vhi(int i) {        // high bf16 -> f32
  return __uint_as_float(((unsigned)i) & 0xffff0000u);
}
static __device__ __forceinline__ float gelu_f(float x) {
  return 0.5f * x * (1.0f + erff(x * 0.70710678118654752f));
}
static __device__ __forceinline__ float elu_f(float x) {
  return x > 0.0f ? x : expm1f(x);
}

// ============ device GEMM bodies (bf16 A, hi-only B, LDS-staged) ================
// wave computes 32 rows x 8*16 cols; A frag: lane l -> row l&15,
// k(i) = 4*(l>>4)+(i&3)+16*(i>>2)+32*ks; C/D: col = lane&15, row = (lane>>4)*4+r.
static __device__ __forceinline__ void load_a2(
    const ushort_t* __restrict__ A, int ar0, int ar1, int ks, int g,
    s8v& a0, s8v& a1) {
  const ushort_t* ap0 = A + (size_t)ar0 * 128 + ks * 32 + g * 4;
  ushort4 u0 = *(const ushort4*)ap0;
  ushort4 u1 = *(const ushort4*)(ap0 + 16);
  a0[0]=(short)u0.x; a0[1]=(short)u0.y; a0[2]=(short)u0.z; a0[3]=(short)u0.w;
  a0[4]=(short)u1.x; a0[5]=(short)u1.y; a0[6]=(short)u1.z; a0[7]=(short)u1.w;
  const ushort_t* ap1 = A + (size_t)ar1 * 128 + ks * 32 + g * 4;
  ushort4 v0 = *(const ushort4*)ap1;
  ushort4 v1 = *(const ushort4*)(ap1 + 16);
  a1[0]=(short)v0.x; a1[1]=(short)v0.y; a1[2]=(short)v0.z; a1[3]=(short)v0.w;
  a1[4]=(short)v1.x; a1[5]=(short)v1.y; a1[6]=(short)v1.z; a1[7]=(short)v1.w;
}

template<bool GELU_A, bool MIX>
__device__ __forceinline__ void dev_gemm8(
    const ushort_t* __restrict__ A, const ushort_t* __restrict__ Bhi,
    const float* __restrict__ bias, ushort_t* __restrict__ Cout,
    const float* __restrict__ skip_ptr, int M, int bx, ushort_t* Bs) {
  for (int i = threadIdx.x; i < 2048; i += 256)
    *(s8v*)&Bs[i * 8] = *(const s8v*)(Bhi + (size_t)i * 8);
  __syncthreads();
  const int lane = threadIdx.x & 63;
  const int wave = threadIdx.x >> 6;
  const int row0 = bx * 128 + wave * 32;
  const int g = lane >> 4, li = lane & 15;
  f4v acc0[8], acc1[8];
#pragma unroll
  for (int ct = 0; ct < 8; ++ct) {
    acc0[ct] = f4v{0.f, 0.f, 0.f, 0.f};
    acc1[ct] = f4v{0.f, 0.f, 0.f, 0.f};
  }
  int ar0 = row0 + li;       if (ar0 >= M) ar0 = M - 1;
  int ar1 = row0 + 16 + li;  if (ar1 >= M) ar1 = M - 1;
#pragma unroll
  for (int ks = 0; ks < 4; ++ks) {
    s8v a0, a1;
    load_a2(A, ar0, ar1, ks, g, a0, a1);
    if (GELU_A) {
#pragma unroll
      for (int i = 0; i < 8; ++i) {
        a0[i] = (short)f2bf(gelu_f(bf2f((unsigned short)a0[i])));
        a1[i] = (short)f2bf(gelu_f(bf2f((unsigned short)a1[i])));
      }
    }
#pragma unroll
    for (int ct = 0; ct < 8; ++ct) {
      s8v bhi = *(const s8v*)&Bs[(ct * 4 + ks) * 512 + lane * 8];
      acc0[ct] = __builtin_amdgcn_mfma_f32_16x16x32_bf16(a0, bhi, acc0[ct], 0, 0, 0);
      acc1[ct] = __builtin_amdgcn_mfma_f32_16x16x32_bf16(a1, bhi, acc1[ct], 0, 0, 0);
    }
  }
  float sskip = 0.f;
  if (MIX) sskip = 1.f / (1.f + __expf(-*skip_ptr));
#pragma unroll
  for (int rf = 0; rf < 2; ++rf) {
#pragma unroll
    for (int ct = 0; ct < 8; ++ct) {
      int col = ct * 16 + li;
      float bv = bias[col];
      f4v a = rf ? acc1[ct] : acc0[ct];
#pragma unroll
      for (int r = 0; r < 4; ++r) {
        int grow = row0 + rf * 16 + g * 4 + r;
        if (grow < M) {
          float v = a[r] + bv;
          size_t off = (size_t)grow * 128 + col;
          if constexpr (MIX) {
            float hprev = bf2f(Cout[off]);
            Cout[off] = f2bf(elu_f(sskip * v + (1.f - sskip) * hprev));
          } else {
            Cout[off] = f2bf(v);
          }
        }
      }
    }
  }
}

__device__ __forceinline__ void dev_gemm_kv(
    const ushort_t* __restrict__ A, const ushort_t* __restrict__ Bkv,
    const float* __restrict__ bias, ushort_t* __restrict__ kvout,
    int M, int bx, int ch, ushort_t* Bs) {
  for (int i = threadIdx.x; i < 2048; i += 256) {
    int kvh = i >> 10, j = i & 1023;
    const ushort_t* src = Bkv + (size_t)kvh * SLOT_ELEMS + ch * 8192 + j * 8;
    *(s8v*)&Bs[kvh * 8192 + j * 8] = *(const s8v*)src;
  }
  __syncthreads();
  const int lane = threadIdx.x & 63;
  const int wave = threadIdx.x >> 6;
  const int row0 = bx * 128 + wave * 32;
  const int g = lane >> 4, li = lane & 15;
  f4v acc0[8], acc1[8];                    // [0..3]=K, [4..7]=V
#pragma unroll
  for (int t = 0; t < 8; ++t) {
    acc0[t] = f4v{0.f, 0.f, 0.f, 0.f};
    acc1[t] = f4v{0.f, 0.f, 0.f, 0.f};
  }
  int ar0 = row0 + li;       if (ar0 >= M) ar0 = M - 1;
  int ar1 = row0 + 16 + li;  if (ar1 >= M) ar1 = M - 1;
#pragma unroll
  for (int ks = 0; ks < 4; ++ks) {
    s8v a0, a1;
    load_a2(A, ar0, ar1, ks, g, a0, a1);
#pragma unroll
    for (int t = 0; t < 4; ++t) {
      s8v kh = *(const s8v*)&Bs[(t * 4 + ks) * 512 + lane * 8];
      acc0[t] = __builtin_amdgcn_mfma_f32_16x16x32_bf16(a0, kh, acc0[t], 0, 0, 0);
      acc1[t] = __builtin_amdgcn_mfma_f32_16x16x32_bf16(a1, kh, acc1[t], 0, 0, 0);
      s8v vh = *(const s8v*)&Bs[8192 + (t * 4 + ks) * 512 + lane * 8];
      acc0[4 + t] = __builtin_amdgcn_mfma_f32_16x16x32_bf16(a0, vh, acc0[4 + t], 0, 0, 0);
      acc1[4 + t] = __builtin_amdgcn_mfma_f32_16x16x32_bf16(a1, vh, acc1[4 + t], 0, 0, 0);
    }
  }
#pragma unroll
  for (int rf = 0; rf < 2; ++rf) {
#pragma unroll
    for (int t = 0; t < 4; ++t) {
      int col = ch * 64 + t * 16 + li;
      float bk = bias[col], bv = bias[128 + col];
#pragma unroll
      for (int r = 0; r < 4; ++r) {
        int grow = row0 + rf * 16 + g * 4 + r;
        if (grow < M) {
          float kvl = rf ? acc1[t][r] : acc0[t][r];
          float vvl = rf ? acc1[4 + t][r] : acc0[4 + t][r];
          ushort2 o;
          o.x = f2bf(kvl + bk);
          o.y = f2bf(vvl + bv);
          *(ushort2*)(kvout + (size_t)grow * 256 + 2 * col) = o;
        }
      }
    }
  }
}

// ============ device attention body (2 dst/wave, virtual list, 4-deep) ==========
template<bool TWO>
__device__ __forceinline__ void dev_attn(
    const int* __restrict__ rp1, const int* __restrict__ col1,
    const ushort_t* __restrict__ kv1,
    const int* __restrict__ rp2, const int* __restrict__ col2,
    const ushort_t* __restrict__ kv2,
    const ushort_t* __restrict__ q,
    const float* __restrict__ prel1, const float* __restrict__ prel2,
    ushort_t* __restrict__ aggout, int ablk) {
  int lane = threadIdx.x & 63;
  int wave = threadIdx.x >> 6;
  int half = lane >> 5;
  int l32  = lane & 31;
  int dst  = ablk * 8 + wave * 2 + half;   // ndst % 8 == 0: no tail
  int head = l32 >> 3;
  const float scale = 0.17677669529663688f; // 1/sqrt(32)
  float pr1 = prel1[head] * scale;
  float pr2 = TWO ? prel2[head] * scale : pr1;
  ushort4 qv = *(const ushort4*)(q + (size_t)dst * D + l32 * 4);
  float q0 = bf2f(qv.x), q1 = bf2f(qv.y), q2 = bf2f(qv.z), q3 = bf2f(qv.w);
  int e0a = rp1[dst];
  int d1  = rp1[dst + 1] - e0a;
  int e0b = 0, dt = d1;
  if (TWO) { e0b = rp2[dst]; dt = d1 + (rp2[dst + 1] - e0b); }
  float z = 0.f, a0 = 0.f, a1 = 0.f, a2 = 0.f, a3 = 0.f;
  for (int jj = 0; jj < dt; jj += 4) {
    int4 us[4]; bool vs[4]; float prs[4];
#pragma unroll
    for (int s2 = 0; s2 < 4; ++s2) {
      int idx = jj + s2;
      bool v = idx < dt;
      bool f = (!TWO) || (idx < d1);
      int ci = 0;
      if (v) ci = f ? (e0a + idx) : (e0b + idx - d1);
      int src = f ? col1[ci] : col2[ci];
      const ushort_t* kvp = f ? kv1 : kv2;
      us[s2] = *(const int4*)(kvp + (size_t)src * 256 + l32 * 8);
      vs[s2] = v;
      prs[s2] = f ? pr1 : pr2;
    }
#pragma unroll
    for (int s2 = 0; s2 < 4; ++s2) {
      float p = q0 * klo(us[s2].x) + q1 * klo(us[s2].y)
              + q2 * klo(us[s2].z) + q3 * klo(us[s2].w);
      p += __shfl_xor(p, 1);
      p += __shfl_xor(p, 2);
      p += __shfl_xor(p, 4);
      float e = vs[s2] ? __expf(p * prs[s2]) : 0.f;
      z  += e;
      a0 += e * vhi(us[s2].x);
      a1 += e * vhi(us[s2].y);
      a2 += e * vhi(us[s2].z);
      a3 += e * vhi(us[s2].w);
    }
  }
  float inv = 1.f / (z + 1e-16f);
  ushort4 o;
  o.x = f2bf(a0 * inv);
  o.y = f2bf(a1 * inv);
  o.z = f2bf(a2 * inv);
  o.w = f2bf(a3 * inv);
  *(ushort4*)(aggout + (size_t)dst * D + l32 * 4) = o;
}

// =============== global kernels =================================================
// paper attention (two relations, joint softmax)
__global__ __launch_bounds__(256, 8) void attn_p(
    const int* __restrict__ rp1, const int* __restrict__ col1,
    const ushort_t* __restrict__ kv1,
    const int* __restrict__ rp2, const int* __restrict__ col2,
    const ushort_t* __restrict__ kv2,
    const ushort_t* __restrict__ q,
    const float* __restrict__ prel1, const float* __restrict__ prel2,
    ushort_t* __restrict__ aggout) {
  dev_attn<true>(rp1, col1, kv1, rp2, col2, kv2, q, prel1, prel2, aggout, blockIdx.x);
}

// MEGA: author attention (8/9 of blocks) || writes-KV gemm (1/9 of blocks)
__global__ __launch_bounds__(256, 4) void mega0(
    const int* __restrict__ rp_r, const int* __restrict__ col_r,
    const ushort_t* __restrict__ kv1, const ushort_t* __restrict__ q,
    const float* __restrict__ prelR, ushort_t* __restrict__ aggout,
    const ushort_t* __restrict__ h_a, const ushort_t* __restrict__ Bkv0,
    const float* __restrict__ cb0, ushort_t* __restrict__ kv2out) {
  __shared__ ushort_t Bs[16384];
  unsigned gidx = blockIdx.x;
  if (gidx % 9 == 0) {
    int gb = gidx / 9;                 // 0..1563
    dev_gemm_kv(h_a, Bkv0, cb0, kv2out, NA, gb >> 1, gb & 1, Bs);
  } else {
    int ablk = gidx - gidx / 9 - 1;    // 0..12511
    if (ablk < GAc)
      dev_attn<false>(rp_r, col_r, kv1, nullptr, nullptr, nullptr,
                      q, prelR, prelR, aggout, ablk);
  }
}

// FUSED phase: author out-mix (y=0) || paper q (y=1) || paper cites-KV (y=2,3)
__global__ __launch_bounds__(256, 4) void fusedA(
    const ushort_t* __restrict__ agg_a, const ushort_t* __restrict__ Bout,
    const float* __restrict__ out_b0, ushort_t* __restrict__ h_a,
    const float* __restrict__ skip0,
    const ushort_t* __restrict__ h_p, const ushort_t* __restrict__ Bq,
    const float* __restrict__ bq_p, ushort_t* __restrict__ qout,
    const ushort_t* __restrict__ Bkv, const float* __restrict__ cb2,
    ushort_t* __restrict__ kvout) {
  __shared__ ushort_t Bs[16384];
  if (blockIdx.y == 0) {
    dev_gemm8<true, true>(agg_a, Bout, out_b0, h_a, skip0, NA, blockIdx.x, Bs);
  } else if (blockIdx.y == 1) {
    dev_gemm8<false, false>(h_p, Bq, bq_p, qout, nullptr, NPP, blockIdx.x, Bs);
  } else {
    dev_gemm_kv(h_p, Bkv, cb2, kvout, NPP, blockIdx.x, blockIdx.y - 2, Bs);
  }
}

// fused Q + KV GEMM (author phase): y=0 q from Aq; y=1/2 kv halves from Akv
__global__ __launch_bounds__(256, 4) void gemm_qkv(
    const ushort_t* __restrict__ Aq, const ushort_t* __restrict__ Akv,
    const ushort_t* __restrict__ Bq, const ushort_t* __restrict__ Bkv,
    const float* __restrict__ bias_q, const float* __restrict__ bias_kv,
    ushort_t* __restrict__ qout, ushort_t* __restrict__ kvout, int M) {
  __shared__ ushort_t Bs[16384];
  if (blockIdx.y == 0)
    dev_gemm8<false, false>(Aq, Bq, bias_q, qout, nullptr, M, blockIdx.x, Bs);
  else
    dev_gemm_kv(Akv, Bkv, bias_kv, kvout, M, blockIdx.x, blockIdx.y - 1, Bs);
}

// paper out-mix standalone
__global__ __launch_bounds__(256, 4) void outmix(
    const ushort_t* __restrict__ agg, const ushort_t* __restrict__ Bout,
    const float* __restrict__ out_b1, ushort_t* __restrict__ h,
    const float* __restrict__ skip1, int M) {
  __shared__ ushort_t Bs[16384];
  dev_gemm8<true, true>(agg, Bout, out_b1, h, skip1, M, blockIdx.x, Bs);
}

// =============== fp32-A GEMM (proj; BLO) and cls ================================
template<int NT16, int NCOLS, int STORE, bool BLO, typename TA>
__global__ __launch_bounds__(256, 4) void gemm4(
    const TA* __restrict__ A,
    const ushort_t* __restrict__ Bhi, const ushort_t* __restrict__ Blo,
    const float* __restrict__ bias, void* __restrict__ Cv, int M) {
  constexpr int HN = NT16 * 2048;
  __shared__ ushort_t Bs[HN * (BLO ? 2 : 1)];
  constexpr bool AFP32 = sizeof(TA) == 4;
  for (int i = threadIdx.x; i < (HN / 8) * (BLO ? 2 : 1); i += 256) {
    int half = i / (HN / 8), j = i % (HN / 8);
    const ushort_t* src = (half ? Blo : Bhi) + (size_t)j * 8;
    *(s8v*)&Bs[half * HN + j * 8] = *(const s8v*)src;
  }
  __syncthreads();
  const int lane = threadIdx.x & 63;
  const int wave = threadIdx.x >> 6;
  const int row0 = blockIdx.x * 128 + wave * 32;
  const int g = lane >> 4, li = lane & 15;
  f4v acc0[NT16], acc1[NT16];
#pragma unroll
  for (int ct = 0; ct < NT16; ++ct) {
    acc0[ct] = f4v{0.f, 0.f, 0.f, 0.f};
    acc1[ct] = f4v{0.f, 0.f, 0.f, 0.f};
  }
  int ar0 = row0 + li;       if (ar0 >= M) ar0 = M - 1;
  int ar1 = row0 + 16 + li;  if (ar1 >= M) ar1 = M - 1;
#pragma unroll
  for (int ks = 0; ks < 4; ++ks) {
    s8v ahi[2], alo[2];
#pragma unroll
    for (int rf = 0; rf < 2; ++rf) {
      int ar = rf ? ar1 : ar0;
      if constexpr (AFP32) {
        const float* ap = (const float*)A + (size_t)ar * 128 + ks * 32 + g * 4;
        float4 u0 = *(const float4*)ap;
        float4 u1 = *(const float4*)(ap + 16);
        float x[8] = {u0.x, u0.y, u0.z, u0.w, u1.x, u1.y, u1.z, u1.w};
#pragma unroll
        for (int i = 0; i < 8; ++i) {
          unsigned short h = f2bf(x[i]);
          ahi[rf][i] = (short)h;
          alo[rf][i] = (short)f2bf(x[i] - bf2f(h));
        }
      } else {
        const ushort_t* ap = (const ushort_t*)A + (size_t)ar * 128 + ks * 32 + g * 4;
        ushort4 u0 = *(const ushort4*)ap;
        ushort4 u1 = *(const ushort4*)(ap + 16);
        ahi[rf][0]=(short)u0.x; ahi[rf][1]=(short)u0.y; ahi[rf][2]=(short)u0.z; ahi[rf][3]=(short)u0.w;
        ahi[rf][4]=(short)u1.x; ahi[rf][5]=(short)u1.y; ahi[rf][6]=(short)u1.z; ahi[rf][7]=(short)u1.w;
      }
    }
#pragma unroll
    for (int ct = 0; ct < NT16; ++ct) {
      const ushort_t* bp = &Bs[(ct * 4 + ks) * 512 + lane * 8];
      s8v bhi = *(const s8v*)bp;
      acc0[ct] = __builtin_amdgcn_mfma_f32_16x16x32_bf16(ahi[0], bhi, acc0[ct], 0, 0, 0);
      acc1[ct] = __builtin_amdgcn_mfma_f32_16x16x32_bf16(ahi[1], bhi, acc1[ct], 0, 0, 0);
      if constexpr (BLO) {
        s8v blo = *(const s8v*)(bp + HN);
        if constexpr (AFP32) {
          acc0[ct] = __builtin_amdgcn_mfma_f32_16x16x32_bf16(alo[0], bhi, acc0[ct], 0, 0, 0);
          acc1[ct] = __builtin_amdgcn_mfma_f32_16x16x32_bf16(alo[1], bhi, acc1[ct], 0, 0, 0);
        }
        acc0[ct] = __builtin_amdgcn_mfma_f32_16x16x32_bf16(ahi[0], blo, acc0[ct], 0, 0, 0);
        acc1[ct] = __builtin_amdgcn_mfma_f32_16x16x32_bf16(ahi[1], blo, acc1[ct], 0, 0, 0);
      }
    }
  }
#pragma unroll
  for (int rf = 0; rf < 2; ++rf) {
#pragma unroll
    for (int ct = 0; ct < NT16; ++ct) {
      int col = ct * 16 + li;
      bool colok = (col < NCOLS);
      float bv = colok ? bias[col] : 0.f;
      f4v a = rf ? acc1[ct] : acc0[ct];
#pragma unroll
      for (int r = 0; r < 4; ++r) {
        int grow = row0 + rf * 16 + g * 4 + r;
        if (grow < M && colok) {
          float v = a[r] + bv;
          size_t off = (size_t)grow * NCOLS + col;
          if constexpr (STORE == 1) ((ushort_t*)Cv)[off] = f2bf(v);
          else                      ((float*)Cv)[off] = v;
        }
      }
    }
  }
}

// ------------- combined weights: cw = W @ blockdiag(rel), cb = b @ blockdiag(rel)
__global__ __launch_bounds__(256) void combine_w(
    const float* __restrict__ kqv_w, const float* __restrict__ kqv_b,
    const float* __restrict__ rel_a, const float* __restrict__ rel_m,
    float* __restrict__ cw, float* __restrict__ cb) {
  int b  = blockIdx.x;            // ((l*R)+r)*2+kv
  int kv = b & 1;
  int r  = (b >> 1) % R;
  int l  = b / (2 * R);
  int t_src = (r == 0) ? 0 : 1;
  int i_w   = (kv == 0) ? 0 : 2;
  const float* W    = kqv_w + ((size_t)((l*3 + i_w)*2 + t_src)) * D * D;
  const float* bvec = kqv_b + ((size_t)((l*3 + i_w)*2 + t_src)) * D;
  const float* rel  = ((kv == 0) ? rel_a : rel_m) + ((size_t)(l*R + r)) * H * 32 * 32;
  float* Cout = cw + (size_t)b * D * D;
  float* cbo  = cb + (size_t)b * D;
  for (int idx = threadIdx.x; idx < D * D; idx += 256) {
    int i = idx / D, j = idx % D;
    int h = j >> 5, f = j & 31;
    const float* relh = rel + h * 32 * 32;
    float sum = 0.f;
#pragma unroll
    for (int d = 0; d < 32; ++d) sum += W[i*D + (h*32 + d)] * relh[d*32 + f];
    Cout[idx] = sum;
  }
  if (threadIdx.x < D) {
    int j = threadIdx.x;
    int h = j >> 5, f = j & 31;
    const float* relh = rel + h * 32 * 32;
    float sum = 0.f;
#pragma unroll
    for (int d = 0; d < 32; ++d) sum += bvec[h*32 + d] * relh[d*32 + f];
    cbo[j] = sum;
  }
}

// ------------- pack weight matrices into MFMA-fragment order (hi/lo split) -------
__global__ __launch_bounds__(256) void pack_b(
    const float* __restrict__ proj_w, const float* __restrict__ kqv_w,
    const float* __restrict__ out_w, const float* __restrict__ cls_w,
    const float* __restrict__ cw,
    ushort_t* __restrict__ phi, ushort_t* __restrict__ plo) {
  int slot = blockIdx.x;
  const float* src; int ncol = 128;
  if (slot == 0) src = proj_w;
  else if (slot == 1) src = proj_w + D * D;
  else if (slot == 22) { src = cls_w; ncol = 40; }
  else {
    int l = (slot - 2) / 10, k = (slot - 2) % 10;
    if (k == 0)      src = kqv_w + ((size_t)((l*3 + 1)*2 + 0)) * D * D;
    else if (k == 1) src = kqv_w + ((size_t)((l*3 + 1)*2 + 1)) * D * D;
    else if (k < 8)  { int idx = k - 2; src = cw + ((size_t)((l*R)*2 + idx)) * D * D; }
    else             src = out_w + ((size_t)(l*2 + (k - 8))) * D * D;
  }
  int nt = (ncol + 15) / 16;
  int total = nt * 4 * 512;
  ushort_t* ph = phi + (size_t)slot * SLOT_ELEMS;
  ushort_t* pl = plo + (size_t)slot * SLOT_ELEMS;
  for (int idx = threadIdx.x; idx < total; idx += 256) {
    int j = idx & 7, lane = (idx >> 3) & 63, ks = (idx >> 9) & 3, ct = idx >> 11;
    int k = 4 * (lane >> 4) + (j & 3) + 16 * (j >> 2) + 32 * ks;
    int n = ct * 16 + (lane & 15);
    float v = (n < ncol) ? src[(size_t)k * ncol + n] : 0.f;
    unsigned short h = f2bf(v);
    ph[idx] = h;
    pl[idx] = f2bf(v - bf2f(h));
  }
}

// ---------------- CSR build (global-atomic; measured best at this size) ---------
__global__ void count3(const int* __restrict__ ei_w, const int* __restrict__ ei_c,
                       const int* __restrict__ ei_r, int* __restrict__ degz) {
  const int* dst = blockIdx.y == 0 ? ei_w + E : blockIdx.y == 1 ? ei_c + E : ei_r + E;
  int* deg = degz + blockIdx.y * NPP;
  for (int e = blockIdx.x * blockDim.x + threadIdx.x; e < E; e += gridDim.x * blockDim.x)
    atomicAdd(&deg[dst[e]], 1);
}
__global__ void fill3(const int* __restrict__ ei_w, const int* __restrict__ ei_c,
                      const int* __restrict__ ei_r,
                      const int* __restrict__ rp_w, const int* __restrict__ rp_c,
                      const int* __restrict__ rp_r,
                      int* __restrict__ cntz, int* __restrict__ colz) {
  int rel = blockIdx.y;
  const int* ei = rel == 0 ? ei_w : rel == 1 ? ei_c : ei_r;
  const int* dst = ei + E;
  const int* rp  = rel == 0 ? rp_w : rel == 1 ? rp_c : rp_r;
  int* cnt = cntz + rel * NPP;
  int* col = colz + rel * E;
  for (int e = blockIdx.x * blockDim.x + threadIdx.x; e < E; e += gridDim.x * blockDim.x) {
    int d = dst[e];
    int pos = atomicAdd(&cnt[d], 1);
    col[rp[d] + pos] = ei[e];          // store SOURCE node directly
  }
}

// 2-phase exclusive scan over three 100000-length deg arrays (contiguous)
__global__ __launch_bounds__(256) void scan_partial(const int* __restrict__ degz,
                                                    int* __restrict__ bsum) {
  int blk = blockIdx.x, rel = blk / 25, t25 = blk % 25;
  const int* deg = degz + rel * NPP + t25 * 4096;
  int nrem = min(4096, NPP - t25 * 4096);
  int base = threadIdx.x * 16;
  int s = 0;
  if (base < nrem) {
#pragma unroll
    for (int i4 = 0; i4 < 4; ++i4) {
      int4 v = *(const int4*)(deg + base + i4 * 4);
      s += v.x + v.y + v.z + v.w;
    }
  }
  __shared__ int sm[256];
  sm[threadIdx.x] = s; __syncthreads();
  for (int o = 128; o > 0; o >>= 1) {
    if (threadIdx.x < o) sm[threadIdx.x] += sm[threadIdx.x + o];
    __syncthreads();
  }
  if (threadIdx.x == 0) bsum[blk] = sm[0];
}
__global__ __launch_bounds__(256) void scan_final(const int* __restrict__ degz,
                                                  const int* __restrict__ bsum,
                                                  int* rp_w, int* rp_c, int* rp_r) {
  int blk = blockIdx.x, rel = blk / 25, t25 = blk % 25;
  const int* deg = degz + rel * NPP + t25 * 4096;
  int* rpb = (rel == 0 ? rp_w : rel == 1 ? rp_c : rp_r);
  int* rp = rpb + t25 * 4096;
  int boffv = 0;
  for (int i = 0; i < t25; ++i) boffv += bsum[rel * 25 + i];
  int nrem = min(4096, NPP - t25 * 4096);
  int base = threadIdx.x * 16;
  bool ok = base < nrem;
  int v[16]; int s = 0;
  if (ok) {
#pragma unroll
    for (int i4 = 0; i4 < 4; ++i4) {
      int4 u = *(const int4*)(deg + base + i4 * 4);
      v[i4*4+0] = u.x; v[i4*4+1] = u.y; v[i4*4+2] = u.z; v[i4*4+3] = u.w;
      s += u.x + u.y + u.z + u.w;
    }
  }
  __shared__ int sm[256];
  sm[threadIdx.x] = s; __syncthreads();
  for (int o = 1; o < 256; o <<= 1) {
    int x = (threadIdx.x >= o) ? sm[threadIdx.x - o] : 0;
    __syncthreads(); sm[threadIdx.x] += x; __syncthreads();
  }
  int run = boffv + sm[threadIdx.x] - s;
  if (ok) {
    int w[16];
#pragma unroll
    for (int i = 0; i < 16; ++i) { w[i] = run; run += v[i]; }
#pragma unroll
    for (int i4 = 0; i4 < 4; ++i4) *(int4*)(rp + base + i4 * 4) = *(const int4*)&w[i4*4];
  }
  if (t25 == 24 && threadIdx.x == 255) rpb[NPP] = boffv + sm[255];
}

extern "C" void kernel_launch(void* const* d_in, const int* in_sizes, int n_in,
                              void* d_out, int out_size, void* d_ws, size_t ws_size,
                              hipStream_t stream) {
  const float* x_a    = (const float*)d_in[0];
  const float* x_p    = (const float*)d_in[1];
  const int*   ei_w   = (const int*)d_in[2];
  const int*   ei_r   = (const int*)d_in[3];
  const int*   ei_c   = (const int*)d_in[4];
  const float* proj_w = (const float*)d_in[5];
  const float* proj_b = (const float*)d_in[6];
  const float* kqv_w  = (const float*)d_in[7];
  const float* kqv_b  = (const float*)d_in[8];
  const float* out_w  = (const float*)d_in[9];
  const float* out_b  = (const float*)d_in[10];
  const float* rel_a  = (const float*)d_in[11];
  const float* rel_m  = (const float*)d_in[12];
  const float* p_rel  = (const float*)d_in[13];
  const float* skip   = (const float*)d_in[14];
  const float* cls_w  = (const float*)d_in[15];
  const float* cls_b  = (const float*)d_in[16];
  float* out = (float*)d_out;

  const size_t NF = (size_t)NA * D;   // 12.8M
  float* ws    = (float*)d_ws;
  // fp32 region
  float* cw    = ws;                             // 12*D*D
  float* cb    = cw + 12 * D * D;                // 12*D
  // bf16 region
  ushort_t* h_a   = (ushort_t*)(cb + 12 * D);    // NF
  ushort_t* h_p   = h_a + NF;                    // NF
  ushort_t* b_q   = h_p + NF;                    // NF (author q/agg)
  ushort_t* b_q2  = b_q + NF;                    // NF (paper q/agg)
  ushort_t* b_kv  = b_q2 + NF;                   // 2*NF pair-interleaved
  ushort_t* b_kv2 = b_kv + 2 * NF;               // 2*NF (writes-relation kv)
  ushort_t* phi   = b_kv2 + 2 * NF;              // 23*SLOT_ELEMS
  ushort_t* plo   = phi + (size_t)NSLOT * SLOT_ELEMS;
  // int region
  int* ip    = (int*)(plo + (size_t)NSLOT * SLOT_ELEMS);
  int* rp_w  = ip;                      // NPP+1
  int* rp_c  = rp_w + (NPP + 1);
  int* rp_r  = rp_c + (NPP + 1);
  int* degz  = rp_r + (NA + 1);         // 3*NPP deg + 3*NPP cnt (contiguous)
  int* cntz  = degz + 3 * NPP;
  int* colz  = cntz + 3 * NPP;          // 3*E (src-node per CSR entry)
  int* bsum  = colz + 3 * E;            // 75
  size_t need_bytes = (size_t)((char*)(bsum + 128) - (char*)d_ws);
  if (ws_size < need_bytes) return;

  hipMemsetAsync(degz, 0, sizeof(int) * 6 * (size_t)NPP, stream);

  count3<<<dim3(256, 3), 256, 0, stream>>>(ei_w, ei_c, ei_r, degz);
  scan_partial<<<75, 256, 0, stream>>>(degz, bsum);
  scan_final<<<75, 256, 0, stream>>>(degz, bsum, rp_w, rp_c, rp_r);
  fill3<<<dim3(256, 3), 256, 0, stream>>>(ei_w, ei_c, ei_r, rp_w, rp_c, rp_r, cntz, colz);
  int* col_w = colz;
  int* col_c = colz + E;
  int* col_r = colz + 2 * E;

  combine_w<<<12, 256, 0, stream>>>(kqv_w, kqv_b, rel_a, rel_m, cw, cb);
  pack_b<<<NSLOT, 256, 0, stream>>>(proj_w, kqv_w, out_w, cls_w, cw, phi, plo);

  auto PH = [&](int s){ return phi + (size_t)s * SLOT_ELEMS; };
  auto PL = [&](int s){ return plo + (size_t)s * SLOT_ELEMS; };

  const dim3 G1(GB2c, 1), GQKV(GB2c, 3), GF(GB2c, 4);
  // initial projections (fp32 input, bf16 h out, A+B split for precision)
  gemm4<8, 128, 1, true, float><<<G1, 256, 0, stream>>>(
      x_a, PH(0), PL(0), proj_b,     h_a, NA);
  gemm4<8, 128, 1, true, float><<<G1, 256, 0, stream>>>(
      x_p, PH(1), PL(1), proj_b + D, h_p, NPP);

  for (int l = 0; l < L; ++l) {
    const int SQA = 2 + l * 10 + 0, SQP = 2 + l * 10 + 1;
    auto SKV = [&](int r){ return 2 + l * 10 + 2 + r * 2; };  // k slot; v slot = +1
    const int SO0 = 2 + l * 10 + 8, SO1 = 2 + l * 10 + 9;
    const float* bq_a = kqv_b + ((size_t)((l*3 + 1)*2 + 0)) * D;
    const float* bq_p = kqv_b + ((size_t)((l*3 + 1)*2 + 1)) * D;
    auto CB2 = [&](int r){ return cb + ((size_t)((l*R + r)*2)) * D; };  // 256 floats (k|v)
    const float* prelW = p_rel + (size_t)(l*R + 0) * H;
    const float* prelR = p_rel + (size_t)(l*R + 1) * H;
    const float* prelC = p_rel + (size_t)(l*R + 2) * H;

    // 1) author q (from h_a) + rev-writes kv1 (from h_p)
    gemm_qkv<<<GQKV, 256, 0, stream>>>(
        h_a, h_p, PH(SQA), PH(SKV(1)), bq_a, CB2(1), b_q, b_kv, NA);
    // 2) MEGA: author attention || writes-relation kv (h_a -> b_kv2)
    mega0<<<MEGA_G, 256, 0, stream>>>(
        rp_r, col_r, b_kv, b_q, prelR, b_q,
        h_a, PH(SKV(0)), CB2(0), b_kv2);
    // 3) FUSED: author out-mix (b_q->h_a) || paper q (h_p->b_q2) || cites kv (h_p->b_kv)
    fusedA<<<GF, 256, 0, stream>>>(
        b_q, PH(SO0), out_b + (size_t)(l*2 + 0) * D, h_a, skip + l*2 + 0,
        h_p, PH(SQP), bq_p, b_q2,
        PH(SKV(2)), CB2(2), b_kv);
    // 4) paper attention: joint softmax writes(b_kv2) + cites(b_kv)
    attn_p<<<GAc, 256, 0, stream>>>(
        rp_w, col_w, b_kv2, rp_c, col_c, b_kv,
        b_q2, prelW, prelC, b_q2);
    // 5) paper out-mix
    outmix<<<G1, 256, 0, stream>>>(
        b_q2, PH(SO1), out_b + (size_t)(l*2 + 1) * D, h_p, skip + l*2 + 1, NPP);
  }

  gemm4<3, 40, 0, true, ushort_t><<<G1, 256, 0, stream>>>(
      h_p, PH(22), PL(22), cls_b, out, NPP);
}

// Round 14
// 865.180 us; speedup vs baseline: 1.5193x; 1.0123x over previous
//
#include <hip/hip_runtime.h>
#include <hip/hip_bf16.h>
#include <math.h>

constexpr int NA  = 100000;
constexpr int NPP = 100000;
constexpr int D   = 128;
constexpr int H   = 4;
constexpr int E   = 400000;
constexpr int R   = 3;
constexpr int L   = 2;
constexpr int NSLOT = 23;
constexpr int SLOT_ELEMS = 8 * 4 * 512;   // 8 col-tiles * 4 ksteps * 512 bf16
constexpr int GB2c = (NA + 127) / 128;    // 782
constexpr int GAc  = NA / 8;              // 12500
constexpr int MEGA_G = 1564 * 9;          // fallback mega grid

using s8v = __attribute__((ext_vector_type(8))) short;
using f4v = __attribute__((ext_vector_type(4))) float;
typedef unsigned short ushort_t;

static __device__ __forceinline__ unsigned short f2bf(float f) {
  unsigned u = __float_as_uint(f);
  return (unsigned short)((u + 0x7fffu + ((u >> 16) & 1u)) >> 16);
}
static __device__ __forceinline__ float bf2f(unsigned short s) {
  return __uint_as_float(((unsigned)s) << 16);
}
static __device__ __forceinline__ float klo(int i) {        // low bf16 -> f32
  return __uint_as_float(((unsigned)i) << 16);
}
static __device__ __forceinline__ float vhi(int i) {        // high bf16 -> f32
  return __uint_as_float(((unsigned)i) & 0xffff0000u);
}
static __device__ __forceinline__ float gelu_f(float x) {
  return 0.5f * x * (1.0f + erff(x * 0.70710678118654752f));
}
static __device__ __forceinline__ float elu_f(float x) {
  return x > 0.0f ? x : expm1f(x);
}

// ============ device GEMM bodies (bf16 A, hi-only B, LDS-staged) ================
static __device__ __forceinline__ void load_a2(
    const ushort_t* __restrict__ A, int ar0, int ar1, int ks, int g,
    s8v& a0, s8v& a1) {
  const ushort_t* ap0 = A + (size_t)ar0 * 128 + ks * 32 + g * 4;
  ushort4 u0 = *(const ushort4*)ap0;
  ushort4 u1 = *(const ushort4*)(ap0 + 16);
  a0[0]=(short)u0.x; a0[1]=(short)u0.y; a0[2]=(short)u0.z; a0[3]=(short)u0.w;
  a0[4]=(short)u1.x; a0[5]=(short)u1.y; a0[6]=(short)u1.z; a0[7]=(short)u1.w;
  const ushort_t* ap1 = A + (size_t)ar1 * 128 + ks * 32 + g * 4;
  ushort4 v0 = *(const ushort4*)ap1;
  ushort4 v1 = *(const ushort4*)(ap1 + 16);
  a1[0]=(short)v0.x; a1[1]=(short)v0.y; a1[2]=(short)v0.z; a1[3]=(short)v0.w;
  a1[4]=(short)v1.x; a1[5]=(short)v1.y; a1[6]=(short)v1.z; a1[7]=(short)v1.w;
}

template<bool GELU_A, bool MIX>
__device__ __forceinline__ void dev_gemm8(
    const ushort_t* __restrict__ A, const ushort_t* __restrict__ Bhi,
    const float* __restrict__ bias, ushort_t* __restrict__ Cout,
    const float* __restrict__ skip_ptr, int M, int bx, ushort_t* Bs) {
  for (int i = threadIdx.x; i < 2048; i += 256)
    *(s8v*)&Bs[i * 8] = *(const s8v*)(Bhi + (size_t)i * 8);
  __syncthreads();
  const int lane = threadIdx.x & 63;
  const int wave = threadIdx.x >> 6;
  const int row0 = bx * 128 + wave * 32;
  const int g = lane >> 4, li = lane & 15;
  f4v acc0[8], acc1[8];
#pragma unroll
  for (int ct = 0; ct < 8; ++ct) {
    acc0[ct] = f4v{0.f, 0.f, 0.f, 0.f};
    acc1[ct] = f4v{0.f, 0.f, 0.f, 0.f};
  }
  int ar0 = row0 + li;       if (ar0 >= M) ar0 = M - 1;
  int ar1 = row0 + 16 + li;  if (ar1 >= M) ar1 = M - 1;
#pragma unroll
  for (int ks = 0; ks < 4; ++ks) {
    s8v a0, a1;
    load_a2(A, ar0, ar1, ks, g, a0, a1);
    if (GELU_A) {
#pragma unroll
      for (int i = 0; i < 8; ++i) {
        a0[i] = (short)f2bf(gelu_f(bf2f((unsigned short)a0[i])));
        a1[i] = (short)f2bf(gelu_f(bf2f((unsigned short)a1[i])));
      }
    }
#pragma unroll
    for (int ct = 0; ct < 8; ++ct) {
      s8v bhi = *(const s8v*)&Bs[(ct * 4 + ks) * 512 + lane * 8];
      acc0[ct] = __builtin_amdgcn_mfma_f32_16x16x32_bf16(a0, bhi, acc0[ct], 0, 0, 0);
      acc1[ct] = __builtin_amdgcn_mfma_f32_16x16x32_bf16(a1, bhi, acc1[ct], 0, 0, 0);
    }
  }
  float sskip = 0.f;
  if (MIX) sskip = 1.f / (1.f + __expf(-*skip_ptr));
#pragma unroll
  for (int rf = 0; rf < 2; ++rf) {
#pragma unroll
    for (int ct = 0; ct < 8; ++ct) {
      int col = ct * 16 + li;
      float bv = bias[col];
      f4v a = rf ? acc1[ct] : acc0[ct];
#pragma unroll
      for (int r = 0; r < 4; ++r) {
        int grow = row0 + rf * 16 + g * 4 + r;
        if (grow < M) {
          float v = a[r] + bv;
          size_t off = (size_t)grow * 128 + col;
          if constexpr (MIX) {
            float hprev = bf2f(Cout[off]);
            Cout[off] = f2bf(elu_f(sskip * v + (1.f - sskip) * hprev));
          } else {
            Cout[off] = f2bf(v);
          }
        }
      }
    }
  }
}

__device__ __forceinline__ void dev_gemm_kv(
    const ushort_t* __restrict__ A, const ushort_t* __restrict__ Bkv,
    const float* __restrict__ bias, ushort_t* __restrict__ kvout,
    int M, int bx, int ch, ushort_t* Bs) {
  for (int i = threadIdx.x; i < 2048; i += 256) {
    int kvh = i >> 10, j = i & 1023;
    const ushort_t* src = Bkv + (size_t)kvh * SLOT_ELEMS + ch * 8192 + j * 8;
    *(s8v*)&Bs[kvh * 8192 + j * 8] = *(const s8v*)src;
  }
  __syncthreads();
  const int lane = threadIdx.x & 63;
  const int wave = threadIdx.x >> 6;
  const int row0 = bx * 128 + wave * 32;
  const int g = lane >> 4, li = lane & 15;
  f4v acc0[8], acc1[8];                    // [0..3]=K, [4..7]=V
#pragma unroll
  for (int t = 0; t < 8; ++t) {
    acc0[t] = f4v{0.f, 0.f, 0.f, 0.f};
    acc1[t] = f4v{0.f, 0.f, 0.f, 0.f};
  }
  int ar0 = row0 + li;       if (ar0 >= M) ar0 = M - 1;
  int ar1 = row0 + 16 + li;  if (ar1 >= M) ar1 = M - 1;
#pragma unroll
  for (int ks = 0; ks < 4; ++ks) {
    s8v a0, a1;
    load_a2(A, ar0, ar1, ks, g, a0, a1);
#pragma unroll
    for (int t = 0; t < 4; ++t) {
      s8v kh = *(const s8v*)&Bs[(t * 4 + ks) * 512 + lane * 8];
      acc0[t] = __builtin_amdgcn_mfma_f32_16x16x32_bf16(a0, kh, acc0[t], 0, 0, 0);
      acc1[t] = __builtin_amdgcn_mfma_f32_16x16x32_bf16(a1, kh, acc1[t], 0, 0, 0);
      s8v vh = *(const s8v*)&Bs[8192 + (t * 4 + ks) * 512 + lane * 8];
      acc0[4 + t] = __builtin_amdgcn_mfma_f32_16x16x32_bf16(a0, vh, acc0[4 + t], 0, 0, 0);
      acc1[4 + t] = __builtin_amdgcn_mfma_f32_16x16x32_bf16(a1, vh, acc1[4 + t], 0, 0, 0);
    }
  }
#pragma unroll
  for (int rf = 0; rf < 2; ++rf) {
#pragma unroll
    for (int t = 0; t < 4; ++t) {
      int col = ch * 64 + t * 16 + li;
      float bk = bias[col], bv = bias[128 + col];
#pragma unroll
      for (int r = 0; r < 4; ++r) {
        int grow = row0 + rf * 16 + g * 4 + r;
        if (grow < M) {
          float kvl = rf ? acc1[t][r] : acc0[t][r];
          float vvl = rf ? acc1[4 + t][r] : acc0[4 + t][r];
          ushort2 o;
          o.x = f2bf(kvl + bk);
          o.y = f2bf(vvl + bv);
          *(ushort2*)(kvout + (size_t)grow * 256 + 2 * col) = o;
        }
      }
    }
  }
}

// ============ device attention body (2 dst/wave, virtual list, 4-deep) ==========
template<bool TWO>
__device__ __forceinline__ void dev_attn(
    const int* __restrict__ rp1, const int* __restrict__ col1,
    const ushort_t* __restrict__ kv1,
    const int* __restrict__ rp2, const int* __restrict__ col2,
    const ushort_t* __restrict__ kv2,
    const ushort_t* __restrict__ q,
    const float* __restrict__ prel1, const float* __restrict__ prel2,
    ushort_t* __restrict__ aggout, int ablk) {
  int lane = threadIdx.x & 63;
  int wave = threadIdx.x >> 6;
  int half = lane >> 5;
  int l32  = lane & 31;
  int dst  = ablk * 8 + wave * 2 + half;   // ndst % 8 == 0: no tail
  int head = l32 >> 3;
  const float scale = 0.17677669529663688f; // 1/sqrt(32)
  float pr1 = prel1[head] * scale;
  float pr2 = TWO ? prel2[head] * scale : pr1;
  ushort4 qv = *(const ushort4*)(q + (size_t)dst * D + l32 * 4);
  float q0 = bf2f(qv.x), q1 = bf2f(qv.y), q2 = bf2f(qv.z), q3 = bf2f(qv.w);
  int e0a = rp1[dst];
  int d1  = rp1[dst + 1] - e0a;
  int e0b = 0, dt = d1;
  if (TWO) { e0b = rp2[dst]; dt = d1 + (rp2[dst + 1] - e0b); }
  float z = 0.f, a0 = 0.f, a1 = 0.f, a2 = 0.f, a3 = 0.f;
  for (int jj = 0; jj < dt; jj += 4) {
    int4 us[4]; bool vs[4]; float prs[4];
#pragma unroll
    for (int s2 = 0; s2 < 4; ++s2) {
      int idx = jj + s2;
      bool v = idx < dt;
      bool f = (!TWO) || (idx < d1);
      int ci = 0;
      if (v) ci = f ? (e0a + idx) : (e0b + idx - d1);
      int src = f ? col1[ci] : col2[ci];
      const ushort_t* kvp = f ? kv1 : kv2;
      us[s2] = *(const int4*)(kvp + (size_t)src * 256 + l32 * 8);
      vs[s2] = v;
      prs[s2] = f ? pr1 : pr2;
    }
#pragma unroll
    for (int s2 = 0; s2 < 4; ++s2) {
      float p = q0 * klo(us[s2].x) + q1 * klo(us[s2].y)
              + q2 * klo(us[s2].z) + q3 * klo(us[s2].w);
      p += __shfl_xor(p, 1);
      p += __shfl_xor(p, 2);
      p += __shfl_xor(p, 4);
      float e = vs[s2] ? __expf(p * prs[s2]) : 0.f;
      z  += e;
      a0 += e * vhi(us[s2].x);
      a1 += e * vhi(us[s2].y);
      a2 += e * vhi(us[s2].z);
      a3 += e * vhi(us[s2].w);
    }
  }
  float inv = 1.f / (z + 1e-16f);
  ushort4 o;
  o.x = f2bf(a0 * inv);
  o.y = f2bf(a1 * inv);
  o.z = f2bf(a2 * inv);
  o.w = f2bf(a3 * inv);
  *(ushort4*)(aggout + (size_t)dst * D + l32 * 4) = o;
}

// =============== merged-path kernels (3 launches / layer) =======================
// bigGEMM: y0 q_a | y1 q_p | y2,3 kv_rev | y4,5 kv_writes | y6,7 kv_cites
__global__ __launch_bounds__(256, 4) void biggemm(
    const ushort_t* __restrict__ h_a, const ushort_t* __restrict__ h_p,
    const ushort_t* __restrict__ Bqa, const ushort_t* __restrict__ Bqp,
    const ushort_t* __restrict__ BkvR, const ushort_t* __restrict__ BkvW,
    const ushort_t* __restrict__ BkvC,
    const float* __restrict__ bqa, const float* __restrict__ bqp,
    const float* __restrict__ cbR, const float* __restrict__ cbW,
    const float* __restrict__ cbC,
    ushort_t* __restrict__ b_q, ushort_t* __restrict__ b_q2,
    ushort_t* __restrict__ kvR, ushort_t* __restrict__ kvW,
    ushort_t* __restrict__ kvC) {
  __shared__ ushort_t Bs[16384];
  int y = blockIdx.y;
  if (y == 0)      dev_gemm8<false, false>(h_a, Bqa, bqa, b_q,  nullptr, NA,  blockIdx.x, Bs);
  else if (y == 1) dev_gemm8<false, false>(h_p, Bqp, bqp, b_q2, nullptr, NPP, blockIdx.x, Bs);
  else if (y <= 3) dev_gemm_kv(h_p, BkvR, cbR, kvR, NPP, blockIdx.x, y - 2, Bs);
  else if (y <= 5) dev_gemm_kv(h_a, BkvW, cbW, kvW, NA,  blockIdx.x, y - 4, Bs);
  else             dev_gemm_kv(h_p, BkvC, cbC, kvC, NPP, blockIdx.x, y - 6, Bs);
}

// bigATTN: parity-interleaved author (odd) + paper (even); 2*GAc blocks
__global__ __launch_bounds__(256, 8) void bigattn(
    const int* __restrict__ rp_r, const int* __restrict__ col_r,
    const ushort_t* __restrict__ kvR, ushort_t* __restrict__ q_a,
    const int* __restrict__ rp_w, const int* __restrict__ col_w,
    const ushort_t* __restrict__ kvW,
    const int* __restrict__ rp_c, const int* __restrict__ col_c,
    const ushort_t* __restrict__ kvC, ushort_t* __restrict__ q_p,
    const float* __restrict__ prelR, const float* __restrict__ prelW,
    const float* __restrict__ prelC) {
  unsigned x = blockIdx.x;
  if (x & 1)
    dev_attn<false>(rp_r, col_r, kvR, nullptr, nullptr, nullptr,
                    q_a, prelR, prelR, q_a, (int)(x >> 1));
  else
    dev_attn<true>(rp_w, col_w, kvW, rp_c, col_c, kvC,
                   q_p, prelW, prelC, q_p, (int)(x >> 1));
}

// bigMIX: y0 author out-mix | y1 paper out-mix
__global__ __launch_bounds__(256, 4) void bigmix(
    const ushort_t* __restrict__ agg_a, const ushort_t* __restrict__ Bo0,
    const float* __restrict__ ob0, ushort_t* __restrict__ h_a,
    const float* __restrict__ sk0,
    const ushort_t* __restrict__ agg_p, const ushort_t* __restrict__ Bo1,
    const float* __restrict__ ob1, ushort_t* __restrict__ h_p,
    const float* __restrict__ sk1) {
  __shared__ ushort_t Bs[16384];
  if (blockIdx.y == 0) dev_gemm8<true, true>(agg_a, Bo0, ob0, h_a, sk0, NA,  blockIdx.x, Bs);
  else                 dev_gemm8<true, true>(agg_p, Bo1, ob1, h_p, sk1, NPP, blockIdx.x, Bs);
}

// =============== fallback-path kernels (round-13 structure) =====================
__global__ __launch_bounds__(256, 8) void attn_p(
    const int* __restrict__ rp1, const int* __restrict__ col1,
    const ushort_t* __restrict__ kv1,
    const int* __restrict__ rp2, const int* __restrict__ col2,
    const ushort_t* __restrict__ kv2,
    const ushort_t* __restrict__ q,
    const float* __restrict__ prel1, const float* __restrict__ prel2,
    ushort_t* __restrict__ aggout) {
  dev_attn<true>(rp1, col1, kv1, rp2, col2, kv2, q, prel1, prel2, aggout, blockIdx.x);
}

__global__ __launch_bounds__(256, 4) void mega0(
    const int* __restrict__ rp_r, const int* __restrict__ col_r,
    const ushort_t* __restrict__ kv1, const ushort_t* __restrict__ q,
    const float* __restrict__ prelR, ushort_t* __restrict__ aggout,
    const ushort_t* __restrict__ h_a, const ushort_t* __restrict__ Bkv0,
    const float* __restrict__ cb0, ushort_t* __restrict__ kv2out) {
  __shared__ ushort_t Bs[16384];
  unsigned gidx = blockIdx.x;
  if (gidx % 9 == 0) {
    int gb = gidx / 9;
    dev_gemm_kv(h_a, Bkv0, cb0, kv2out, NA, gb >> 1, gb & 1, Bs);
  } else {
    int ablk = gidx - gidx / 9 - 1;
    if (ablk < GAc)
      dev_attn<false>(rp_r, col_r, kv1, nullptr, nullptr, nullptr,
                      q, prelR, prelR, aggout, ablk);
  }
}

__global__ __launch_bounds__(256, 4) void fusedA(
    const ushort_t* __restrict__ agg_a, const ushort_t* __restrict__ Bout,
    const float* __restrict__ out_b0, ushort_t* __restrict__ h_a,
    const float* __restrict__ skip0,
    const ushort_t* __restrict__ h_p, const ushort_t* __restrict__ Bq,
    const float* __restrict__ bq_p, ushort_t* __restrict__ qout,
    const ushort_t* __restrict__ Bkv, const float* __restrict__ cb2,
    ushort_t* __restrict__ kvout) {
  __shared__ ushort_t Bs[16384];
  if (blockIdx.y == 0) {
    dev_gemm8<true, true>(agg_a, Bout, out_b0, h_a, skip0, NA, blockIdx.x, Bs);
  } else if (blockIdx.y == 1) {
    dev_gemm8<false, false>(h_p, Bq, bq_p, qout, nullptr, NPP, blockIdx.x, Bs);
  } else {
    dev_gemm_kv(h_p, Bkv, cb2, kvout, NPP, blockIdx.x, blockIdx.y - 2, Bs);
  }
}

__global__ __launch_bounds__(256, 4) void gemm_qkv(
    const ushort_t* __restrict__ Aq, const ushort_t* __restrict__ Akv,
    const ushort_t* __restrict__ Bq, const ushort_t* __restrict__ Bkv,
    const float* __restrict__ bias_q, const float* __restrict__ bias_kv,
    ushort_t* __restrict__ qout, ushort_t* __restrict__ kvout, int M) {
  __shared__ ushort_t Bs[16384];
  if (blockIdx.y == 0)
    dev_gemm8<false, false>(Aq, Bq, bias_q, qout, nullptr, M, blockIdx.x, Bs);
  else
    dev_gemm_kv(Akv, Bkv, bias_kv, kvout, M, blockIdx.x, blockIdx.y - 1, Bs);
}

__global__ __launch_bounds__(256, 4) void outmix(
    const ushort_t* __restrict__ agg, const ushort_t* __restrict__ Bout,
    const float* __restrict__ out_b1, ushort_t* __restrict__ h,
    const float* __restrict__ skip1, int M) {
  __shared__ ushort_t Bs[16384];
  dev_gemm8<true, true>(agg, Bout, out_b1, h, skip1, M, blockIdx.x, Bs);
}

// =============== fp32-A GEMM (proj; BLO) and cls ================================
template<int NT16, int NCOLS, int STORE, bool BLO, typename TA>
__global__ __launch_bounds__(256, 4) void gemm4(
    const TA* __restrict__ A,
    const ushort_t* __restrict__ Bhi, const ushort_t* __restrict__ Blo,
    const float* __restrict__ bias, void* __restrict__ Cv, int M) {
  constexpr int HN = NT16 * 2048;
  __shared__ ushort_t Bs[HN * (BLO ? 2 : 1)];
  constexpr bool AFP32 = sizeof(TA) == 4;
  for (int i = threadIdx.x; i < (HN / 8) * (BLO ? 2 : 1); i += 256) {
    int half = i / (HN / 8), j = i % (HN / 8);
    const ushort_t* src = (half ? Blo : Bhi) + (size_t)j * 8;
    *(s8v*)&Bs[half * HN + j * 8] = *(const s8v*)src;
  }
  __syncthreads();
  const int lane = threadIdx.x & 63;
  const int wave = threadIdx.x >> 6;
  const int row0 = blockIdx.x * 128 + wave * 32;
  const int g = lane >> 4, li = lane & 15;
  f4v acc0[NT16], acc1[NT16];
#pragma unroll
  for (int ct = 0; ct < NT16; ++ct) {
    acc0[ct] = f4v{0.f, 0.f, 0.f, 0.f};
    acc1[ct] = f4v{0.f, 0.f, 0.f, 0.f};
  }
  int ar0 = row0 + li;       if (ar0 >= M) ar0 = M - 1;
  int ar1 = row0 + 16 + li;  if (ar1 >= M) ar1 = M - 1;
#pragma unroll
  for (int ks = 0; ks < 4; ++ks) {
    s8v ahi[2], alo[2];
#pragma unroll
    for (int rf = 0; rf < 2; ++rf) {
      int ar = rf ? ar1 : ar0;
      if constexpr (AFP32) {
        const float* ap = (const float*)A + (size_t)ar * 128 + ks * 32 + g * 4;
        float4 u0 = *(const float4*)ap;
        float4 u1 = *(const float4*)(ap + 16);
        float x[8] = {u0.x, u0.y, u0.z, u0.w, u1.x, u1.y, u1.z, u1.w};
#pragma unroll
        for (int i = 0; i < 8; ++i) {
          unsigned short h = f2bf(x[i]);
          ahi[rf][i] = (short)h;
          alo[rf][i] = (short)f2bf(x[i] - bf2f(h));
        }
      } else {
        const ushort_t* ap = (const ushort_t*)A + (size_t)ar * 128 + ks * 32 + g * 4;
        ushort4 u0 = *(const ushort4*)ap;
        ushort4 u1 = *(const ushort4*)(ap + 16);
        ahi[rf][0]=(short)u0.x; ahi[rf][1]=(short)u0.y; ahi[rf][2]=(short)u0.z; ahi[rf][3]=(short)u0.w;
        ahi[rf][4]=(short)u1.x; ahi[rf][5]=(short)u1.y; ahi[rf][6]=(short)u1.z; ahi[rf][7]=(short)u1.w;
      }
    }
#pragma unroll
    for (int ct = 0; ct < NT16; ++ct) {
      const ushort_t* bp = &Bs[(ct * 4 + ks) * 512 + lane * 8];
      s8v bhi = *(const s8v*)bp;
      acc0[ct] = __builtin_amdgcn_mfma_f32_16x16x32_bf16(ahi[0], bhi, acc0[ct], 0, 0, 0);
      acc1[ct] = __builtin_amdgcn_mfma_f32_16x16x32_bf16(ahi[1], bhi, acc1[ct], 0, 0, 0);
      if constexpr (BLO) {
        s8v blo = *(const s8v*)(bp + HN);
        if constexpr (AFP32) {
          acc0[ct] = __builtin_amdgcn_mfma_f32_16x16x32_bf16(alo[0], bhi, acc0[ct], 0, 0, 0);
          acc1[ct] = __builtin_amdgcn_mfma_f32_16x16x32_bf16(alo[1], bhi, acc1[ct], 0, 0, 0);
        }
        acc0[ct] = __builtin_amdgcn_mfma_f32_16x16x32_bf16(ahi[0], blo, acc0[ct], 0, 0, 0);
        acc1[ct] = __builtin_amdgcn_mfma_f32_16x16x32_bf16(ahi[1], blo, acc1[ct], 0, 0, 0);
      }
    }
  }
#pragma unroll
  for (int rf = 0; rf < 2; ++rf) {
#pragma unroll
    for (int ct = 0; ct < NT16; ++ct) {
      int col = ct * 16 + li;
      bool colok = (col < NCOLS);
      float bv = colok ? bias[col] : 0.f;
      f4v a = rf ? acc1[ct] : acc0[ct];
#pragma unroll
      for (int r = 0; r < 4; ++r) {
        int grow = row0 + rf * 16 + g * 4 + r;
        if (grow < M && colok) {
          float v = a[r] + bv;
          size_t off = (size_t)grow * NCOLS + col;
          if constexpr (STORE == 1) ((ushort_t*)Cv)[off] = f2bf(v);
          else                      ((float*)Cv)[off] = v;
        }
      }
    }
  }
}

// ------------- combined weights: cw = W @ blockdiag(rel), cb = b @ blockdiag(rel)
__global__ __launch_bounds__(256) void combine_w(
    const float* __restrict__ kqv_w, const float* __restrict__ kqv_b,
    const float* __restrict__ rel_a, const float* __restrict__ rel_m,
    float* __restrict__ cw, float* __restrict__ cb) {
  int b  = blockIdx.x;            // ((l*R)+r)*2+kv
  int kv = b & 1;
  int r  = (b >> 1) % R;
  int l  = b / (2 * R);
  int t_src = (r == 0) ? 0 : 1;
  int i_w   = (kv == 0) ? 0 : 2;
  const float* W    = kqv_w + ((size_t)((l*3 + i_w)*2 + t_src)) * D * D;
  const float* bvec = kqv_b + ((size_t)((l*3 + i_w)*2 + t_src)) * D;
  const float* rel  = ((kv == 0) ? rel_a : rel_m) + ((size_t)(l*R + r)) * H * 32 * 32;
  float* Cout = cw + (size_t)b * D * D;
  float* cbo  = cb + (size_t)b * D;
  for (int idx = threadIdx.x; idx < D * D; idx += 256) {
    int i = idx / D, j = idx % D;
    int h = j >> 5, f = j & 31;
    const float* relh = rel + h * 32 * 32;
    float sum = 0.f;
#pragma unroll
    for (int d = 0; d < 32; ++d) sum += W[i*D + (h*32 + d)] * relh[d*32 + f];
    Cout[idx] = sum;
  }
  if (threadIdx.x < D) {
    int j = threadIdx.x;
    int h = j >> 5, f = j & 31;
    const float* relh = rel + h * 32 * 32;
    float sum = 0.f;
#pragma unroll
    for (int d = 0; d < 32; ++d) sum += bvec[h*32 + d] * relh[d*32 + f];
    cbo[j] = sum;
  }
}

// ------------- pack weight matrices into MFMA-fragment order (hi/lo split) -------
__global__ __launch_bounds__(256) void pack_b(
    const float* __restrict__ proj_w, const float* __restrict__ kqv_w,
    const float* __restrict__ out_w, const float* __restrict__ cls_w,
    const float* __restrict__ cw,
    ushort_t* __restrict__ phi, ushort_t* __restrict__ plo) {
  int slot = blockIdx.x;
  const float* src; int ncol = 128;
  if (slot == 0) src = proj_w;
  else if (slot == 1) src = proj_w + D * D;
  else if (slot == 22) { src = cls_w; ncol = 40; }
  else {
    int l = (slot - 2) / 10, k = (slot - 2) % 10;
    if (k == 0)      src = kqv_w + ((size_t)((l*3 + 1)*2 + 0)) * D * D;
    else if (k == 1) src = kqv_w + ((size_t)((l*3 + 1)*2 + 1)) * D * D;
    else if (k < 8)  { int idx = k - 2; src = cw + ((size_t)((l*R)*2 + idx)) * D * D; }
    else             src = out_w + ((size_t)(l*2 + (k - 8))) * D * D;
  }
  int nt = (ncol + 15) / 16;
  int total = nt * 4 * 512;
  ushort_t* ph = phi + (size_t)slot * SLOT_ELEMS;
  ushort_t* pl = plo + (size_t)slot * SLOT_ELEMS;
  for (int idx = threadIdx.x; idx < total; idx += 256) {
    int j = idx & 7, lane = (idx >> 3) & 63, ks = (idx >> 9) & 3, ct = idx >> 11;
    int k = 4 * (lane >> 4) + (j & 3) + 16 * (j >> 2) + 32 * ks;
    int n = ct * 16 + (lane & 15);
    float v = (n < ncol) ? src[(size_t)k * ncol + n] : 0.f;
    unsigned short h = f2bf(v);
    ph[idx] = h;
    pl[idx] = f2bf(v - bf2f(h));
  }
}

// ---------------- CSR build (global-atomic; measured best at this size) ---------
__global__ void count3(const int* __restrict__ ei_w, const int* __restrict__ ei_c,
                       const int* __restrict__ ei_r, int* __restrict__ degz) {
  const int* dst = blockIdx.y == 0 ? ei_w + E : blockIdx.y == 1 ? ei_c + E : ei_r + E;
  int* deg = degz + blockIdx.y * NPP;
  for (int e = blockIdx.x * blockDim.x + threadIdx.x; e < E; e += gridDim.x * blockDim.x)
    atomicAdd(&deg[dst[e]], 1);
}
__global__ void fill3(const int* __restrict__ ei_w, const int* __restrict__ ei_c,
                      const int* __restrict__ ei_r,
                      const int* __restrict__ rp_w, const int* __restrict__ rp_c,
                      const int* __restrict__ rp_r,
                      int* __restrict__ cntz, int* __restrict__ colz) {
  int rel = blockIdx.y;
  const int* ei = rel == 0 ? ei_w : rel == 1 ? ei_c : ei_r;
  const int* dst = ei + E;
  const int* rp  = rel == 0 ? rp_w : rel == 1 ? rp_c : rp_r;
  int* cnt = cntz + rel * NPP;
  int* col = colz + rel * E;
  for (int e = blockIdx.x * blockDim.x + threadIdx.x; e < E; e += gridDim.x * blockDim.x) {
    int d = dst[e];
    int pos = atomicAdd(&cnt[d], 1);
    col[rp[d] + pos] = ei[e];          // store SOURCE node directly
  }
}

__global__ __launch_bounds__(256) void scan_partial(const int* __restrict__ degz,
                                                    int* __restrict__ bsum) {
  int blk = blockIdx.x, rel = blk / 25, t25 = blk % 25;
  const int* deg = degz + rel * NPP + t25 * 4096;
  int nrem = min(4096, NPP - t25 * 4096);
  int base = threadIdx.x * 16;
  int s = 0;
  if (base < nrem) {
#pragma unroll
    for (int i4 = 0; i4 < 4; ++i4) {
      int4 v = *(const int4*)(deg + base + i4 * 4);
      s += v.x + v.y + v.z + v.w;
    }
  }
  __shared__ int sm[256];
  sm[threadIdx.x] = s; __syncthreads();
  for (int o = 128; o > 0; o >>= 1) {
    if (threadIdx.x < o) sm[threadIdx.x] += sm[threadIdx.x + o];
    __syncthreads();
  }
  if (threadIdx.x == 0) bsum[blk] = sm[0];
}
__global__ __launch_bounds__(256) void scan_final(const int* __restrict__ degz,
                                                  const int* __restrict__ bsum,
                                                  int* rp_w, int* rp_c, int* rp_r) {
  int blk = blockIdx.x, rel = blk / 25, t25 = blk % 25;
  const int* deg = degz + rel * NPP + t25 * 4096;
  int* rpb = (rel == 0 ? rp_w : rel == 1 ? rp_c : rp_r);
  int* rp = rpb + t25 * 4096;
  int boffv = 0;
  for (int i = 0; i < t25; ++i) boffv += bsum[rel * 25 + i];
  int nrem = min(4096, NPP - t25 * 4096);
  int base = threadIdx.x * 16;
  bool ok = base < nrem;
  int v[16]; int s = 0;
  if (ok) {
#pragma unroll
    for (int i4 = 0; i4 < 4; ++i4) {
      int4 u = *(const int4*)(deg + base + i4 * 4);
      v[i4*4+0] = u.x; v[i4*4+1] = u.y; v[i4*4+2] = u.z; v[i4*4+3] = u.w;
      s += u.x + u.y + u.z + u.w;
    }
  }
  __shared__ int sm[256];
  sm[threadIdx.x] = s; __syncthreads();
  for (int o = 1; o < 256; o <<= 1) {
    int x = (threadIdx.x >= o) ? sm[threadIdx.x - o] : 0;
    __syncthreads(); sm[threadIdx.x] += x; __syncthreads();
  }
  int run = boffv + sm[threadIdx.x] - s;
  if (ok) {
    int w[16];
#pragma unroll
    for (int i = 0; i < 16; ++i) { w[i] = run; run += v[i]; }
#pragma unroll
    for (int i4 = 0; i4 < 4; ++i4) *(int4*)(rp + base + i4 * 4) = *(const int4*)&w[i4*4];
  }
  if (t25 == 24 && threadIdx.x == 255) rpb[NPP] = boffv + sm[255];
}

extern "C" void kernel_launch(void* const* d_in, const int* in_sizes, int n_in,
                              void* d_out, int out_size, void* d_ws, size_t ws_size,
                              hipStream_t stream) {
  const float* x_a    = (const float*)d_in[0];
  const float* x_p    = (const float*)d_in[1];
  const int*   ei_w   = (const int*)d_in[2];
  const int*   ei_r   = (const int*)d_in[3];
  const int*   ei_c   = (const int*)d_in[4];
  const float* proj_w = (const float*)d_in[5];
  const float* proj_b = (const float*)d_in[6];
  const float* kqv_w  = (const float*)d_in[7];
  const float* kqv_b  = (const float*)d_in[8];
  const float* out_w  = (const float*)d_in[9];
  const float* out_b  = (const float*)d_in[10];
  const float* rel_a  = (const float*)d_in[11];
  const float* rel_m  = (const float*)d_in[12];
  const float* p_rel  = (const float*)d_in[13];
  const float* skip   = (const float*)d_in[14];
  const float* cls_w  = (const float*)d_in[15];
  const float* cls_b  = (const float*)d_in[16];
  float* out = (float*)d_out;

  const size_t NF = (size_t)NA * D;   // 12.8M
  // ---- layout: decide 2 vs 3 KV buffers by ws_size ----
  const size_t head_b = (size_t)(12 * D * D + 12 * D) * 4 + 4 * NF * 2; // cw,cb,h_a,h_p,b_q,b_q2
  const size_t kv_b   = 2 * NF * 2;
  const size_t rest_b = 2 * (size_t)NSLOT * SLOT_ELEMS * 2 +
                        sizeof(int) * ((size_t)3 * (NPP + 1) + 6 * NPP + 3 * E + 128);
  const bool use3 = ws_size >= head_b + 3 * kv_b + rest_b;
  if (!use3 && ws_size < head_b + 2 * kv_b + rest_b) return;

  char* p = (char*)d_ws;
  float* cw = (float*)p;              p += (size_t)12 * D * D * 4;
  float* cb = (float*)p;              p += (size_t)12 * D * 4;
  ushort_t* h_a   = (ushort_t*)p;     p += NF * 2;
  ushort_t* h_p   = (ushort_t*)p;     p += NF * 2;
  ushort_t* b_q   = (ushort_t*)p;     p += NF * 2;
  ushort_t* b_q2  = (ushort_t*)p;     p += NF * 2;
  ushort_t* b_kvR = (ushort_t*)p;     p += 2 * NF * 2;
  ushort_t* b_kvW = (ushort_t*)p;     p += 2 * NF * 2;
  ushort_t* b_kvC = nullptr;
  if (use3) { b_kvC = (ushort_t*)p;   p += 2 * NF * 2; }
  ushort_t* phi = (ushort_t*)p;       p += (size_t)NSLOT * SLOT_ELEMS * 2;
  ushort_t* plo = (ushort_t*)p;       p += (size_t)NSLOT * SLOT_ELEMS * 2;
  int* rp_w = (int*)p;                p += (NPP + 1) * 4;
  int* rp_c = (int*)p;                p += (NPP + 1) * 4;
  int* rp_r = (int*)p;                p += (NA + 1) * 4;
  int* degz = (int*)p;                p += (size_t)3 * NPP * 4;
  int* cntz = (int*)p;                p += (size_t)3 * NPP * 4;
  int* colz = (int*)p;                p += (size_t)3 * E * 4;
  int* bsum = (int*)p;

  hipMemsetAsync(degz, 0, sizeof(int) * 6 * (size_t)NPP, stream);

  count3<<<dim3(256, 3), 256, 0, stream>>>(ei_w, ei_c, ei_r, degz);
  scan_partial<<<75, 256, 0, stream>>>(degz, bsum);
  scan_final<<<75, 256, 0, stream>>>(degz, bsum, rp_w, rp_c, rp_r);
  fill3<<<dim3(256, 3), 256, 0, stream>>>(ei_w, ei_c, ei_r, rp_w, rp_c, rp_r, cntz, colz);
  int* col_w = colz;
  int* col_c = colz + E;
  int* col_r = colz + 2 * E;

  combine_w<<<12, 256, 0, stream>>>(kqv_w, kqv_b, rel_a, rel_m, cw, cb);
  pack_b<<<NSLOT, 256, 0, stream>>>(proj_w, kqv_w, out_w, cls_w, cw, phi, plo);

  auto PH = [&](int s){ return phi + (size_t)s * SLOT_ELEMS; };
  auto PL = [&](int s){ return plo + (size_t)s * SLOT_ELEMS; };

  const dim3 G1(GB2c, 1);
  gemm4<8, 128, 1, true, float><<<G1, 256, 0, stream>>>(
      x_a, PH(0), PL(0), proj_b,     h_a, NA);
  gemm4<8, 128, 1, true, float><<<G1, 256, 0, stream>>>(
      x_p, PH(1), PL(1), proj_b + D, h_p, NPP);

  for (int l = 0; l < L; ++l) {
    const int SQA = 2 + l * 10 + 0, SQP = 2 + l * 10 + 1;
    auto SKV = [&](int r){ return 2 + l * 10 + 2 + r * 2; };
    const int SO0 = 2 + l * 10 + 8, SO1 = 2 + l * 10 + 9;
    const float* bq_a = kqv_b + ((size_t)((l*3 + 1)*2 + 0)) * D;
    const float* bq_p = kqv_b + ((size_t)((l*3 + 1)*2 + 1)) * D;
    auto CB2 = [&](int r){ return cb + ((size_t)((l*R + r)*2)) * D; };
    const float* prelW = p_rel + (size_t)(l*R + 0) * H;
    const float* prelR = p_rel + (size_t)(l*R + 1) * H;
    const float* prelC = p_rel + (size_t)(l*R + 2) * H;

    if (use3) {
      // ---- merged 3-launch layer ----
      biggemm<<<dim3(GB2c, 8), 256, 0, stream>>>(
          h_a, h_p, PH(SQA), PH(SQP), PH(SKV(1)), PH(SKV(0)), PH(SKV(2)),
          bq_a, bq_p, CB2(1), CB2(0), CB2(2),
          b_q, b_q2, b_kvR, b_kvW, b_kvC);
      bigattn<<<2 * GAc, 256, 0, stream>>>(
          rp_r, col_r, b_kvR, b_q,
          rp_w, col_w, b_kvW, rp_c, col_c, b_kvC, b_q2,
          prelR, prelW, prelC);
      bigmix<<<dim3(GB2c, 2), 256, 0, stream>>>(
          b_q,  PH(SO0), out_b + (size_t)(l*2 + 0) * D, h_a, skip + l*2 + 0,
          b_q2, PH(SO1), out_b + (size_t)(l*2 + 1) * D, h_p, skip + l*2 + 1);
    } else {
      // ---- fallback: round-13 5-launch layer (2 KV buffers) ----
      gemm_qkv<<<dim3(GB2c, 3), 256, 0, stream>>>(
          h_a, h_p, PH(SQA), PH(SKV(1)), bq_a, CB2(1), b_q, b_kvR, NA);
      mega0<<<MEGA_G, 256, 0, stream>>>(
          rp_r, col_r, b_kvR, b_q, prelR, b_q,
          h_a, PH(SKV(0)), CB2(0), b_kvW);
      fusedA<<<dim3(GB2c, 4), 256, 0, stream>>>(
          b_q, PH(SO0), out_b + (size_t)(l*2 + 0) * D, h_a, skip + l*2 + 0,
          h_p, PH(SQP), bq_p, b_q2,
          PH(SKV(2)), CB2(2), b_kvR);
      attn_p<<<GAc, 256, 0, stream>>>(
          rp_w, col_w, b_kvW, rp_c, col_c, b_kvR,
          b_q2, prelW, prelC, b_q2);
      outmix<<<G1, 256, 0, stream>>>(
          b_q2, PH(SO1), out_b + (size_t)(l*2 + 1) * D, h_p, skip + l*2 + 1, NPP);
    }
  }

  gemm4<3, 40, 0, true, ushort_t><<<G1, 256, 0, stream>>>(
      h_p, PH(22), PL(22), cls_b, out, NPP);
}

// Round 15
// 799.881 us; speedup vs baseline: 1.6433x; 1.0816x over previous
//
#include <hip/hip_runtime.h>
#include <hip/hip_bf16.h>
#include <math.h>

constexpr int NA  = 100000;
constexpr int NPP = 100000;
constexpr int D   = 128;
constexpr int H   = 4;
constexpr int E   = 400000;
constexpr int R   = 3;
constexpr int L   = 2;
constexpr int NSLOT = 23;
constexpr int SLOT_ELEMS = 8 * 4 * 512;   // 8 col-tiles * 4 ksteps * 512 bf16
constexpr int GB2c = (NA + 127) / 128;    // 782
constexpr int GAc  = NA / 8;              // 12500

using s8v = __attribute__((ext_vector_type(8))) short;
using f4v = __attribute__((ext_vector_type(4))) float;
typedef unsigned short ushort_t;

static __device__ __forceinline__ unsigned short f2bf(float f) {
  unsigned u = __float_as_uint(f);
  return (unsigned short)((u + 0x7fffu + ((u >> 16) & 1u)) >> 16);
}
static __device__ __forceinline__ float bf2f(unsigned short s) {
  return __uint_as_float(((unsigned)s) << 16);
}
static __device__ __forceinline__ float klo(int i) {        // low bf16 -> f32
  return __uint_as_float(((unsigned)i) << 16);
}
static __device__ __forceinline__ float vhi(int i) {        // high bf16 -> f32
  return __uint_as_float(((unsigned)i) & 0xffff0000u);
}
static __device__ __forceinline__ float gelu_f(float x) {
  return 0.5f * x * (1.0f + erff(x * 0.70710678118654752f));
}
static __device__ __forceinline__ float elu_f(float x) {
  return x > 0.0f ? x : expm1f(x);
}

// ============ device GEMM bodies (bf16 A, hi-only B, LDS-staged) ================
static __device__ __forceinline__ void load_a2(
    const ushort_t* __restrict__ A, int ar0, int ar1, int ks, int g,
    s8v& a0, s8v& a1) {
  const ushort_t* ap0 = A + (size_t)ar0 * 128 + ks * 32 + g * 4;
  ushort4 u0 = *(const ushort4*)ap0;
  ushort4 u1 = *(const ushort4*)(ap0 + 16);
  a0[0]=(short)u0.x; a0[1]=(short)u0.y; a0[2]=(short)u0.z; a0[3]=(short)u0.w;
  a0[4]=(short)u1.x; a0[5]=(short)u1.y; a0[6]=(short)u1.z; a0[7]=(short)u1.w;
  const ushort_t* ap1 = A + (size_t)ar1 * 128 + ks * 32 + g * 4;
  ushort4 v0 = *(const ushort4*)ap1;
  ushort4 v1 = *(const ushort4*)(ap1 + 16);
  a1[0]=(short)v0.x; a1[1]=(short)v0.y; a1[2]=(short)v0.z; a1[3]=(short)v0.w;
  a1[4]=(short)v1.x; a1[5]=(short)v1.y; a1[6]=(short)v1.z; a1[7]=(short)v1.w;
}

template<bool GELU_A, bool MIX>
__device__ __forceinline__ void dev_gemm8(
    const ushort_t* __restrict__ A, const ushort_t* __restrict__ Bhi,
    const float* __restrict__ bias, ushort_t* __restrict__ Cout,
    const float* __restrict__ skip_ptr, int M, int bx, ushort_t* Bs) {
  for (int i = threadIdx.x; i < 2048; i += 256)
    *(s8v*)&Bs[i * 8] = *(const s8v*)(Bhi + (size_t)i * 8);
  __syncthreads();
  const int lane = threadIdx.x & 63;
  const int wave = threadIdx.x >> 6;
  const int row0 = bx * 128 + wave * 32;
  const int g = lane >> 4, li = lane & 15;
  f4v acc0[8], acc1[8];
#pragma unroll
  for (int ct = 0; ct < 8; ++ct) {
    acc0[ct] = f4v{0.f, 0.f, 0.f, 0.f};
    acc1[ct] = f4v{0.f, 0.f, 0.f, 0.f};
  }
  int ar0 = row0 + li;       if (ar0 >= M) ar0 = M - 1;
  int ar1 = row0 + 16 + li;  if (ar1 >= M) ar1 = M - 1;
#pragma unroll
  for (int ks = 0; ks < 4; ++ks) {
    s8v a0, a1;
    load_a2(A, ar0, ar1, ks, g, a0, a1);
    if (GELU_A) {
#pragma unroll
      for (int i = 0; i < 8; ++i) {
        a0[i] = (short)f2bf(gelu_f(bf2f((unsigned short)a0[i])));
        a1[i] = (short)f2bf(gelu_f(bf2f((unsigned short)a1[i])));
      }
    }
#pragma unroll
    for (int ct = 0; ct < 8; ++ct) {
      s8v bhi = *(const s8v*)&Bs[(ct * 4 + ks) * 512 + lane * 8];
      acc0[ct] = __builtin_amdgcn_mfma_f32_16x16x32_bf16(a0, bhi, acc0[ct], 0, 0, 0);
      acc1[ct] = __builtin_amdgcn_mfma_f32_16x16x32_bf16(a1, bhi, acc1[ct], 0, 0, 0);
    }
  }
  float sskip = 0.f;
  if (MIX) sskip = 1.f / (1.f + __expf(-*skip_ptr));
#pragma unroll
  for (int rf = 0; rf < 2; ++rf) {
#pragma unroll
    for (int ct = 0; ct < 8; ++ct) {
      int col = ct * 16 + li;
      float bv = bias[col];
      f4v a = rf ? acc1[ct] : acc0[ct];
#pragma unroll
      for (int r = 0; r < 4; ++r) {
        int grow = row0 + rf * 16 + g * 4 + r;
        if (grow < M) {
          float v = a[r] + bv;
          size_t off = (size_t)grow * 128 + col;
          if constexpr (MIX) {
            float hprev = bf2f(Cout[off]);
            Cout[off] = f2bf(elu_f(sskip * v + (1.f - sskip) * hprev));
          } else {
            Cout[off] = f2bf(v);
          }
        }
      }
    }
  }
}

__device__ __forceinline__ void dev_gemm_kv(
    const ushort_t* __restrict__ A, const ushort_t* __restrict__ Bkv,
    const float* __restrict__ bias, ushort_t* __restrict__ kvout,
    int M, int bx, int ch, ushort_t* Bs) {
  for (int i = threadIdx.x; i < 2048; i += 256) {
    int kvh = i >> 10, j = i & 1023;
    const ushort_t* src = Bkv + (size_t)kvh * SLOT_ELEMS + ch * 8192 + j * 8;
    *(s8v*)&Bs[kvh * 8192 + j * 8] = *(const s8v*)src;
  }
  __syncthreads();
  const int lane = threadIdx.x & 63;
  const int wave = threadIdx.x >> 6;
  const int row0 = bx * 128 + wave * 32;
  const int g = lane >> 4, li = lane & 15;
  f4v acc0[8], acc1[8];                    // [0..3]=K, [4..7]=V
#pragma unroll
  for (int t = 0; t < 8; ++t) {
    acc0[t] = f4v{0.f, 0.f, 0.f, 0.f};
    acc1[t] = f4v{0.f, 0.f, 0.f, 0.f};
  }
  int ar0 = row0 + li;       if (ar0 >= M) ar0 = M - 1;
  int ar1 = row0 + 16 + li;  if (ar1 >= M) ar1 = M - 1;
#pragma unroll
  for (int ks = 0; ks < 4; ++ks) {
    s8v a0, a1;
    load_a2(A, ar0, ar1, ks, g, a0, a1);
#pragma unroll
    for (int t = 0; t < 4; ++t) {
      s8v kh = *(const s8v*)&Bs[(t * 4 + ks) * 512 + lane * 8];
      acc0[t] = __builtin_amdgcn_mfma_f32_16x16x32_bf16(a0, kh, acc0[t], 0, 0, 0);
      acc1[t] = __builtin_amdgcn_mfma_f32_16x16x32_bf16(a1, kh, acc1[t], 0, 0, 0);
      s8v vh = *(const s8v*)&Bs[8192 + (t * 4 + ks) * 512 + lane * 8];
      acc0[4 + t] = __builtin_amdgcn_mfma_f32_16x16x32_bf16(a0, vh, acc0[4 + t], 0, 0, 0);
      acc1[4 + t] = __builtin_amdgcn_mfma_f32_16x16x32_bf16(a1, vh, acc1[4 + t], 0, 0, 0);
    }
  }
#pragma unroll
  for (int rf = 0; rf < 2; ++rf) {
#pragma unroll
    for (int t = 0; t < 4; ++t) {
      int col = ch * 64 + t * 16 + li;
      float bk = bias[col], bv = bias[128 + col];
#pragma unroll
      for (int r = 0; r < 4; ++r) {
        int grow = row0 + rf * 16 + g * 4 + r;
        if (grow < M) {
          float kvl = rf ? acc1[t][r] : acc0[t][r];
          float vvl = rf ? acc1[4 + t][r] : acc0[4 + t][r];
          ushort2 o;
          o.x = f2bf(kvl + bk);
          o.y = f2bf(vvl + bv);
          *(ushort2*)(kvout + (size_t)grow * 256 + 2 * col) = o;
        }
      }
    }
  }
}

// fp32-A proj body (A hi/lo + B hi/lo split, 3 MFMAs/tile, bf16 out); needs 64KB Bs
__device__ __forceinline__ void dev_proj(
    const float* __restrict__ A, const ushort_t* __restrict__ Bhi,
    const ushort_t* __restrict__ Blo, const float* __restrict__ bias,
    ushort_t* __restrict__ Cout, int M, int bx, ushort_t* Bs) {
  for (int i = threadIdx.x; i < 4096; i += 256) {
    int half = i >> 11, j = i & 2047;
    const ushort_t* src = (half ? Blo : Bhi) + (size_t)j * 8;
    *(s8v*)&Bs[half * 16384 + j * 8] = *(const s8v*)src;
  }
  __syncthreads();
  const int lane = threadIdx.x & 63;
  const int wave = threadIdx.x >> 6;
  const int row0 = bx * 128 + wave * 32;
  const int g = lane >> 4, li = lane & 15;
  f4v acc0[8], acc1[8];
#pragma unroll
  for (int ct = 0; ct < 8; ++ct) {
    acc0[ct] = f4v{0.f, 0.f, 0.f, 0.f};
    acc1[ct] = f4v{0.f, 0.f, 0.f, 0.f};
  }
  int ar0 = row0 + li;       if (ar0 >= M) ar0 = M - 1;
  int ar1 = row0 + 16 + li;  if (ar1 >= M) ar1 = M - 1;
#pragma unroll
  for (int ks = 0; ks < 4; ++ks) {
    s8v ahi[2], alo[2];
#pragma unroll
    for (int rf = 0; rf < 2; ++rf) {
      int ar = rf ? ar1 : ar0;
      const float* ap = A + (size_t)ar * 128 + ks * 32 + g * 4;
      float4 u0 = *(const float4*)ap;
      float4 u1 = *(const float4*)(ap + 16);
      float x[8] = {u0.x, u0.y, u0.z, u0.w, u1.x, u1.y, u1.z, u1.w};
#pragma unroll
      for (int i = 0; i < 8; ++i) {
        unsigned short h = f2bf(x[i]);
        ahi[rf][i] = (short)h;
        alo[rf][i] = (short)f2bf(x[i] - bf2f(h));
      }
    }
#pragma unroll
    for (int ct = 0; ct < 8; ++ct) {
      const ushort_t* bp = &Bs[(ct * 4 + ks) * 512 + lane * 8];
      s8v bhi = *(const s8v*)bp;
      s8v blo = *(const s8v*)(bp + 16384);
      acc0[ct] = __builtin_amdgcn_mfma_f32_16x16x32_bf16(ahi[0], bhi, acc0[ct], 0, 0, 0);
      acc1[ct] = __builtin_amdgcn_mfma_f32_16x16x32_bf16(ahi[1], bhi, acc1[ct], 0, 0, 0);
      acc0[ct] = __builtin_amdgcn_mfma_f32_16x16x32_bf16(alo[0], bhi, acc0[ct], 0, 0, 0);
      acc1[ct] = __builtin_amdgcn_mfma_f32_16x16x32_bf16(alo[1], bhi, acc1[ct], 0, 0, 0);
      acc0[ct] = __builtin_amdgcn_mfma_f32_16x16x32_bf16(ahi[0], blo, acc0[ct], 0, 0, 0);
      acc1[ct] = __builtin_amdgcn_mfma_f32_16x16x32_bf16(ahi[1], blo, acc1[ct], 0, 0, 0);
    }
  }
#pragma unroll
  for (int rf = 0; rf < 2; ++rf) {
#pragma unroll
    for (int ct = 0; ct < 8; ++ct) {
      int col = ct * 16 + li;
      float bv = bias[col];
      f4v a = rf ? acc1[ct] : acc0[ct];
#pragma unroll
      for (int r = 0; r < 4; ++r) {
        int grow = row0 + rf * 16 + g * 4 + r;
        if (grow < M) Cout[(size_t)grow * 128 + col] = f2bf(a[r] + bv);
      }
    }
  }
}

// ============ device attention body (2 dst/wave, virtual list, 4-deep) ==========
template<bool TWO>
__device__ __forceinline__ void dev_attn(
    const int* __restrict__ rp1, const int* __restrict__ col1,
    const ushort_t* __restrict__ kv1,
    const int* __restrict__ rp2, const int* __restrict__ col2,
    const ushort_t* __restrict__ kv2,
    const ushort_t* __restrict__ q,
    const float* __restrict__ prel1, const float* __restrict__ prel2,
    ushort_t* __restrict__ aggout, int ablk) {
  int lane = threadIdx.x & 63;
  int wave = threadIdx.x >> 6;
  int half = lane >> 5;
  int l32  = lane & 31;
  int dst  = ablk * 8 + wave * 2 + half;   // ndst % 8 == 0: no tail
  int head = l32 >> 3;
  const float scale = 0.17677669529663688f; // 1/sqrt(32)
  float pr1 = prel1[head] * scale;
  float pr2 = TWO ? prel2[head] * scale : pr1;
  ushort4 qv = *(const ushort4*)(q + (size_t)dst * D + l32 * 4);
  float q0 = bf2f(qv.x), q1 = bf2f(qv.y), q2 = bf2f(qv.z), q3 = bf2f(qv.w);
  int e0a = rp1[dst];
  int d1  = rp1[dst + 1] - e0a;
  int e0b = 0, dt = d1;
  if (TWO) { e0b = rp2[dst]; dt = d1 + (rp2[dst + 1] - e0b); }
  float z = 0.f, a0 = 0.f, a1 = 0.f, a2 = 0.f, a3 = 0.f;
  for (int jj = 0; jj < dt; jj += 4) {
    int4 us[4]; bool vs[4]; float prs[4];
#pragma unroll
    for (int s2 = 0; s2 < 4; ++s2) {
      int idx = jj + s2;
      bool v = idx < dt;
      bool f = (!TWO) || (idx < d1);
      int ci = 0;
      if (v) ci = f ? (e0a + idx) : (e0b + idx - d1);
      int src = f ? col1[ci] : col2[ci];
      const ushort_t* kvp = f ? kv1 : kv2;
      us[s2] = *(const int4*)(kvp + (size_t)src * 256 + l32 * 8);
      vs[s2] = v;
      prs[s2] = f ? pr1 : pr2;
    }
#pragma unroll
    for (int s2 = 0; s2 < 4; ++s2) {
      float p = q0 * klo(us[s2].x) + q1 * klo(us[s2].y)
              + q2 * klo(us[s2].z) + q3 * klo(us[s2].w);
      p += __shfl_xor(p, 1);
      p += __shfl_xor(p, 2);
      p += __shfl_xor(p, 4);
      float e = vs[s2] ? __expf(p * prs[s2]) : 0.f;
      z  += e;
      a0 += e * vhi(us[s2].x);
      a1 += e * vhi(us[s2].y);
      a2 += e * vhi(us[s2].z);
      a3 += e * vhi(us[s2].w);
    }
  }
  float inv = 1.f / (z + 1e-16f);
  ushort4 o;
  o.x = f2bf(a0 * inv);
  o.y = f2bf(a1 * inv);
  o.z = f2bf(a2 * inv);
  o.w = f2bf(a3 * inv);
  *(ushort4*)(aggout + (size_t)dst * D + l32 * 4) = o;
}

// ============ device CSR-build bodies ===========================================
__device__ __forceinline__ void dev_count(const int* __restrict__ dst,
                                          int* __restrict__ deg, int bidx) {
  for (int e = bidx * 256 + (int)threadIdx.x; e < E; e += 256 * 256)
    atomicAdd(&deg[dst[e]], 1);
}
__device__ __forceinline__ void dev_fill(const int* __restrict__ ei,
                                         const int* __restrict__ rp,
                                         int* __restrict__ cnt,
                                         int* __restrict__ col, int bidx) {
  const int* dst = ei + E;
  for (int e = bidx * 256 + (int)threadIdx.x; e < E; e += 256 * 256) {
    int d = dst[e];
    int pos = atomicAdd(&cnt[d], 1);
    col[rp[d] + pos] = ei[e];
  }
}

// =============== global kernels =================================================
// fusedProj: proj_a || proj_p || count3 (3-way interleave: b%3==2 -> count)
__global__ __launch_bounds__(256, 2) void fusedProj(
    const float* __restrict__ x_a, const float* __restrict__ x_p,
    const ushort_t* __restrict__ B0h, const ushort_t* __restrict__ B0l,
    const ushort_t* __restrict__ B1h, const ushort_t* __restrict__ B1l,
    const float* __restrict__ proj_b,
    ushort_t* __restrict__ h_a, ushort_t* __restrict__ h_p,
    const int* __restrict__ ei_w, const int* __restrict__ ei_c,
    const int* __restrict__ ei_r, int* __restrict__ degz) {
  __shared__ ushort_t Bs[32768];
  unsigned b = blockIdx.x;
  if (b % 3 == 2) {
    int ci = b / 3;
    if (ci < 768) {
      int rel = ci >> 8, sub = ci & 255;
      const int* dst = rel == 0 ? ei_w + E : rel == 1 ? ei_c + E : ei_r + E;
      dev_count(dst, degz + rel * NPP, sub);
    }
  } else {
    int gi = b - (b + 1) / 3;
    if (gi < GB2c) dev_proj(x_a, B0h, B0l, proj_b,     h_a, NA,  gi, Bs);
    else           dev_proj(x_p, B1h, B1l, proj_b + D, h_p, NPP, gi - GB2c, Bs);
  }
}

// bigGEMM slices: s0 q_a | s1 q_p | s2,3 kv_rev | s4,5 kv_writes | s6,7 kv_cites
__device__ __forceinline__ void dev_biggemm_slice(
    int slice, int bx,
    const ushort_t* h_a, const ushort_t* h_p,
    const ushort_t* Bqa, const ushort_t* Bqp,
    const ushort_t* BkvR, const ushort_t* BkvW, const ushort_t* BkvC,
    const float* bqa, const float* bqp,
    const float* cbR, const float* cbW, const float* cbC,
    ushort_t* b_q, ushort_t* b_q2,
    ushort_t* kvR, ushort_t* kvW, ushort_t* kvC, ushort_t* Bs) {
  if (slice == 0)      dev_gemm8<false, false>(h_a, Bqa, bqa, b_q,  nullptr, NA,  bx, Bs);
  else if (slice == 1) dev_gemm8<false, false>(h_p, Bqp, bqp, b_q2, nullptr, NPP, bx, Bs);
  else if (slice <= 3) dev_gemm_kv(h_p, BkvR, cbR, kvR, NPP, bx, slice - 2, Bs);
  else if (slice <= 5) dev_gemm_kv(h_a, BkvW, cbW, kvW, NA,  bx, slice - 4, Bs);
  else                 dev_gemm_kv(h_p, BkvC, cbC, kvC, NPP, bx, slice - 6, Bs);
}

__global__ __launch_bounds__(256, 4) void biggemm(
    const ushort_t* __restrict__ h_a, const ushort_t* __restrict__ h_p,
    const ushort_t* __restrict__ Bqa, const ushort_t* __restrict__ Bqp,
    const ushort_t* __restrict__ BkvR, const ushort_t* __restrict__ BkvW,
    const ushort_t* __restrict__ BkvC,
    const float* __restrict__ bqa, const float* __restrict__ bqp,
    const float* __restrict__ cbR, const float* __restrict__ cbW,
    const float* __restrict__ cbC,
    ushort_t* __restrict__ b_q, ushort_t* __restrict__ b_q2,
    ushort_t* __restrict__ kvR, ushort_t* __restrict__ kvW,
    ushort_t* __restrict__ kvC) {
  __shared__ ushort_t Bs[16384];
  dev_biggemm_slice(blockIdx.y, blockIdx.x, h_a, h_p, Bqa, Bqp, BkvR, BkvW, BkvC,
                    bqa, bqp, cbR, cbW, cbC, b_q, b_q2, kvR, kvW, kvC, Bs);
}

// fusedFill (layer 0): biggemm (8*782 blocks) || fill3 (768 blocks), 9-way interleave
__global__ __launch_bounds__(256, 4) void fusedFill(
    const ushort_t* __restrict__ h_a, const ushort_t* __restrict__ h_p,
    const ushort_t* __restrict__ Bqa, const ushort_t* __restrict__ Bqp,
    const ushort_t* __restrict__ BkvR, const ushort_t* __restrict__ BkvW,
    const ushort_t* __restrict__ BkvC,
    const float* __restrict__ bqa, const float* __restrict__ bqp,
    const float* __restrict__ cbR, const float* __restrict__ cbW,
    const float* __restrict__ cbC,
    ushort_t* __restrict__ b_q, ushort_t* __restrict__ b_q2,
    ushort_t* __restrict__ kvR, ushort_t* __restrict__ kvW,
    ushort_t* __restrict__ kvC,
    const int* __restrict__ ei_w, const int* __restrict__ ei_c,
    const int* __restrict__ ei_r,
    const int* __restrict__ rp_w, const int* __restrict__ rp_c,
    const int* __restrict__ rp_r,
    int* __restrict__ cntz, int* __restrict__ colz) {
  __shared__ ushort_t Bs[16384];
  unsigned b = blockIdx.x;
  if (b % 9 == 8) {
    int fi = b / 9;
    if (fi < 768) {
      int rel = fi >> 8, sub = fi & 255;
      const int* ei = rel == 0 ? ei_w : rel == 1 ? ei_c : ei_r;
      const int* rp = rel == 0 ? rp_w : rel == 1 ? rp_c : rp_r;
      dev_fill(ei, rp, cntz + rel * NPP, colz + rel * E, sub);
    }
  } else {
    int gi = b - (b + 1) / 9;
    int slice = gi & 7, bx = gi >> 3;
    if (bx < GB2c)
      dev_biggemm_slice(slice, bx, h_a, h_p, Bqa, Bqp, BkvR, BkvW, BkvC,
                        bqa, bqp, cbR, cbW, cbC, b_q, b_q2, kvR, kvW, kvC, Bs);
  }
}

// bigATTN: parity-interleaved author (odd) + paper (even); 2*GAc blocks
__global__ __launch_bounds__(256, 8) void bigattn(
    const int* __restrict__ rp_r, const int* __restrict__ col_r,
    const ushort_t* __restrict__ kvR, ushort_t* __restrict__ q_a,
    const int* __restrict__ rp_w, const int* __restrict__ col_w,
    const ushort_t* __restrict__ kvW,
    const int* __restrict__ rp_c, const int* __restrict__ col_c,
    const ushort_t* __restrict__ kvC, ushort_t* __restrict__ q_p,
    const float* __restrict__ prelR, const float* __restrict__ prelW,
    const float* __restrict__ prelC) {
  unsigned x = blockIdx.x;
  if (x & 1)
    dev_attn<false>(rp_r, col_r, kvR, nullptr, nullptr, nullptr,
                    q_a, prelR, prelR, q_a, (int)(x >> 1));
  else
    dev_attn<true>(rp_w, col_w, kvW, rp_c, col_c, kvC,
                   q_p, prelW, prelC, q_p, (int)(x >> 1));
}

// bigMIX: y0 author out-mix | y1 paper out-mix
__global__ __launch_bounds__(256, 4) void bigmix(
    const ushort_t* __restrict__ agg_a, const ushort_t* __restrict__ Bo0,
    const float* __restrict__ ob0, ushort_t* __restrict__ h_a,
    const float* __restrict__ sk0,
    const ushort_t* __restrict__ agg_p, const ushort_t* __restrict__ Bo1,
    const float* __restrict__ ob1, ushort_t* __restrict__ h_p,
    const float* __restrict__ sk1) {
  __shared__ ushort_t Bs[16384];
  if (blockIdx.y == 0) dev_gemm8<true, true>(agg_a, Bo0, ob0, h_a, sk0, NA,  blockIdx.x, Bs);
  else                 dev_gemm8<true, true>(agg_p, Bo1, ob1, h_p, sk1, NPP, blockIdx.x, Bs);
}

// cls: bf16 A, B hi/lo, fp32 out, 3 col tiles (40 cols)
__global__ __launch_bounds__(256, 4) void gemm_cls(
    const ushort_t* __restrict__ A,
    const ushort_t* __restrict__ Bhi, const ushort_t* __restrict__ Blo,
    const float* __restrict__ bias, float* __restrict__ Cv, int M) {
  constexpr int NT16 = 3;
  constexpr int HN = NT16 * 2048;
  __shared__ ushort_t Bs[HN * 2];
  for (int i = threadIdx.x; i < (HN / 8) * 2; i += 256) {
    int half = i / (HN / 8), j = i % (HN / 8);
    const ushort_t* src = (half ? Blo : Bhi) + (size_t)j * 8;
    *(s8v*)&Bs[half * HN + j * 8] = *(const s8v*)src;
  }
  __syncthreads();
  const int lane = threadIdx.x & 63;
  const int wave = threadIdx.x >> 6;
  const int row0 = blockIdx.x * 128 + wave * 32;
  const int g = lane >> 4, li = lane & 15;
  f4v acc0[NT16], acc1[NT16];
#pragma unroll
  for (int ct = 0; ct < NT16; ++ct) {
    acc0[ct] = f4v{0.f, 0.f, 0.f, 0.f};
    acc1[ct] = f4v{0.f, 0.f, 0.f, 0.f};
  }
  int ar0 = row0 + li;       if (ar0 >= M) ar0 = M - 1;
  int ar1 = row0 + 16 + li;  if (ar1 >= M) ar1 = M - 1;
#pragma unroll
  for (int ks = 0; ks < 4; ++ks) {
    s8v a0, a1;
    load_a2(A, ar0, ar1, ks, g, a0, a1);
#pragma unroll
    for (int ct = 0; ct < NT16; ++ct) {
      const ushort_t* bp = &Bs[(ct * 4 + ks) * 512 + lane * 8];
      s8v bhi = *(const s8v*)bp;
      s8v blo = *(const s8v*)(bp + HN);
      acc0[ct] = __builtin_amdgcn_mfma_f32_16x16x32_bf16(a0, bhi, acc0[ct], 0, 0, 0);
      acc1[ct] = __builtin_amdgcn_mfma_f32_16x16x32_bf16(a1, bhi, acc1[ct], 0, 0, 0);
      acc0[ct] = __builtin_amdgcn_mfma_f32_16x16x32_bf16(a0, blo, acc0[ct], 0, 0, 0);
      acc1[ct] = __builtin_amdgcn_mfma_f32_16x16x32_bf16(a1, blo, acc1[ct], 0, 0, 0);
    }
  }
#pragma unroll
  for (int rf = 0; rf < 2; ++rf) {
#pragma unroll
    for (int ct = 0; ct < NT16; ++ct) {
      int col = ct * 16 + li;
      bool colok = (col < 40);
      float bv = colok ? bias[col] : 0.f;
      f4v a = rf ? acc1[ct] : acc0[ct];
#pragma unroll
      for (int r = 0; r < 4; ++r) {
        int grow = row0 + rf * 16 + g * 4 + r;
        if (grow < M && colok) Cv[(size_t)grow * 40 + col] = a[r] + bv;
      }
    }
  }
}

// ------------- combined weights: cw = W @ blockdiag(rel), cb = b @ blockdiag(rel)
__global__ __launch_bounds__(256) void combine_w(
    const float* __restrict__ kqv_w, const float* __restrict__ kqv_b,
    const float* __restrict__ rel_a, const float* __restrict__ rel_m,
    float* __restrict__ cw, float* __restrict__ cb) {
  int b  = blockIdx.x;            // ((l*R)+r)*2+kv
  int kv = b & 1;
  int r  = (b >> 1) % R;
  int l  = b / (2 * R);
  int t_src = (r == 0) ? 0 : 1;
  int i_w   = (kv == 0) ? 0 : 2;
  const float* W    = kqv_w + ((size_t)((l*3 + i_w)*2 + t_src)) * D * D;
  const float* bvec = kqv_b + ((size_t)((l*3 + i_w)*2 + t_src)) * D;
  const float* rel  = ((kv == 0) ? rel_a : rel_m) + ((size_t)(l*R + r)) * H * 32 * 32;
  float* Cout = cw + (size_t)b * D * D;
  float* cbo  = cb + (size_t)b * D;
  for (int idx = threadIdx.x; idx < D * D; idx += 256) {
    int i = idx / D, j = idx % D;
    int h = j >> 5, f = j & 31;
    const float* relh = rel + h * 32 * 32;
    float sum = 0.f;
#pragma unroll
    for (int d = 0; d < 32; ++d) sum += W[i*D + (h*32 + d)] * relh[d*32 + f];
    Cout[idx] = sum;
  }
  if (threadIdx.x < D) {
    int j = threadIdx.x;
    int h = j >> 5, f = j & 31;
    const float* relh = rel + h * 32 * 32;
    float sum = 0.f;
#pragma unroll
    for (int d = 0; d < 32; ++d) sum += bvec[h*32 + d] * relh[d*32 + f];
    cbo[j] = sum;
  }
}

// ------------- pack weight matrices into MFMA-fragment order (hi/lo split) -------
__global__ __launch_bounds__(256) void pack_b(
    const float* __restrict__ proj_w, const float* __restrict__ kqv_w,
    const float* __restrict__ out_w, const float* __restrict__ cls_w,
    const float* __restrict__ cw,
    ushort_t* __restrict__ phi, ushort_t* __restrict__ plo) {
  int slot = blockIdx.x;
  const float* src; int ncol = 128;
  if (slot == 0) src = proj_w;
  else if (slot == 1) src = proj_w + D * D;
  else if (slot == 22) { src = cls_w; ncol = 40; }
  else {
    int l = (slot - 2) / 10, k = (slot - 2) % 10;
    if (k == 0)      src = kqv_w + ((size_t)((l*3 + 1)*2 + 0)) * D * D;
    else if (k == 1) src = kqv_w + ((size_t)((l*3 + 1)*2 + 1)) * D * D;
    else if (k < 8)  { int idx = k - 2; src = cw + ((size_t)((l*R)*2 + idx)) * D * D; }
    else             src = out_w + ((size_t)(l*2 + (k - 8))) * D * D;
  }
  int nt = (ncol + 15) / 16;
  int total = nt * 4 * 512;
  ushort_t* ph = phi + (size_t)slot * SLOT_ELEMS;
  ushort_t* pl = plo + (size_t)slot * SLOT_ELEMS;
  for (int idx = threadIdx.x; idx < total; idx += 256) {
    int j = idx & 7, lane = (idx >> 3) & 63, ks = (idx >> 9) & 3, ct = idx >> 11;
    int k = 4 * (lane >> 4) + (j & 3) + 16 * (j >> 2) + 32 * ks;
    int n = ct * 16 + (lane & 15);
    float v = (n < ncol) ? src[(size_t)k * ncol + n] : 0.f;
    unsigned short h = f2bf(v);
    ph[idx] = h;
    pl[idx] = f2bf(v - bf2f(h));
  }
}

// ---------------- scans ---------------------------------------------------------
__global__ __launch_bounds__(256) void scan_partial(const int* __restrict__ degz,
                                                    int* __restrict__ bsum) {
  int blk = blockIdx.x, rel = blk / 25, t25 = blk % 25;
  const int* deg = degz + rel * NPP + t25 * 4096;
  int nrem = min(4096, NPP - t25 * 4096);
  int base = threadIdx.x * 16;
  int s = 0;
  if (base < nrem) {
#pragma unroll
    for (int i4 = 0; i4 < 4; ++i4) {
      int4 v = *(const int4*)(deg + base + i4 * 4);
      s += v.x + v.y + v.z + v.w;
    }
  }
  __shared__ int sm[256];
  sm[threadIdx.x] = s; __syncthreads();
  for (int o = 128; o > 0; o >>= 1) {
    if (threadIdx.x < o) sm[threadIdx.x] += sm[threadIdx.x + o];
    __syncthreads();
  }
  if (threadIdx.x == 0) bsum[blk] = sm[0];
}
__global__ __launch_bounds__(256) void scan_final(const int* __restrict__ degz,
                                                  const int* __restrict__ bsum,
                                                  int* rp_w, int* rp_c, int* rp_r) {
  int blk = blockIdx.x, rel = blk / 25, t25 = blk % 25;
  const int* deg = degz + rel * NPP + t25 * 4096;
  int* rpb = (rel == 0 ? rp_w : rel == 1 ? rp_c : rp_r);
  int* rp = rpb + t25 * 4096;
  int boffv = 0;
  for (int i = 0; i < t25; ++i) boffv += bsum[rel * 25 + i];
  int nrem = min(4096, NPP - t25 * 4096);
  int base = threadIdx.x * 16;
  bool ok = base < nrem;
  int v[16]; int s = 0;
  if (ok) {
#pragma unroll
    for (int i4 = 0; i4 < 4; ++i4) {
      int4 u = *(const int4*)(deg + base + i4 * 4);
      v[i4*4+0] = u.x; v[i4*4+1] = u.y; v[i4*4+2] = u.z; v[i4*4+3] = u.w;
      s += u.x + u.y + u.z + u.w;
    }
  }
  __shared__ int sm[256];
  sm[threadIdx.x] = s; __syncthreads();
  for (int o = 1; o < 256; o <<= 1) {
    int x = (threadIdx.x >= o) ? sm[threadIdx.x - o] : 0;
    __syncthreads(); sm[threadIdx.x] += x; __syncthreads();
  }
  int run = boffv + sm[threadIdx.x] - s;
  if (ok) {
    int w[16];
#pragma unroll
    for (int i = 0; i < 16; ++i) { w[i] = run; run += v[i]; }
#pragma unroll
    for (int i4 = 0; i4 < 4; ++i4) *(int4*)(rp + base + i4 * 4) = *(const int4*)&w[i4*4];
  }
  if (t25 == 24 && threadIdx.x == 255) rpb[NPP] = boffv + sm[255];
}

extern "C" void kernel_launch(void* const* d_in, const int* in_sizes, int n_in,
                              void* d_out, int out_size, void* d_ws, size_t ws_size,
                              hipStream_t stream) {
  const float* x_a    = (const float*)d_in[0];
  const float* x_p    = (const float*)d_in[1];
  const int*   ei_w   = (const int*)d_in[2];
  const int*   ei_r   = (const int*)d_in[3];
  const int*   ei_c   = (const int*)d_in[4];
  const float* proj_w = (const float*)d_in[5];
  const float* proj_b = (const float*)d_in[6];
  const float* kqv_w  = (const float*)d_in[7];
  const float* kqv_b  = (const float*)d_in[8];
  const float* out_w  = (const float*)d_in[9];
  const float* out_b  = (const float*)d_in[10];
  const float* rel_a  = (const float*)d_in[11];
  const float* rel_m  = (const float*)d_in[12];
  const float* p_rel  = (const float*)d_in[13];
  const float* skip   = (const float*)d_in[14];
  const float* cls_w  = (const float*)d_in[15];
  const float* cls_b  = (const float*)d_in[16];
  float* out = (float*)d_out;

  const size_t NF = (size_t)NA * D;   // 12.8M
  char* p = (char*)d_ws;
  float* cw = (float*)p;              p += (size_t)12 * D * D * 4;
  float* cb = (float*)p;              p += (size_t)12 * D * 4;
  ushort_t* h_a   = (ushort_t*)p;     p += NF * 2;
  ushort_t* h_p   = (ushort_t*)p;     p += NF * 2;
  ushort_t* b_q   = (ushort_t*)p;     p += NF * 2;
  ushort_t* b_q2  = (ushort_t*)p;     p += NF * 2;
  ushort_t* b_kvR = (ushort_t*)p;     p += 2 * NF * 2;
  ushort_t* b_kvW = (ushort_t*)p;     p += 2 * NF * 2;
  ushort_t* b_kvC = (ushort_t*)p;     p += 2 * NF * 2;
  ushort_t* phi = (ushort_t*)p;       p += (size_t)NSLOT * SLOT_ELEMS * 2;
  ushort_t* plo = (ushort_t*)p;       p += (size_t)NSLOT * SLOT_ELEMS * 2;
  int* rp_w = (int*)p;                p += (NPP + 1) * 4;
  int* rp_c = (int*)p;                p += (NPP + 1) * 4;
  int* rp_r = (int*)p;                p += (NA + 1) * 4;
  int* degz = (int*)p;                p += (size_t)3 * NPP * 4;
  int* cntz = (int*)p;                p += (size_t)3 * NPP * 4;
  int* colz = (int*)p;                p += (size_t)3 * E * 4;
  int* bsum = (int*)p;                p += 128 * 4;
  if (ws_size < (size_t)(p - (char*)d_ws)) return;   // graceful fail

  hipMemsetAsync(degz, 0, sizeof(int) * 6 * (size_t)NPP, stream);

  combine_w<<<12, 256, 0, stream>>>(kqv_w, kqv_b, rel_a, rel_m, cw, cb);
  pack_b<<<NSLOT, 256, 0, stream>>>(proj_w, kqv_w, out_w, cls_w, cw, phi, plo);

  auto PH = [&](int s){ return phi + (size_t)s * SLOT_ELEMS; };
  auto PL = [&](int s){ return plo + (size_t)s * SLOT_ELEMS; };

  // proj_a || proj_p || count3  (2346 blocks, 3-way interleave)
  fusedProj<<<2346, 256, 0, stream>>>(
      x_a, x_p, PH(0), PL(0), PH(1), PL(1), proj_b, h_a, h_p,
      ei_w, ei_c, ei_r, degz);
  scan_partial<<<75, 256, 0, stream>>>(degz, bsum);
  scan_final<<<75, 256, 0, stream>>>(degz, bsum, rp_w, rp_c, rp_r);
  int* col_w = colz;
  int* col_c = colz + E;
  int* col_r = colz + 2 * E;

  for (int l = 0; l < L; ++l) {
    const int SQA = 2 + l * 10 + 0, SQP = 2 + l * 10 + 1;
    auto SKV = [&](int r){ return 2 + l * 10 + 2 + r * 2; };
    const int SO0 = 2 + l * 10 + 8, SO1 = 2 + l * 10 + 9;
    const float* bq_a = kqv_b + ((size_t)((l*3 + 1)*2 + 0)) * D;
    const float* bq_p = kqv_b + ((size_t)((l*3 + 1)*2 + 1)) * D;
    auto CB2 = [&](int r){ return cb + ((size_t)((l*R + r)*2)) * D; };
    const float* prelW = p_rel + (size_t)(l*R + 0) * H;
    const float* prelR = p_rel + (size_t)(l*R + 1) * H;
    const float* prelC = p_rel + (size_t)(l*R + 2) * H;

    if (l == 0) {
      // biggemm(l0) || fill3  (7038 blocks, 9-way interleave)
      fusedFill<<<7038, 256, 0, stream>>>(
          h_a, h_p, PH(SQA), PH(SQP), PH(SKV(1)), PH(SKV(0)), PH(SKV(2)),
          bq_a, bq_p, CB2(1), CB2(0), CB2(2),
          b_q, b_q2, b_kvR, b_kvW, b_kvC,
          ei_w, ei_c, ei_r, rp_w, rp_c, rp_r, cntz, colz);
    } else {
      biggemm<<<dim3(GB2c, 8), 256, 0, stream>>>(
          h_a, h_p, PH(SQA), PH(SQP), PH(SKV(1)), PH(SKV(0)), PH(SKV(2)),
          bq_a, bq_p, CB2(1), CB2(0), CB2(2),
          b_q, b_q2, b_kvR, b_kvW, b_kvC);
    }
    bigattn<<<2 * GAc, 256, 0, stream>>>(
        rp_r, col_r, b_kvR, b_q,
        rp_w, col_w, b_kvW, rp_c, col_c, b_kvC, b_q2,
        prelR, prelW, prelC);
    bigmix<<<dim3(GB2c, 2), 256, 0, stream>>>(
        b_q,  PH(SO0), out_b + (size_t)(l*2 + 0) * D, h_a, skip + l*2 + 0,
        b_q2, PH(SO1), out_b + (size_t)(l*2 + 1) * D, h_p, skip + l*2 + 1);
  }

  gemm_cls<<<dim3(GB2c, 1), 256, 0, stream>>>(
      h_p, PH(22), PL(22), cls_b, out, NPP);
}

// Round 16
// 781.882 us; speedup vs baseline: 1.6812x; 1.0230x over previous
//
#include <hip/hip_runtime.h>
#include <hip/hip_bf16.h>
#include <math.h>

constexpr int NA  = 100000;
constexpr int NPP = 100000;
constexpr int D   = 128;
constexpr int H   = 4;
constexpr int E   = 400000;
constexpr int R   = 3;
constexpr int L   = 2;
constexpr int NSLOT = 23;
constexpr int SLOT_ELEMS = 8 * 4 * 512;   // 8 col-tiles * 4 ksteps * 512 bf16
constexpr int GB2c = (NA + 127) / 128;    // 782
constexpr int GAc  = NA / 8;              // 12500

using s8v = __attribute__((ext_vector_type(8))) short;
using f4v = __attribute__((ext_vector_type(4))) float;
typedef unsigned short ushort_t;

static __device__ __forceinline__ unsigned short f2bf(float f) {
  unsigned u = __float_as_uint(f);
  return (unsigned short)((u + 0x7fffu + ((u >> 16) & 1u)) >> 16);
}
static __device__ __forceinline__ float bf2f(unsigned short s) {
  return __uint_as_float(((unsigned)s) << 16);
}
static __device__ __forceinline__ float klo(int i) {        // low bf16 -> f32
  return __uint_as_float(((unsigned)i) << 16);
}
static __device__ __forceinline__ float vhi(int i) {        // high bf16 -> f32
  return __uint_as_float(((unsigned)i) & 0xffff0000u);
}
static __device__ __forceinline__ float gelu_f(float x) {
  return 0.5f * x * (1.0f + erff(x * 0.70710678118654752f));
}
static __device__ __forceinline__ float elu_f(float x) {
  return x > 0.0f ? x : expm1f(x);
}

// ============ device GEMM bodies (bf16 A, hi-only B, LDS-staged) ================
static __device__ __forceinline__ void load_a2(
    const ushort_t* __restrict__ A, int ar0, int ar1, int ks, int g,
    s8v& a0, s8v& a1) {
  const ushort_t* ap0 = A + (size_t)ar0 * 128 + ks * 32 + g * 4;
  ushort4 u0 = *(const ushort4*)ap0;
  ushort4 u1 = *(const ushort4*)(ap0 + 16);
  a0[0]=(short)u0.x; a0[1]=(short)u0.y; a0[2]=(short)u0.z; a0[3]=(short)u0.w;
  a0[4]=(short)u1.x; a0[5]=(short)u1.y; a0[6]=(short)u1.z; a0[7]=(short)u1.w;
  const ushort_t* ap1 = A + (size_t)ar1 * 128 + ks * 32 + g * 4;
  ushort4 v0 = *(const ushort4*)ap1;
  ushort4 v1 = *(const ushort4*)(ap1 + 16);
  a1[0]=(short)v0.x; a1[1]=(short)v0.y; a1[2]=(short)v0.z; a1[3]=(short)v0.w;
  a1[4]=(short)v1.x; a1[5]=(short)v1.y; a1[6]=(short)v1.z; a1[7]=(short)v1.w;
}

template<bool GELU_A, bool MIX>
__device__ __forceinline__ void dev_gemm8(
    const ushort_t* __restrict__ A, const ushort_t* __restrict__ Bhi,
    const float* __restrict__ bias, ushort_t* __restrict__ Cout,
    const float* __restrict__ skip_ptr, int M, int bx, ushort_t* Bs) {
  for (int i = threadIdx.x; i < 2048; i += 256)
    *(s8v*)&Bs[i * 8] = *(const s8v*)(Bhi + (size_t)i * 8);
  __syncthreads();
  const int lane = threadIdx.x & 63;
  const int wave = threadIdx.x >> 6;
  const int row0 = bx * 128 + wave * 32;
  const int g = lane >> 4, li = lane & 15;
  f4v acc0[8], acc1[8];
#pragma unroll
  for (int ct = 0; ct < 8; ++ct) {
    acc0[ct] = f4v{0.f, 0.f, 0.f, 0.f};
    acc1[ct] = f4v{0.f, 0.f, 0.f, 0.f};
  }
  int ar0 = row0 + li;       if (ar0 >= M) ar0 = M - 1;
  int ar1 = row0 + 16 + li;  if (ar1 >= M) ar1 = M - 1;
#pragma unroll
  for (int ks = 0; ks < 4; ++ks) {
    s8v a0, a1;
    load_a2(A, ar0, ar1, ks, g, a0, a1);
    if (GELU_A) {
#pragma unroll
      for (int i = 0; i < 8; ++i) {
        a0[i] = (short)f2bf(gelu_f(bf2f((unsigned short)a0[i])));
        a1[i] = (short)f2bf(gelu_f(bf2f((unsigned short)a1[i])));
      }
    }
#pragma unroll
    for (int ct = 0; ct < 8; ++ct) {
      s8v bhi = *(const s8v*)&Bs[(ct * 4 + ks) * 512 + lane * 8];
      acc0[ct] = __builtin_amdgcn_mfma_f32_16x16x32_bf16(a0, bhi, acc0[ct], 0, 0, 0);
      acc1[ct] = __builtin_amdgcn_mfma_f32_16x16x32_bf16(a1, bhi, acc1[ct], 0, 0, 0);
    }
  }
  float sskip = 0.f;
  if (MIX) sskip = 1.f / (1.f + __expf(-*skip_ptr));
#pragma unroll
  for (int rf = 0; rf < 2; ++rf) {
#pragma unroll
    for (int ct = 0; ct < 8; ++ct) {
      int col = ct * 16 + li;
      float bv = bias[col];
      f4v a = rf ? acc1[ct] : acc0[ct];
#pragma unroll
      for (int r = 0; r < 4; ++r) {
        int grow = row0 + rf * 16 + g * 4 + r;
        if (grow < M) {
          float v = a[r] + bv;
          size_t off = (size_t)grow * 128 + col;
          if constexpr (MIX) {
            float hprev = bf2f(Cout[off]);
            Cout[off] = f2bf(elu_f(sskip * v + (1.f - sskip) * hprev));
          } else {
            Cout[off] = f2bf(v);
          }
        }
      }
    }
  }
}

__device__ __forceinline__ void dev_gemm_kv(
    const ushort_t* __restrict__ A, const ushort_t* __restrict__ Bkv,
    const float* __restrict__ bias, ushort_t* __restrict__ kvout,
    int M, int bx, int ch, ushort_t* Bs) {
  for (int i = threadIdx.x; i < 2048; i += 256) {
    int kvh = i >> 10, j = i & 1023;
    const ushort_t* src = Bkv + (size_t)kvh * SLOT_ELEMS + ch * 8192 + j * 8;
    *(s8v*)&Bs[kvh * 8192 + j * 8] = *(const s8v*)src;
  }
  __syncthreads();
  const int lane = threadIdx.x & 63;
  const int wave = threadIdx.x >> 6;
  const int row0 = bx * 128 + wave * 32;
  const int g = lane >> 4, li = lane & 15;
  f4v acc0[8], acc1[8];                    // [0..3]=K, [4..7]=V
#pragma unroll
  for (int t = 0; t < 8; ++t) {
    acc0[t] = f4v{0.f, 0.f, 0.f, 0.f};
    acc1[t] = f4v{0.f, 0.f, 0.f, 0.f};
  }
  int ar0 = row0 + li;       if (ar0 >= M) ar0 = M - 1;
  int ar1 = row0 + 16 + li;  if (ar1 >= M) ar1 = M - 1;
#pragma unroll
  for (int ks = 0; ks < 4; ++ks) {
    s8v a0, a1;
    load_a2(A, ar0, ar1, ks, g, a0, a1);
#pragma unroll
    for (int t = 0; t < 4; ++t) {
      s8v kh = *(const s8v*)&Bs[(t * 4 + ks) * 512 + lane * 8];
      acc0[t] = __builtin_amdgcn_mfma_f32_16x16x32_bf16(a0, kh, acc0[t], 0, 0, 0);
      acc1[t] = __builtin_amdgcn_mfma_f32_16x16x32_bf16(a1, kh, acc1[t], 0, 0, 0);
      s8v vh = *(const s8v*)&Bs[8192 + (t * 4 + ks) * 512 + lane * 8];
      acc0[4 + t] = __builtin_amdgcn_mfma_f32_16x16x32_bf16(a0, vh, acc0[4 + t], 0, 0, 0);
      acc1[4 + t] = __builtin_amdgcn_mfma_f32_16x16x32_bf16(a1, vh, acc1[4 + t], 0, 0, 0);
    }
  }
#pragma unroll
  for (int rf = 0; rf < 2; ++rf) {
#pragma unroll
    for (int t = 0; t < 4; ++t) {
      int col = ch * 64 + t * 16 + li;
      float bk = bias[col], bv = bias[128 + col];
#pragma unroll
      for (int r = 0; r < 4; ++r) {
        int grow = row0 + rf * 16 + g * 4 + r;
        if (grow < M) {
          float kvl = rf ? acc1[t][r] : acc0[t][r];
          float vvl = rf ? acc1[4 + t][r] : acc0[4 + t][r];
          ushort2 o;
          o.x = f2bf(kvl + bk);
          o.y = f2bf(vvl + bv);
          *(ushort2*)(kvout + (size_t)grow * 256 + 2 * col) = o;
        }
      }
    }
  }
}

// fp32-A proj body: bf16-rounded A, B hi/lo split (4 MFMAs/tile-pair); 64KB Bs
__device__ __forceinline__ void dev_proj(
    const float* __restrict__ A, const ushort_t* __restrict__ Bhi,
    const ushort_t* __restrict__ Blo, const float* __restrict__ bias,
    ushort_t* __restrict__ Cout, int M, int bx, ushort_t* Bs) {
  for (int i = threadIdx.x; i < 4096; i += 256) {
    int half = i >> 11, j = i & 2047;
    const ushort_t* src = (half ? Blo : Bhi) + (size_t)j * 8;
    *(s8v*)&Bs[half * 16384 + j * 8] = *(const s8v*)src;
  }
  __syncthreads();
  const int lane = threadIdx.x & 63;
  const int wave = threadIdx.x >> 6;
  const int row0 = bx * 128 + wave * 32;
  const int g = lane >> 4, li = lane & 15;
  f4v acc0[8], acc1[8];
#pragma unroll
  for (int ct = 0; ct < 8; ++ct) {
    acc0[ct] = f4v{0.f, 0.f, 0.f, 0.f};
    acc1[ct] = f4v{0.f, 0.f, 0.f, 0.f};
  }
  int ar0 = row0 + li;       if (ar0 >= M) ar0 = M - 1;
  int ar1 = row0 + 16 + li;  if (ar1 >= M) ar1 = M - 1;
#pragma unroll
  for (int ks = 0; ks < 4; ++ks) {
    s8v ahi[2];
#pragma unroll
    for (int rf = 0; rf < 2; ++rf) {
      int ar = rf ? ar1 : ar0;
      const float* ap = A + (size_t)ar * 128 + ks * 32 + g * 4;
      float4 u0 = *(const float4*)ap;
      float4 u1 = *(const float4*)(ap + 16);
      float x[8] = {u0.x, u0.y, u0.z, u0.w, u1.x, u1.y, u1.z, u1.w};
#pragma unroll
      for (int i = 0; i < 8; ++i) ahi[rf][i] = (short)f2bf(x[i]);
    }
#pragma unroll
    for (int ct = 0; ct < 8; ++ct) {
      const ushort_t* bp = &Bs[(ct * 4 + ks) * 512 + lane * 8];
      s8v bhi = *(const s8v*)bp;
      s8v blo = *(const s8v*)(bp + 16384);
      acc0[ct] = __builtin_amdgcn_mfma_f32_16x16x32_bf16(ahi[0], bhi, acc0[ct], 0, 0, 0);
      acc1[ct] = __builtin_amdgcn_mfma_f32_16x16x32_bf16(ahi[1], bhi, acc1[ct], 0, 0, 0);
      acc0[ct] = __builtin_amdgcn_mfma_f32_16x16x32_bf16(ahi[0], blo, acc0[ct], 0, 0, 0);
      acc1[ct] = __builtin_amdgcn_mfma_f32_16x16x32_bf16(ahi[1], blo, acc1[ct], 0, 0, 0);
    }
  }
#pragma unroll
  for (int rf = 0; rf < 2; ++rf) {
#pragma unroll
    for (int ct = 0; ct < 8; ++ct) {
      int col = ct * 16 + li;
      float bv = bias[col];
      f4v a = rf ? acc1[ct] : acc0[ct];
#pragma unroll
      for (int r = 0; r < 4; ++r) {
        int grow = row0 + rf * 16 + g * 4 + r;
        if (grow < M) Cout[(size_t)grow * 128 + col] = f2bf(a[r] + bv);
      }
    }
  }
}

// ============ attention body: single merged stream, 2 dst/wave, 4-deep ==========
// SEL: per-edge p_rel select by arena row (row>=NA -> cites).
template<bool SEL>
__device__ __forceinline__ void dev_attn_m(
    const int* __restrict__ rp, const int* __restrict__ col,
    const ushort_t* __restrict__ kv, const ushort_t* __restrict__ q,
    float prW, float prC, ushort_t* __restrict__ aggout, int ablk) {
  int lane = threadIdx.x & 63;
  int wave = threadIdx.x >> 6;
  int half = lane >> 5;
  int l32  = lane & 31;
  int dst  = ablk * 8 + wave * 2 + half;   // ndst % 8 == 0: no tail
  ushort4 qv = *(const ushort4*)(q + (size_t)dst * D + l32 * 4);
  float q0 = bf2f(qv.x), q1 = bf2f(qv.y), q2 = bf2f(qv.z), q3 = bf2f(qv.w);
  int e0 = rp[dst];
  int dt = rp[dst + 1] - e0;
  float z = 0.f, a0 = 0.f, a1 = 0.f, a2 = 0.f, a3 = 0.f;
  for (int jj = 0; jj < dt; jj += 4) {
    int4 us[4]; bool vs[4]; float prs[4];
#pragma unroll
    for (int s2 = 0; s2 < 4; ++s2) {
      int idx = jj + s2;
      bool v = idx < dt;
      int ci = e0 + (v ? idx : 0);
      int row = col[ci];
      us[s2] = *(const int4*)(kv + (size_t)row * 256 + l32 * 8);
      vs[s2] = v;
      prs[s2] = SEL ? ((row >= NA) ? prC : prW) : prW;
    }
#pragma unroll
    for (int s2 = 0; s2 < 4; ++s2) {
      float p = q0 * klo(us[s2].x) + q1 * klo(us[s2].y)
              + q2 * klo(us[s2].z) + q3 * klo(us[s2].w);
      p += __shfl_xor(p, 1);
      p += __shfl_xor(p, 2);
      p += __shfl_xor(p, 4);
      float e = vs[s2] ? __expf(p * prs[s2]) : 0.f;
      z  += e;
      a0 += e * vhi(us[s2].x);
      a1 += e * vhi(us[s2].y);
      a2 += e * vhi(us[s2].z);
      a3 += e * vhi(us[s2].w);
    }
  }
  float inv = 1.f / (z + 1e-16f);
  ushort4 o;
  o.x = f2bf(a0 * inv);
  o.y = f2bf(a1 * inv);
  o.z = f2bf(a2 * inv);
  o.w = f2bf(a3 * inv);
  *(ushort4*)(aggout + (size_t)dst * D + l32 * 4) = o;
}

// ============ device CSR-build bodies ===========================================
__device__ __forceinline__ void dev_count(const int* __restrict__ dst,
                                          int* __restrict__ deg, int bidx) {
  for (int e = bidx * 256 + (int)threadIdx.x; e < E; e += 256 * 256)
    atomicAdd(&deg[dst[e]], 1);
}
__device__ __forceinline__ void dev_fill(const int* __restrict__ ei,
                                         const int* __restrict__ rp,
                                         int* __restrict__ cnt,
                                         int* __restrict__ col, int bidx, int off) {
  const int* dst = ei + E;
  for (int e = bidx * 256 + (int)threadIdx.x; e < E; e += 256 * 256) {
    int d = dst[e];
    int pos = atomicAdd(&cnt[d], 1);
    col[rp[d] + pos] = ei[e] + off;
  }
}

// =============== global kernels =================================================
// fusedProj: proj_a || proj_p || count (3-way interleave: b%3==2 -> count)
__global__ __launch_bounds__(256, 2) void fusedProj(
    const float* __restrict__ x_a, const float* __restrict__ x_p,
    const ushort_t* __restrict__ B0h, const ushort_t* __restrict__ B0l,
    const ushort_t* __restrict__ B1h, const ushort_t* __restrict__ B1l,
    const float* __restrict__ proj_b,
    ushort_t* __restrict__ h_a, ushort_t* __restrict__ h_p,
    const int* __restrict__ ei_w, const int* __restrict__ ei_c,
    const int* __restrict__ ei_r, int* __restrict__ degz) {
  __shared__ ushort_t Bs[32768];
  unsigned b = blockIdx.x;
  if (b % 3 == 2) {
    int ci = b / 3;
    if (ci < 768) {
      int rel = ci >> 8, sub = ci & 255;
      const int* dst = rel == 0 ? ei_w + E : rel == 1 ? ei_c + E : ei_r + E;
      int* deg = (rel == 2) ? (degz + NPP) : degz;   // deg_p merged; deg_a second
      dev_count(dst, deg, sub);
    }
  } else {
    int gi = b - (b + 1) / 3;
    if (gi < GB2c) dev_proj(x_a, B0h, B0l, proj_b,     h_a, NA,  gi, Bs);
    else           dev_proj(x_p, B1h, B1l, proj_b + D, h_p, NPP, gi - GB2c, Bs);
  }
}

// bigGEMM slices: s0 q_a | s1 q_p | s2,3 kv_rev | s4,5 kvW->arena[0,NA) | s6,7 kvC->arena[NA,..)
__device__ __forceinline__ void dev_biggemm_slice(
    int slice, int bx,
    const ushort_t* h_a, const ushort_t* h_p,
    const ushort_t* Bqa, const ushort_t* Bqp,
    const ushort_t* BkvR, const ushort_t* BkvW, const ushort_t* BkvC,
    const float* bqa, const float* bqp,
    const float* cbR, const float* cbW, const float* cbC,
    ushort_t* b_q, ushort_t* b_q2,
    ushort_t* kvR, ushort_t* kvP, ushort_t* Bs) {
  if (slice == 0)      dev_gemm8<false, false>(h_a, Bqa, bqa, b_q,  nullptr, NA,  bx, Bs);
  else if (slice == 1) dev_gemm8<false, false>(h_p, Bqp, bqp, b_q2, nullptr, NPP, bx, Bs);
  else if (slice <= 3) dev_gemm_kv(h_p, BkvR, cbR, kvR, NPP, bx, slice - 2, Bs);
  else if (slice <= 5) dev_gemm_kv(h_a, BkvW, cbW, kvP, NA,  bx, slice - 4, Bs);
  else                 dev_gemm_kv(h_p, BkvC, cbC, kvP + (size_t)NA * 256, NPP, bx, slice - 6, Bs);
}

__global__ __launch_bounds__(256, 4) void biggemm(
    const ushort_t* __restrict__ h_a, const ushort_t* __restrict__ h_p,
    const ushort_t* __restrict__ Bqa, const ushort_t* __restrict__ Bqp,
    const ushort_t* __restrict__ BkvR, const ushort_t* __restrict__ BkvW,
    const ushort_t* __restrict__ BkvC,
    const float* __restrict__ bqa, const float* __restrict__ bqp,
    const float* __restrict__ cbR, const float* __restrict__ cbW,
    const float* __restrict__ cbC,
    ushort_t* __restrict__ b_q, ushort_t* __restrict__ b_q2,
    ushort_t* __restrict__ kvR, ushort_t* __restrict__ kvP) {
  __shared__ ushort_t Bs[16384];
  dev_biggemm_slice(blockIdx.y, blockIdx.x, h_a, h_p, Bqa, Bqp, BkvR, BkvW, BkvC,
                    bqa, bqp, cbR, cbW, cbC, b_q, b_q2, kvR, kvP, Bs);
}

// fusedFill (layer 0): biggemm || fill (768 blocks), 9-way interleave
__global__ __launch_bounds__(256, 4) void fusedFill(
    const ushort_t* __restrict__ h_a, const ushort_t* __restrict__ h_p,
    const ushort_t* __restrict__ Bqa, const ushort_t* __restrict__ Bqp,
    const ushort_t* __restrict__ BkvR, const ushort_t* __restrict__ BkvW,
    const ushort_t* __restrict__ BkvC,
    const float* __restrict__ bqa, const float* __restrict__ bqp,
    const float* __restrict__ cbR, const float* __restrict__ cbW,
    const float* __restrict__ cbC,
    ushort_t* __restrict__ b_q, ushort_t* __restrict__ b_q2,
    ushort_t* __restrict__ kvR, ushort_t* __restrict__ kvP,
    const int* __restrict__ ei_w, const int* __restrict__ ei_c,
    const int* __restrict__ ei_r,
    const int* __restrict__ rp_p, const int* __restrict__ rp_r,
    int* __restrict__ cntz, int* __restrict__ col_p, int* __restrict__ col_r) {
  __shared__ ushort_t Bs[16384];
  unsigned b = blockIdx.x;
  if (b % 9 == 8) {
    int fi = b / 9;
    if (fi < 768) {
      int rel = fi >> 8, sub = fi & 255;
      if (rel == 0)      dev_fill(ei_w, rp_p, cntz,       col_p, sub, 0);
      else if (rel == 1) dev_fill(ei_c, rp_p, cntz,       col_p, sub, NA);
      else               dev_fill(ei_r, rp_r, cntz + NPP, col_r, sub, 0);
    }
  } else {
    int gi = b - (b + 1) / 9;
    int slice = gi & 7, bx = gi >> 3;
    if (bx < GB2c)
      dev_biggemm_slice(slice, bx, h_a, h_p, Bqa, Bqp, BkvR, BkvW, BkvC,
                        bqa, bqp, cbR, cbW, cbC, b_q, b_q2, kvR, kvP, Bs);
  }
}

// bigATTN: parity-interleaved author (odd) + paper (even); 2*GAc blocks
__global__ __launch_bounds__(256, 8) void bigattn(
    const int* __restrict__ rp_r, const int* __restrict__ col_r,
    const ushort_t* __restrict__ kvR, ushort_t* __restrict__ q_a,
    const int* __restrict__ rp_p, const int* __restrict__ col_p,
    const ushort_t* __restrict__ kvP, ushort_t* __restrict__ q_p,
    const float* __restrict__ prelR, const float* __restrict__ prelW,
    const float* __restrict__ prelC) {
  unsigned x = blockIdx.x;
  int head = (threadIdx.x & 31) >> 3;
  const float scale = 0.17677669529663688f; // 1/sqrt(32)
  if (x & 1) {
    float pr = prelR[head] * scale;
    dev_attn_m<false>(rp_r, col_r, kvR, q_a, pr, pr, q_a, (int)(x >> 1));
  } else {
    dev_attn_m<true>(rp_p, col_p, kvP, q_p,
                     prelW[head] * scale, prelC[head] * scale, q_p, (int)(x >> 1));
  }
}

// bigMIX: y0 author out-mix | y1 paper out-mix
__global__ __launch_bounds__(256, 4) void bigmix(
    const ushort_t* __restrict__ agg_a, const ushort_t* __restrict__ Bo0,
    const float* __restrict__ ob0, ushort_t* __restrict__ h_a,
    const float* __restrict__ sk0,
    const ushort_t* __restrict__ agg_p, const ushort_t* __restrict__ Bo1,
    const float* __restrict__ ob1, ushort_t* __restrict__ h_p,
    const float* __restrict__ sk1) {
  __shared__ ushort_t Bs[16384];
  if (blockIdx.y == 0) dev_gemm8<true, true>(agg_a, Bo0, ob0, h_a, sk0, NA,  blockIdx.x, Bs);
  else                 dev_gemm8<true, true>(agg_p, Bo1, ob1, h_p, sk1, NPP, blockIdx.x, Bs);
}

// cls: bf16 A, B hi/lo, fp32 out, 3 col tiles (40 cols)
__global__ __launch_bounds__(256, 4) void gemm_cls(
    const ushort_t* __restrict__ A,
    const ushort_t* __restrict__ Bhi, const ushort_t* __restrict__ Blo,
    const float* __restrict__ bias, float* __restrict__ Cv, int M) {
  constexpr int NT16 = 3;
  constexpr int HN = NT16 * 2048;
  __shared__ ushort_t Bs[HN * 2];
  for (int i = threadIdx.x; i < (HN / 8) * 2; i += 256) {
    int half = i / (HN / 8), j = i % (HN / 8);
    const ushort_t* src = (half ? Blo : Bhi) + (size_t)j * 8;
    *(s8v*)&Bs[half * HN + j * 8] = *(const s8v*)src;
  }
  __syncthreads();
  const int lane = threadIdx.x & 63;
  const int wave = threadIdx.x >> 6;
  const int row0 = blockIdx.x * 128 + wave * 32;
  const int g = lane >> 4, li = lane & 15;
  f4v acc0[NT16], acc1[NT16];
#pragma unroll
  for (int ct = 0; ct < NT16; ++ct) {
    acc0[ct] = f4v{0.f, 0.f, 0.f, 0.f};
    acc1[ct] = f4v{0.f, 0.f, 0.f, 0.f};
  }
  int ar0 = row0 + li;       if (ar0 >= M) ar0 = M - 1;
  int ar1 = row0 + 16 + li;  if (ar1 >= M) ar1 = M - 1;
#pragma unroll
  for (int ks = 0; ks < 4; ++ks) {
    s8v a0, a1;
    load_a2(A, ar0, ar1, ks, g, a0, a1);
#pragma unroll
    for (int ct = 0; ct < NT16; ++ct) {
      const ushort_t* bp = &Bs[(ct * 4 + ks) * 512 + lane * 8];
      s8v bhi = *(const s8v*)bp;
      s8v blo = *(const s8v*)(bp + HN);
      acc0[ct] = __builtin_amdgcn_mfma_f32_16x16x32_bf16(a0, bhi, acc0[ct], 0, 0, 0);
      acc1[ct] = __builtin_amdgcn_mfma_f32_16x16x32_bf16(a1, bhi, acc1[ct], 0, 0, 0);
      acc0[ct] = __builtin_amdgcn_mfma_f32_16x16x32_bf16(a0, blo, acc0[ct], 0, 0, 0);
      acc1[ct] = __builtin_amdgcn_mfma_f32_16x16x32_bf16(a1, blo, acc1[ct], 0, 0, 0);
    }
  }
#pragma unroll
  for (int rf = 0; rf < 2; ++rf) {
#pragma unroll
    for (int ct = 0; ct < NT16; ++ct) {
      int col = ct * 16 + li;
      bool colok = (col < 40);
      float bv = colok ? bias[col] : 0.f;
      f4v a = rf ? acc1[ct] : acc0[ct];
#pragma unroll
      for (int r = 0; r < 4; ++r) {
        int grow = row0 + rf * 16 + g * 4 + r;
        if (grow < M && colok) Cv[(size_t)grow * 40 + col] = a[r] + bv;
      }
    }
  }
}

// ------------- combined weights: cw = W @ blockdiag(rel), cb = b @ blockdiag(rel)
__global__ __launch_bounds__(256) void combine_w(
    const float* __restrict__ kqv_w, const float* __restrict__ kqv_b,
    const float* __restrict__ rel_a, const float* __restrict__ rel_m,
    float* __restrict__ cw, float* __restrict__ cb) {
  int b  = blockIdx.x;            // ((l*R)+r)*2+kv
  int kv = b & 1;
  int r  = (b >> 1) % R;
  int l  = b / (2 * R);
  int t_src = (r == 0) ? 0 : 1;
  int i_w   = (kv == 0) ? 0 : 2;
  const float* W    = kqv_w + ((size_t)((l*3 + i_w)*2 + t_src)) * D * D;
  const float* bvec = kqv_b + ((size_t)((l*3 + i_w)*2 + t_src)) * D;
  const float* rel  = ((kv == 0) ? rel_a : rel_m) + ((size_t)(l*R + r)) * H * 32 * 32;
  float* Cout = cw + (size_t)b * D * D;
  float* cbo  = cb + (size_t)b * D;
  for (int idx = threadIdx.x; idx < D * D; idx += 256) {
    int i = idx / D, j = idx % D;
    int h = j >> 5, f = j & 31;
    const float* relh = rel + h * 32 * 32;
    float sum = 0.f;
#pragma unroll
    for (int d = 0; d < 32; ++d) sum += W[i*D + (h*32 + d)] * relh[d*32 + f];
    Cout[idx] = sum;
  }
  if (threadIdx.x < D) {
    int j = threadIdx.x;
    int h = j >> 5, f = j & 31;
    const float* relh = rel + h * 32 * 32;
    float sum = 0.f;
#pragma unroll
    for (int d = 0; d < 32; ++d) sum += bvec[h*32 + d] * relh[d*32 + f];
    cbo[j] = sum;
  }
}

// ------------- pack weight matrices into MFMA-fragment order (hi/lo split) -------
__global__ __launch_bounds__(256) void pack_b(
    const float* __restrict__ proj_w, const float* __restrict__ kqv_w,
    const float* __restrict__ out_w, const float* __restrict__ cls_w,
    const float* __restrict__ cw,
    ushort_t* __restrict__ phi, ushort_t* __restrict__ plo) {
  int slot = blockIdx.x;
  const float* src; int ncol = 128;
  if (slot == 0) src = proj_w;
  else if (slot == 1) src = proj_w + D * D;
  else if (slot == 22) { src = cls_w; ncol = 40; }
  else {
    int l = (slot - 2) / 10, k = (slot - 2) % 10;
    if (k == 0)      src = kqv_w + ((size_t)((l*3 + 1)*2 + 0)) * D * D;
    else if (k == 1) src = kqv_w + ((size_t)((l*3 + 1)*2 + 1)) * D * D;
    else if (k < 8)  { int idx = k - 2; src = cw + ((size_t)((l*R)*2 + idx)) * D * D; }
    else             src = out_w + ((size_t)(l*2 + (k - 8))) * D * D;
  }
  int nt = (ncol + 15) / 16;
  int total = nt * 4 * 512;
  ushort_t* ph = phi + (size_t)slot * SLOT_ELEMS;
  ushort_t* pl = plo + (size_t)slot * SLOT_ELEMS;
  for (int idx = threadIdx.x; idx < total; idx += 256) {
    int j = idx & 7, lane = (idx >> 3) & 63, ks = (idx >> 9) & 3, ct = idx >> 11;
    int k = 4 * (lane >> 4) + (j & 3) + 16 * (j >> 2) + 32 * ks;
    int n = ct * 16 + (lane & 15);
    float v = (n < ncol) ? src[(size_t)k * ncol + n] : 0.f;
    unsigned short h = f2bf(v);
    ph[idx] = h;
    pl[idx] = f2bf(v - bf2f(h));
  }
}

// ---------------- scans (2 arrays: deg_p, deg_a; 50 blocks) ---------------------
__global__ __launch_bounds__(256) void scan_partial(const int* __restrict__ degz,
                                                    int* __restrict__ bsum) {
  int blk = blockIdx.x, rel = blk / 25, t25 = blk % 25;
  const int* deg = degz + rel * NPP + t25 * 4096;
  int nrem = min(4096, NPP - t25 * 4096);
  int base = threadIdx.x * 16;
  int s = 0;
  if (base < nrem) {
#pragma unroll
    for (int i4 = 0; i4 < 4; ++i4) {
      int4 v = *(const int4*)(deg + base + i4 * 4);
      s += v.x + v.y + v.z + v.w;
    }
  }
  __shared__ int sm[256];
  sm[threadIdx.x] = s; __syncthreads();
  for (int o = 128; o > 0; o >>= 1) {
    if (threadIdx.x < o) sm[threadIdx.x] += sm[threadIdx.x + o];
    __syncthreads();
  }
  if (threadIdx.x == 0) bsum[blk] = sm[0];
}
__global__ __launch_bounds__(256) void scan_final(const int* __restrict__ degz,
                                                  const int* __restrict__ bsum,
                                                  int* rp_p, int* rp_r) {
  int blk = blockIdx.x, rel = blk / 25, t25 = blk % 25;
  const int* deg = degz + rel * NPP + t25 * 4096;
  int* rpb = (rel == 0 ? rp_p : rp_r);
  int* rp = rpb + t25 * 4096;
  int boffv = 0;
  for (int i = 0; i < t25; ++i) boffv += bsum[rel * 25 + i];
  int nrem = min(4096, NPP - t25 * 4096);
  int base = threadIdx.x * 16;
  bool ok = base < nrem;
  int v[16]; int s = 0;
  if (ok) {
#pragma unroll
    for (int i4 = 0; i4 < 4; ++i4) {
      int4 u = *(const int4*)(deg + base + i4 * 4);
      v[i4*4+0] = u.x; v[i4*4+1] = u.y; v[i4*4+2] = u.z; v[i4*4+3] = u.w;
      s += u.x + u.y + u.z + u.w;
    }
  }
  __shared__ int sm[256];
  sm[threadIdx.x] = s; __syncthreads();
  for (int o = 1; o < 256; o <<= 1) {
    int x = (threadIdx.x >= o) ? sm[threadIdx.x - o] : 0;
    __syncthreads(); sm[threadIdx.x] += x; __syncthreads();
  }
  int run = boffv + sm[threadIdx.x] - s;
  if (ok) {
    int w[16];
#pragma unroll
    for (int i = 0; i < 16; ++i) { w[i] = run; run += v[i]; }
#pragma unroll
    for (int i4 = 0; i4 < 4; ++i4) *(int4*)(rp + base + i4 * 4) = *(const int4*)&w[i4*4];
  }
  if (t25 == 24 && threadIdx.x == 255) rpb[NPP] = boffv + sm[255];
}

extern "C" void kernel_launch(void* const* d_in, const int* in_sizes, int n_in,
                              void* d_out, int out_size, void* d_ws, size_t ws_size,
                              hipStream_t stream) {
  const float* x_a    = (const float*)d_in[0];
  const float* x_p    = (const float*)d_in[1];
  const int*   ei_w   = (const int*)d_in[2];
  const int*   ei_r   = (const int*)d_in[3];
  const int*   ei_c   = (const int*)d_in[4];
  const float* proj_w = (const float*)d_in[5];
  const float* proj_b = (const float*)d_in[6];
  const float* kqv_w  = (const float*)d_in[7];
  const float* kqv_b  = (const float*)d_in[8];
  const float* out_w  = (const float*)d_in[9];
  const float* out_b  = (const float*)d_in[10];
  const float* rel_a  = (const float*)d_in[11];
  const float* rel_m  = (const float*)d_in[12];
  const float* p_rel  = (const float*)d_in[13];
  const float* skip   = (const float*)d_in[14];
  const float* cls_w  = (const float*)d_in[15];
  const float* cls_b  = (const float*)d_in[16];
  float* out = (float*)d_out;

  const size_t NF = (size_t)NA * D;   // 12.8M
  char* p = (char*)d_ws;
  float* cw = (float*)p;              p += (size_t)12 * D * D * 4;
  float* cb = (float*)p;              p += (size_t)12 * D * 4;
  ushort_t* h_a   = (ushort_t*)p;     p += NF * 2;
  ushort_t* h_p   = (ushort_t*)p;     p += NF * 2;
  ushort_t* b_q   = (ushort_t*)p;     p += NF * 2;
  ushort_t* b_q2  = (ushort_t*)p;     p += NF * 2;
  ushort_t* b_kvR = (ushort_t*)p;     p += 2 * NF * 2;
  ushort_t* b_kvP = (ushort_t*)p;     p += 4 * NF * 2;   // arena: [0,NA) writes; [NA,..) cites
  ushort_t* phi = (ushort_t*)p;       p += (size_t)NSLOT * SLOT_ELEMS * 2;
  ushort_t* plo = (ushort_t*)p;       p += (size_t)NSLOT * SLOT_ELEMS * 2;
  int* rp_p = (int*)p;                p += (NPP + 1) * 4;
  int* rp_r = (int*)p;                p += (NA + 1) * 4;
  int* degz = (int*)p;                p += (size_t)2 * NPP * 4;   // deg_p, deg_a
  int* cntz = (int*)p;                p += (size_t)2 * NPP * 4;   // cnt_p, cnt_a
  int* col_p = (int*)p;               p += (size_t)2 * E * 4;
  int* col_r = (int*)p;               p += (size_t)E * 4;
  int* bsum = (int*)p;                p += 128 * 4;
  if (ws_size < (size_t)(p - (char*)d_ws)) return;   // graceful fail

  hipMemsetAsync(degz, 0, sizeof(int) * 4 * (size_t)NPP, stream);

  combine_w<<<12, 256, 0, stream>>>(kqv_w, kqv_b, rel_a, rel_m, cw, cb);
  pack_b<<<NSLOT, 256, 0, stream>>>(proj_w, kqv_w, out_w, cls_w, cw, phi, plo);

  auto PH = [&](int s){ return phi + (size_t)s * SLOT_ELEMS; };
  auto PL = [&](int s){ return plo + (size_t)s * SLOT_ELEMS; };

  // proj_a || proj_p || count  (2346 blocks, 3-way interleave)
  fusedProj<<<2346, 256, 0, stream>>>(
      x_a, x_p, PH(0), PL(0), PH(1), PL(1), proj_b, h_a, h_p,
      ei_w, ei_c, ei_r, degz);
  scan_partial<<<50, 256, 0, stream>>>(degz, bsum);
  scan_final<<<50, 256, 0, stream>>>(degz, bsum, rp_p, rp_r);

  for (int l = 0; l < L; ++l) {
    const int SQA = 2 + l * 10 + 0, SQP = 2 + l * 10 + 1;
    auto SKV = [&](int r){ return 2 + l * 10 + 2 + r * 2; };
    const int SO0 = 2 + l * 10 + 8, SO1 = 2 + l * 10 + 9;
    const float* bq_a = kqv_b + ((size_t)((l*3 + 1)*2 + 0)) * D;
    const float* bq_p = kqv_b + ((size_t)((l*3 + 1)*2 + 1)) * D;
    auto CB2 = [&](int r){ return cb + ((size_t)((l*R + r)*2)) * D; };
    const float* prelW = p_rel + (size_t)(l*R + 0) * H;
    const float* prelR = p_rel + (size_t)(l*R + 1) * H;
    const float* prelC = p_rel + (size_t)(l*R + 2) * H;

    if (l == 0) {
      fusedFill<<<7038, 256, 0, stream>>>(
          h_a, h_p, PH(SQA), PH(SQP), PH(SKV(1)), PH(SKV(0)), PH(SKV(2)),
          bq_a, bq_p, CB2(1), CB2(0), CB2(2),
          b_q, b_q2, b_kvR, b_kvP,
          ei_w, ei_c, ei_r, rp_p, rp_r, cntz, col_p, col_r);
    } else {
      biggemm<<<dim3(GB2c, 8), 256, 0, stream>>>(
          h_a, h_p, PH(SQA), PH(SQP), PH(SKV(1)), PH(SKV(0)), PH(SKV(2)),
          bq_a, bq_p, CB2(1), CB2(0), CB2(2),
          b_q, b_q2, b_kvR, b_kvP);
    }
    bigattn<<<2 * GAc, 256, 0, stream>>>(
        rp_r, col_r, b_kvR, b_q,
        rp_p, col_p, b_kvP, b_q2,
        prelR, prelW, prelC);
    bigmix<<<dim3(GB2c, 2), 256, 0, stream>>>(
        b_q,  PH(SO0), out_b + (size_t)(l*2 + 0) * D, h_a, skip + l*2 + 0,
        b_q2, PH(SO1), out_b + (size_t)(l*2 + 1) * D, h_p, skip + l*2 + 1);
  }

  gemm_cls<<<dim3(GB2c, 1), 256, 0, stream>>>(
      h_p, PH(22), PL(22), cls_b, out, NPP);
}